// Round 3
// 1993.719 us; speedup vs baseline: 1.4089x; 1.4089x over previous
//
#include <hip/hip_runtime.h>

// ---------------- problem constants ----------------
#define C_   64
#define U_   5
#define V_   5
#define H_   128
#define W_   128
#define NH_  4
#define HD_  16
#define WSZ  8
#define S_   64        // tokens per window
#define HW   16384     // H*W
#define UV   25        // U*V
#define POS  409600    // UV*HW, per-channel spatial size
#define TOT  26214400  // C_*POS
#define C4_  256

typedef unsigned short u16;
typedef unsigned int   u32;
typedef __attribute__((ext_vector_type(8))) short s16x8;   // 8 bf16 (4 VGPR)
typedef __attribute__((ext_vector_type(4))) float f32x4;   // MFMA acc

// bf16 <-> fp32 helpers (raw bit manipulation, round-to-nearest-even)
__device__ __forceinline__ float us2f(u16 h){ return __uint_as_float(((u32)h)<<16); }
__device__ __forceinline__ u16 f2us(float f){
  u32 u = __float_as_uint(f);
  return (u16)((u + 0x7fffu + ((u>>16)&1u))>>16);
}
__device__ __forceinline__ float silu_f(float x){ return x/(1.f+__expf(-x)); }
__device__ __forceinline__ s16x8 as_s8(uint4 u){ return __builtin_bit_cast(s16x8, u); }
__device__ __forceinline__ f32x4 mfma16(s16x8 a, s16x8 b, f32x4 c){
  return __builtin_amdgcn_mfma_f32_16x16x32_bf16(a, b, c, 0, 0, 0);
}

// ---------------- K1: LayerNorm over C (norm1) : x(f32) -> t(bf16, pools only) ----
__global__ __launch_bounds__(256,2) void k_ln1(const float* __restrict__ x,
                                               const float* __restrict__ w,
                                               const float* __restrict__ b,
                                               u16* __restrict__ t){
  int p = blockIdx.x*256 + threadIdx.x;        // 0..409599
  float v[64]; float s=0.f, sq=0.f;
  #pragma unroll
  for(int c=0;c<64;c++){ float f = x[c*POS+p]; v[c]=f; s+=f; sq+=f*f; }
  float mu = s*(1.f/64.f);
  float var = sq*(1.f/64.f) - mu*mu;
  float r = rsqrtf(var + 1e-5f);
  #pragma unroll
  for(int c=0;c<64;c++){
    t[c*POS+p] = f2us((v[c]-mu)*r*w[c] + b[c]);
  }
}

// ---------------- K7: LayerNorm over C (norm2) : x2(f32) -> t2(bf16, plane-major) ----
// Plane-major [c*25+uv][hw] — REQUIRED: mbconv's reshape(B*U*V,C,H,W) is a flat
// plane regrouping (batch n uses planes [n*64, n*64+64)), which crosses uv
// boundaries. Pixel-major keyed by true (uv,c) scrambled it (round-2 absmax 0.176).
__global__ __launch_bounds__(256,2) void k_ln2(const float* __restrict__ x2,
                                               const float* __restrict__ w,
                                               const float* __restrict__ b,
                                               u16* __restrict__ t2){
  int p = blockIdx.x*256 + threadIdx.x;
  float v[64]; float s=0.f, sq=0.f;
  #pragma unroll
  for(int c=0;c<64;c++){ float f = x2[c*POS+p]; v[c]=f; s+=f; sq+=f*f; }
  float mu = s*(1.f/64.f);
  float r = rsqrtf(sq*(1.f/64.f) - mu*mu + 1e-5f);
  #pragma unroll
  for(int c=0;c<64;c++){
    t2[c*POS+p] = f2us((v[c]-mu)*r*w[c] + b[c]);
  }
}

// ---------------- K2a: pool over (u,v) -> P_hw[c][h][w] (raw sums) ----------------
__global__ void k_pool_hw(const u16* __restrict__ t, float* __restrict__ P){
  int idx = blockIdx.x*256 + threadIdx.x;      // < 64*16384
  int c = idx>>14, hw = idx & 16383;
  const u16* base = t + c*POS + hw;
  float s = 0.f;
  #pragma unroll
  for(int uv=0; uv<25; uv++) s += us2f(base[uv*HW]);
  P[idx] = s;
}

// ---------------- K2b: pool over (v,w) -> P_hu[c][u][h] ----------------
__global__ void k_pool_hu(const u16* __restrict__ t, float* __restrict__ P){
  int g = blockIdx.x*256 + threadIdx.x;
  int wid = g>>6, lane = g&63;                 // wid < 40960
  int c = wid/640, rem = wid - c*640;
  int u = rem>>7, h = rem&127;
  const u16* base = t + c*POS + u*5*HW + h*128;
  float s = 0.f;
  #pragma unroll
  for(int v=0;v<5;v++){ s += us2f(base[v*HW+lane]) + us2f(base[v*HW+lane+64]); }
  for(int off=32; off; off>>=1) s += __shfl_down(s, off);
  if(lane==0) P[wid] = s;
}

// ---------------- K2c: pool over (u,h) -> P_vw[c][v][w] (direct reduction) --------
__global__ void k_pool_vw(const u16* __restrict__ t, float* __restrict__ P){
  int bid = blockIdx.x;                        // 320 = 64*5
  int c = bid/5, v = bid - c*5;
  int w = threadIdx.x;                         // 128 threads
  float s = 0.f;
  for(int u=0;u<5;u++){
    const u16* base = t + c*POS + (u*5+v)*HW + w;
    for(int h=0;h<128;h++) s += us2f(base[h*128]);
  }
  P[(c*5+v)*128 + w] = s;
}

// ---------------- K2d: pool over (h,w) -> P_uv[c][u][v] ----------------
__global__ void k_pool_uv(const u16* __restrict__ t, float* __restrict__ P){
  int g = blockIdx.x*256 + threadIdx.x;
  int wid = g>>6, lane = g&63;                 // wid < 1600
  int c = wid/25, rem = wid - c*25;
  const u16* base = t + c*POS + rem*HW;
  float s = 0.f;
  #pragma unroll 8
  for(int k=0;k<256;k++) s += us2f(base[lane + k*64]);
  for(int off=32; off; off>>=1) s += __shfl_down(s, off);
  if(lane==0) P[wid] = s;
}

// ---------------- K3: MCA fused conv1 -> silu -> conv2 -> head conv -> fields ----------
__global__ __launch_bounds__(256,1) void k_mca(
    const float* __restrict__ Phw, const float* __restrict__ Phu,
    const float* __restrict__ Pvw, const float* __restrict__ Puv,
    const float* __restrict__ w1, const float* __restrict__ b1,
    const float* __restrict__ w2, const float* __restrict__ b2,
    const float* __restrict__ fw, const float* __restrict__ fb,
    float* __restrict__ F0, float* __restrict__ F1,
    float* __restrict__ F2, float* __restrict__ F3){
  __shared__ float W1s[4096], W2s[4096];
  for(int i=threadIdx.x;i<4096;i+=256){ W1s[i]=w1[i]; W2s[i]=w2[i]; }
  __syncthreads();
  int pos = blockIdx.x*256 + threadIdx.x;
  if(pos >= 133*133) return;
  int r = pos/133, cc = pos - r*133;

  float y1[64];
  #pragma unroll
  for(int o=0;o<64;o++) y1[o] = b1[o];
  for(int c=0;c<64;c++){
    float in;
    if(r<128){
      if(cc<128) in = Phw[(c<<14)+(r<<7)+cc]*(1.f/25.f);
      else       in = Phu[(c*5+(cc-128))*128 + r]*(1.f/640.f);
    } else {
      if(cc<128) in = Pvw[(c*5+(r-128))*128 + cc]*(1.f/640.f);
      else       in = Puv[c*25 + (cc-128)*5 + (r-128)]*(1.f/16384.f);
    }
    #pragma unroll
    for(int o=0;o<64;o++) y1[o] += W1s[o*64+c]*in;
  }
  float y2[64];
  #pragma unroll
  for(int o=0;o<64;o++) y2[o] = b2[o];
  for(int c=0;c<64;c++){
    float v = silu_f(y1[c]);
    #pragma unroll
    for(int o=0;o<64;o++) y2[o] += W2s[o*64+c]*v;
  }
  int hidx, idx0, stride_o; float* dst;
  if(r<128){
    if(cc<128){ hidx=0; dst=F0; idx0=(r<<7)+cc;            stride_o=16384; }
    else      { hidx=2; dst=F2; idx0=(cc-128)*128 + r;     stride_o=640;   }
  } else {
    if(cc<128){ hidx=3; dst=F3; idx0=(r-128)*128 + cc;     stride_o=640;   }
    else      { hidx=1; dst=F1; idx0=(cc-128)*5 + (r-128); stride_o=25;    }
  }
  const float* fwh = fw + hidx*4096;
  for(int o=0;o<64;o++){
    float f = fb[hidx*64+o];
    #pragma unroll
    for(int c=0;c<64;c++) f += fwh[o*64+c]*y2[c];
    dst[o*stride_o + idx0] = f;
  }
}

// ---------------- K5: attention bias gather -> Bt[h][key][query] ----------------
__global__ void k_bias(const int* __restrict__ rpi, const float* __restrict__ tab,
                       float* __restrict__ Bt){
  int idx = blockIdx.x*256 + threadIdx.x;      // < 4096, idx = i*64 + t (i=query)
  int i = idx>>6, tk = idx&63;
  int ri = rpi[idx];
  #pragma unroll
  for(int h=0;h<4;h++) Bt[h*4096 + tk*64 + i] = tab[ri*4+h];
}

// ---------------- K5b: pre-transpose qkv weights -> qkvT[(h*64+c)*48+dd] -------
__global__ void k_wt(const float* __restrict__ qkvw, float* __restrict__ qkvT){
  int i = blockIdx.x*256 + threadIdx.x;        // < 12288
  int h = i/3072, rem = i - h*3072;
  int c = rem/48, dd = rem - c*48;
  qkvT[i] = qkvw[(h*48+dd)*64 + c];
}

// ---------------- K4: x2 = x + LN1(x)*A  (fused-LN MCA combine, all fp32) -------
__global__ __launch_bounds__(256) void k_combine(
    const float* __restrict__ x,
    const float* __restrict__ n1w, const float* __restrict__ n1b,
    const float* __restrict__ F0, const float* __restrict__ F1,
    const float* __restrict__ F2, const float* __restrict__ F3,
    float* __restrict__ x2){
  int p = blockIdx.x*256 + threadIdx.x;        // < 409600
  float v[64]; float s=0.f, sq=0.f;
  #pragma unroll
  for(int c=0;c<64;c++){ float f = x[c*POS+p]; v[c]=f; s+=f; sq+=f*f; }
  float mu = s*(1.f/64.f);
  float r = rsqrtf(sq*(1.f/64.f) - mu*mu + 1e-5f);
  int uvi = p>>14, hw = p & 16383;
  int u = uvi/5, vv = uvi - 5*u;
  int h = hw>>7, w = hw & 127;
  #pragma unroll
  for(int c=0;c<64;c++){
    float t = (v[c]-mu)*r*n1w[c] + n1b[c];
    float A = F0[(c<<14)+hw] + F1[c*25+uvi] + F2[(c*5+u)*128+h] + F3[(c*5+vv)*128+w];
    x2[c*POS+p] = v[c] + t*A;
  }
}

// ---------------- K6: shifted window attention (fp32, in-kernel LN), += x2 ------
__global__ __launch_bounds__(256) void k_attn(
    const float* __restrict__ x,
    const float* __restrict__ n1w, const float* __restrict__ n1b,
    const float* __restrict__ qkvT, const float* __restrict__ qkvb,
    const float* __restrict__ projw, const float* __restrict__ projb,
    const float* __restrict__ Bt, float* __restrict__ x2){
  __shared__ float xws[64*68];                 // [tok][c] raw->normed, reused as ao
  __shared__ float kvu[8*64*16];               // [k/v][head][tok][d]
  __shared__ float ms[64], rs[64], wn[64], bn[64];
  int tid = threadIdx.x;
  int wid = blockIdx.x;
  int uv = wid>>8; int u = uv/5, v = uv - 5*u;
  int hb = (wid>>4)&15, wb = wid&15;
  const float* xbase = x + (u*5+v)*HW;

  if(tid<64){ wn[tid] = n1w[tid]; bn[tid] = n1b[tid]; }
  // stage raw x window (roll +4,+4 applied at gather)
  #pragma unroll
  for(int k2=0;k2<16;k2++){
    int lin = k2*256 + tid;
    int c = lin>>6, tok = lin&63;
    int ti = tok>>3, tj = tok&7;
    int hs = (hb*8+ti-4)&127, ws2 = (wb*8+tj-4)&127;
    xws[tok*68+c] = xbase[c*POS + hs*128 + ws2];
  }
  __syncthreads();
  // per-token LN stats
  if(tid<64){
    float s=0.f, sq=0.f;
    #pragma unroll
    for(int c=0;c<64;c++){ float f = xws[tid*68+c]; s+=f; sq+=f*f; }
    float mu = s*(1.f/64.f);
    ms[tid] = mu;
    rs[tid] = rsqrtf(sq*(1.f/64.f) - mu*mu + 1e-5f);
  }
  __syncthreads();
  // normalize in place
  #pragma unroll
  for(int k2=0;k2<16;k2++){
    int lin = k2*256 + tid;
    int c = lin>>6, tok = lin&63;
    xws[tok*68+c] = (xws[tok*68+c]-ms[tok])*rs[tok]*wn[c] + bn[c];
  }
  __syncthreads();                             // sync: tokens ready

  int h = tid>>6, lane = tid&63;               // head, token
  int hu_ = __builtin_amdgcn_readfirstlane(h); // wave-uniform head for weights
  float A[48];
  #pragma unroll
  for(int j=0;j<48;j++) A[j] = qkvb[hu_*48+j];
  const float* wT = qkvT + hu_*3072;           // [(c)*48+dd]
  for(int c=0;c<64;c++){
    float xc = xws[lane*68+c];
    const float* wr = wT + c*48;               // wave-uniform, cached
    #pragma unroll
    for(int j=0;j<48;j++) A[j] += xc*wr[j];
  }
  float q[16];
  #pragma unroll
  for(int d=0;d<16;d++) q[d] = A[d];
  #pragma unroll
  for(int d=0;d<16;d++){
    kvu[(h*64+lane)*16 + d]     = A[16+d];     // k
    kvu[((4+h)*64+lane)*16 + d] = A[32+d];     // v
  }
  __syncthreads();                             // kv ready; xws input no longer needed

  // scores + softmax (query = lane)
  float s[64]; float mx = -1e30f;
  #pragma unroll
  for(int tk=0;tk<64;tk++){
    const float4* kp = (const float4*)&kvu[(h*64+tk)*16];
    float a = 0.f;
    #pragma unroll
    for(int g4=0; g4<4; g4++){
      float4 kk = kp[g4];
      a += q[g4*4+0]*kk.x + q[g4*4+1]*kk.y + q[g4*4+2]*kk.z + q[g4*4+3]*kk.w;
    }
    a = a*0.25f + Bt[h*4096 + tk*64 + lane];
    s[tk] = a; mx = fmaxf(mx, a);
  }
  float l = 0.f;
  #pragma unroll
  for(int tk=0;tk<64;tk++){ float e = __expf(s[tk]-mx); s[tk]=e; l+=e; }
  float inv = 1.f/l;
  float o[16];
  #pragma unroll
  for(int d=0;d<16;d++) o[d] = 0.f;
  #pragma unroll
  for(int tk=0;tk<64;tk++){
    const float4* vp = (const float4*)&kvu[((4+h)*64+tk)*16];
    float pp = s[tk];
    #pragma unroll
    for(int g4=0; g4<4; g4++){
      float4 vv4 = vp[g4];
      o[g4*4+0] += pp*vv4.x; o[g4*4+1] += pp*vv4.y;
      o[g4*4+2] += pp*vv4.z; o[g4*4+3] += pp*vv4.w;
    }
  }
  #pragma unroll
  for(int d=0;d<16;d++) xws[lane*68 + h*16+d] = o[d]*inv;   // ao (c = h*16+d)
  __syncthreads();                             // ao ready

  // projection + scatter-add into x2 (inverse roll at write)
  int tok = tid&63, cg = tid>>6;
  int cgs = __builtin_amdgcn_readfirstlane(cg);
  float xin2[64];
  #pragma unroll
  for(int k2=0;k2<64;k2++) xin2[k2] = xws[tok*68+k2];
  int ti = tok>>3, tj = tok&7;
  int hf = (hb*8+ti-4)&127, wf_ = (wb*8+tj-4)&127;
  float* xb = x2 + (u*5+v)*HW + hf*128 + wf_;
  for(int cq=0;cq<16;cq++){
    int c = cgs*16+cq;
    float a = projb[c];
    const float* pw = projw + c*64;            // wave-uniform rows, cached
    #pragma unroll
    for(int k2=0;k2<64;k2++) a += xin2[k2]*pw[k2];
    xb[c*POS] += a;
  }
}

// ---------------- K9: pre-fragment mbconv weights for MFMA (hi/lo split bf16) ----
// w1f: 64 frags (t<16 N-tile, h<2 K-half, s<2 split), frag = (t*2+h)*2+s.
//      lane l, elem e: value split_s(w1[o][c]), o = t*16+(l&15), c = h*32+8*(l>>4)+e.
// w2f: 64 frags (q<4 K-chunk, h<2, s<2, t<4 N-tile), frag = ((q*2+h)*2+s)*4+t.
//      lane l, elem e: value split_s(w2[outc][oc]), outc = t*16+(l&15),
//      oc = q*64+h*32+8*(l>>4)+e.
// Layout: frag*512 + l*8 + e (u16), so a lane's frag is one dwordx4 load.
__global__ void k_wfrag(const float* __restrict__ w1, const float* __restrict__ w2,
                        u16* __restrict__ w1f, u16* __restrict__ w2f){
  int g = blockIdx.x*256 + threadIdx.x;        // < 65536
  int table = g >> 15;
  int rem = g & 32767;
  int f = rem >> 9, i = rem & 511;
  int l = i >> 3, e = i & 7;
  int l15 = l & 15, lg = l >> 4;
  if(table==0){
    int t = f >> 2, h = (f>>1)&1, s = f&1;
    int o = t*16 + l15, c = h*32 + lg*8 + e;
    float w = w1[o*64 + c];
    u16 hi = f2us(w);
    w1f[f*512 + i] = (s==0) ? hi : f2us(w - us2f(hi));
  } else {
    int t = f & 3, g2 = f >> 2;
    int s = g2 & 1, h = (g2>>1)&1, q = g2>>2;
    int oc = q*64 + h*32 + lg*8 + e, outc = t*16 + l15;
    float w = w2[outc*256 + oc];
    u16 hi = f2us(w);
    w2f[f*512 + i] = (s==0) ? hi : f2us(w - us2f(hi));
  }
}

// ---------------- K8 v5: fused MBConv on matrix cores (layout-fixed) ----------------
// v4 lesson (round 2, absmax 0.176): mbconv's reshape is a FLAT PLANE regrouping —
// batch n = planes [n*64, n*64+64) of the [c][uv] plane sequence, crossing uv
// boundaries. So t2 must stay plane-major [plane][HW] (old verified layout) and the
// halo staging transposes plane-major global -> pixel-major LDS here.
// Compute engine (v4, unchanged): 1x1 convs on mfma_f32_16x16x32_bf16 with
// split-precision weights (hi+lo bf16), depthwise 5x5 on fp32 VALU.
//   expand:  A = t2 (bf16), B = w1_hi + w1_lo  (2 MFMA per K-half)
//   project: A = y2_hi/lo, B = w2_hi/lo, D += AhBh + AhBl + AlBh
#define LN_T2 72   // t2s row stride (u16)
#define LN_Y1 68   // y1s row stride (u16)
#define LN_Y2 72   // y2h/y2l row stride (u16)
__global__ __launch_bounds__(256,2) void k_mbconv(
    const u16* __restrict__ t2, const float* x2,
    const u16* __restrict__ w1f, const float* __restrict__ b1,
    const float* __restrict__ dwg, const float* __restrict__ db,
    const u16* __restrict__ w2f, const float* __restrict__ b2,
    float* out){
  __shared__ __align__(16) u16 t2s[144*LN_T2];   // 12x12 halo x 64ch   20736B
  __shared__ __align__(16) u16 y1s[144*LN_Y1];   // chunk expand+silu   19584B
  __shared__ __align__(16) u16 y2h[64*LN_Y2];    // dw out hi            9216B
  __shared__ __align__(16) u16 y2l[64*LN_Y2];    // dw out lo            9216B
  __shared__ float dws[64*25];                   // dw weights chunk     6400B
  int tid = threadIdx.x;
  int lane = tid & 63, wv = tid >> 6;
  int l15 = lane & 15, lg = lane >> 4;
  int n = blockIdx.x >> 8, tile = blockIdx.x & 255;   // 25 groups x 256 tiles
  int h0 = (tile>>4)<<3, w0 = (tile&15)<<3;

  // ---- stage t2 halo: plane-major global -> pixel-major bf16 LDS tile ----
  // planes n*64+c (c = reshaped channel), pixel pairs as aligned u32 (ww even).
  {
    const u16* tb = t2 + (size_t)n*64*HW;
    for(int L=tid; L<4608; L+=256){
      int c = L/72, j = L - c*72;
      int rr = j/6, k2 = j - rr*6;
      int pc = k2*2;
      int hh = h0-2+rr, ww = w0-2+pc;
      u32 val = 0;
      if((unsigned)hh<128u){
        const u16* rowp = tb + c*HW + hh*128;
        if((unsigned)ww<127u) val = *(const u32*)(rowp + ww);     // both pixels in
        else {
          u32 lo = ((unsigned)ww    <128u) ? rowp[ww]   : 0;
          u32 hi = ((unsigned)(ww+1)<128u) ? rowp[ww+1] : 0;
          val = lo | (hi<<16);
        }
      }
      int p = rr*12 + pc;
      t2s[p*LN_T2 + c]      = (u16)val;
      t2s[(p+1)*LN_T2 + c]  = (u16)(val>>16);
    }
  }
  f32x4 accP[4];
  #pragma unroll
  for(int m=0;m<4;m++) accP[m] = (f32x4){0.f,0.f,0.f,0.f};
  __syncthreads();

  for(int q=0;q<4;q++){                        // 4 chunks of 64 expanded channels
    // stage this chunk's depthwise weights (read after next barrier)
    for(int i=tid;i<1600;i+=256) dws[i] = dwg[q*1600 + i];

    // ---- expand 1x1 (MFMA): y1s[pos][oc_local] = pad ? 0 : silu(t2.w1 + b1) ----
    {
      int t_g = q*4 + wv;                      // global N-tile, this wave's 16 oc
      float b1v = b1[t_g*16 + l15];
      const uint4* wf = (const uint4*)w1f;
      s16x8 b00 = as_s8(wf[((t_g*2+0)*2+0)*64 + lane]);   // h=0 hi
      s16x8 b01 = as_s8(wf[((t_g*2+0)*2+1)*64 + lane]);   // h=0 lo
      s16x8 b10 = as_s8(wf[((t_g*2+1)*2+0)*64 + lane]);   // h=1 hi
      s16x8 b11 = as_s8(wf[((t_g*2+1)*2+1)*64 + lane]);   // h=1 lo
      int colw = wv*16 + l15;
      #pragma unroll
      for(int m=0;m<9;m++){
        s16x8 a0 = *(const s16x8*)(t2s + (m*16+l15)*LN_T2 + lg*8);
        s16x8 a1 = *(const s16x8*)(t2s + (m*16+l15)*LN_T2 + 32 + lg*8);
        f32x4 acc = (f32x4){b1v,b1v,b1v,b1v};
        acc = mfma16(a0, b00, acc);
        acc = mfma16(a0, b01, acc);
        acc = mfma16(a1, b10, acc);
        acc = mfma16(a1, b11, acc);
        #pragma unroll
        for(int r=0;r<4;r++){
          int pos = m*16 + lg*4 + r;           // D row = 4*(l>>4)+r
          int rr = pos/12, pc = pos - rr*12;
          int hh = h0-2+rr, ww = w0-2+pc;
          bool in = ((unsigned)hh<128u)&&((unsigned)ww<128u);
          y1s[pos*LN_Y1 + colw] = in ? f2us(silu_f(acc[r])) : (u16)0;
        }
      }
    }
    __syncthreads();                           // y1s + dws ready

    // ---- depthwise 5x5 + silu (fp32 VALU), split hi/lo bf16 -> y2h/y2l ----
    {
      float wreg[25];
      #pragma unroll
      for(int k=0;k<25;k++) wreg[k] = dws[lane*25+k];
      float dbv = db[q*64+lane];
      #pragma unroll
      for(int pp=0;pp<16;pp++){
        int pix = wv*16 + pp;
        int r = pix>>3, cc = pix&7;
        float s = 0.f;
        #pragma unroll
        for(int kh=0;kh<5;kh++)
          #pragma unroll
          for(int kw=0;kw<5;kw++)
            s += us2f(y1s[((r+kh)*12 + cc+kw)*LN_Y1 + lane]) * wreg[kh*5+kw];
        float y2 = silu_f(s + dbv);
        u16 hi = f2us(y2);
        y2h[pix*LN_Y2 + lane] = hi;
        y2l[pix*LN_Y2 + lane] = f2us(y2 - us2f(hi));
      }
    }
    __syncthreads();                           // y2 ready

    // ---- project 1x1 (MFMA) accumulate: D[pix][outc] += y2 . w2 ----
    {
      const uint4* wf = (const uint4*)w2f;
      s16x8 bh0 = as_s8(wf[(((q*2+0)*2+0)*4 + wv)*64 + lane]);
      s16x8 bl0 = as_s8(wf[(((q*2+0)*2+1)*4 + wv)*64 + lane]);
      s16x8 bh1 = as_s8(wf[(((q*2+1)*2+0)*4 + wv)*64 + lane]);
      s16x8 bl1 = as_s8(wf[(((q*2+1)*2+1)*4 + wv)*64 + lane]);
      #pragma unroll
      for(int m=0;m<4;m++){
        s16x8 ah0 = *(const s16x8*)(y2h + (m*16+l15)*LN_Y2 + lg*8);
        s16x8 al0 = *(const s16x8*)(y2l + (m*16+l15)*LN_Y2 + lg*8);
        s16x8 ah1 = *(const s16x8*)(y2h + (m*16+l15)*LN_Y2 + 32 + lg*8);
        s16x8 al1 = *(const s16x8*)(y2l + (m*16+l15)*LN_Y2 + 32 + lg*8);
        f32x4 acc = accP[m];
        acc = mfma16(ah0, bh0, acc);
        acc = mfma16(ah0, bl0, acc);
        acc = mfma16(al0, bh0, acc);
        acc = mfma16(ah1, bh1, acc);
        acc = mfma16(ah1, bl1, acc);
        acc = mfma16(al1, bh1, acc);
        accP[m] = acc;
      }
    }
    __syncthreads();                           // before next chunk reuses y1s/y2/dws
  }

  // ---- epilogue: out = accP + b2 + x2 (unique-writer RMW, in-place d_out) ----
  int outc = wv*16 + l15;
  float b2v = b2[outc];
  float*       ob = out + (size_t)(n*64+outc)*HW;
  const float* xb = x2  + (size_t)(n*64+outc)*HW;
  #pragma unroll
  for(int m=0;m<4;m++){
    #pragma unroll
    for(int r=0;r<4;r++){
      int pix = m*16 + lg*4 + r;
      int rr = pix>>3, cc = pix&7;
      int g = (h0+rr)*128 + (w0+cc);
      ob[g] = accP[m][r] + b2v + xb[g];
    }
  }
}

// ---------------- workspace layout (bytes), total 61,600,256 ----------------
static const size_t OFF_T   = 0;             // u16  t / t2 (reused)   52,428,800
static const size_t OFF_PHW = 52428800;      // f32  pool hw            4,194,304
static const size_t OFF_PHU = 56623104;      // f32  pool hu              163,840
static const size_t OFF_PVW = 56786944;      // f32  pool vw              163,840
static const size_t OFF_PUV = 56950784;      // f32  pool uv                6,400
static const size_t OFF_F0  = 56957184;      // f32  field hw           4,194,304
static const size_t OFF_F2  = 61151488;      // f32  field uh             163,840
static const size_t OFF_F3  = 61315328;      // f32  field vw             163,840
static const size_t OFF_F1  = 61479168;      // f32  field uv               6,400
static const size_t OFF_BT  = 61485568;      // f32  attn bias             65,536
static const size_t OFF_QT  = 61551104;      // f32  qkvT                  49,152
// w1f/w2f (64KB each) alias onto the Phw region, which is dead after k_mca;
// k_wfrag runs after k_attn, before k_mbconv. Zero workspace growth.
static const size_t OFF_W1F = 52428800;      // u16  w1 MFMA frags         65,536
static const size_t OFF_W2F = 52494336;      // u16  w2 MFMA frags         65,536

extern "C" void kernel_launch(void* const* d_in, const int* in_sizes, int n_in,
                              void* d_out, int out_size, void* d_ws, size_t ws_size,
                              hipStream_t stream){
  (void)in_sizes; (void)n_in; (void)out_size; (void)ws_size;
  const float* x     = (const float*)d_in[0];
  const float* n1w   = (const float*)d_in[1];
  const float* n1b   = (const float*)d_in[2];
  const float* n2w   = (const float*)d_in[3];
  const float* n2b   = (const float*)d_in[4];
  const float* qkvw  = (const float*)d_in[5];
  const float* qkvb  = (const float*)d_in[6];
  const float* projw = (const float*)d_in[7];
  const float* projb = (const float*)d_in[8];
  const float* rpbt  = (const float*)d_in[9];
  const int*   rpi   = (const int*)d_in[10];
  const float* mw1   = (const float*)d_in[11];
  const float* mb1   = (const float*)d_in[12];
  const float* mw2   = (const float*)d_in[13];
  const float* mb2   = (const float*)d_in[14];
  const float* mfw   = (const float*)d_in[15];
  const float* mfb   = (const float*)d_in[16];
  const float* bw1   = (const float*)d_in[17];
  const float* bb1   = (const float*)d_in[18];
  const float* bdw   = (const float*)d_in[19];
  const float* bdb   = (const float*)d_in[20];
  const float* bw2   = (const float*)d_in[21];
  const float* bb2   = (const float*)d_in[22];

  char* ws = (char*)d_ws;
  u16*   t   = (u16*)  (ws + OFF_T);
  float* Phw = (float*)(ws + OFF_PHW);
  float* Phu = (float*)(ws + OFF_PHU);
  float* Pvw = (float*)(ws + OFF_PVW);
  float* Puv = (float*)(ws + OFF_PUV);
  float* F0  = (float*)(ws + OFF_F0);
  float* F1  = (float*)(ws + OFF_F1);
  float* F2  = (float*)(ws + OFF_F2);
  float* F3  = (float*)(ws + OFF_F3);
  float* Bt  = (float*)(ws + OFF_BT);
  float* qT  = (float*)(ws + OFF_QT);
  u16*   w1f = (u16*)  (ws + OFF_W1F);
  u16*   w2f = (u16*)  (ws + OFF_W2F);
  float* x2  = (float*)d_out;    // f32 residual accumulator lives in d_out
  float* outp= (float*)d_out;

  // 1) t = LN1(x) (bf16 channel-major, pool consumption only)
  k_ln1<<<1600,256,0,stream>>>(x, n1w, n1b, t);
  // 2) pools of t
  k_pool_hw<<<4096,256,0,stream>>>(t, Phw);
  k_pool_hu<<<10240,256,0,stream>>>(t, Phu);
  k_pool_vw<<<320,128,0,stream>>>(t, Pvw);
  k_pool_uv<<<400,256,0,stream>>>(t, Puv);
  // 3) MCA convs -> gate fields
  k_mca<<<70,256,0,stream>>>(Phw,Phu,Pvw,Puv, mw1,mb1,mw2,mb2, mfw,mfb, F0,F1,F2,F3);
  // 4) attention bias table + qkv weight transpose
  k_bias<<<16,256,0,stream>>>(rpi, rpbt, Bt);
  k_wt<<<48,256,0,stream>>>(qkvw, qT);
  // 5) x2 = x + LN1(x)*A  (fused LN, pure write of all of d_out)
  k_combine<<<1600,256,0,stream>>>(x, n1w, n1b, F0,F1,F2,F3, x2);
  // 6) x2 += window_attn(LN1(x))  (fp32, in-kernel LN; unique-writer RMW)
  k_attn<<<6400,256,0,stream>>>(x, n1w, n1b, qT, qkvb, projw, projb, Bt, x2);
  // 7) pre-fragment mbconv weights (Phw region now dead)
  k_wfrag<<<256,256,0,stream>>>(bw1, bw2, w1f, w2f);
  // 8) t2 = LN2(x2), plane-major bf16 (t buffer reused; verified mbconv layout)
  k_ln2<<<1600,256,0,stream>>>(x2, n2w, n2b, t);
  // 9) out = x2 + mbconv(t2)  (MFMA v5, in-place on d_out)
  k_mbconv<<<6400,256,0,stream>>>(t, x2, w1f, bb1, bdw, bdb, w2f, bb2, outp);
}

// Round 4
// 1440.018 us; speedup vs baseline: 1.9506x; 1.3845x over previous
//
#include <hip/hip_runtime.h>

// ---------------- problem constants ----------------
#define C_   64
#define U_   5
#define V_   5
#define H_   128
#define W_   128
#define NH_  4
#define HD_  16
#define WSZ  8
#define S_   64        // tokens per window
#define HW   16384     // H*W
#define UV   25        // U*V
#define POS  409600    // UV*HW, per-channel spatial size
#define TOT  26214400  // C_*POS
#define C4_  256

typedef unsigned short u16;
typedef unsigned int   u32;
typedef __attribute__((ext_vector_type(8))) short s16x8;   // 8 bf16 (4 VGPR)
typedef __attribute__((ext_vector_type(4))) float f32x4;   // MFMA acc

// bf16 <-> fp32 helpers (raw bit manipulation, round-to-nearest-even)
__device__ __forceinline__ float us2f(u16 h){ return __uint_as_float(((u32)h)<<16); }
__device__ __forceinline__ u16 f2us(float f){
  u32 u = __float_as_uint(f);
  return (u16)((u + 0x7fffu + ((u>>16)&1u))>>16);
}
__device__ __forceinline__ float silu_f(float x){ return x/(1.f+__expf(-x)); }
__device__ __forceinline__ s16x8 as_s8(uint4 u){ return __builtin_bit_cast(s16x8, u); }
__device__ __forceinline__ f32x4 mfma16(s16x8 a, s16x8 b, f32x4 c){
  return __builtin_amdgcn_mfma_f32_16x16x32_bf16(a, b, c, 0, 0, 0);
}

// ---------------- K1: LayerNorm over C (norm1) : x(f32) -> t(bf16) ----
// t is consumed by the pools AND (round 4) as the bf16 input to MFMA attention.
__global__ __launch_bounds__(256,2) void k_ln1(const float* __restrict__ x,
                                               const float* __restrict__ w,
                                               const float* __restrict__ b,
                                               u16* __restrict__ t){
  int p = blockIdx.x*256 + threadIdx.x;        // 0..409599
  float v[64]; float s=0.f, sq=0.f;
  #pragma unroll
  for(int c=0;c<64;c++){ float f = x[c*POS+p]; v[c]=f; s+=f; sq+=f*f; }
  float mu = s*(1.f/64.f);
  float var = sq*(1.f/64.f) - mu*mu;
  float r = rsqrtf(var + 1e-5f);
  #pragma unroll
  for(int c=0;c<64;c++){
    t[c*POS+p] = f2us((v[c]-mu)*r*w[c] + b[c]);
  }
}

// ---------------- K7: LayerNorm over C (norm2) : x2(f32) -> t2(bf16, plane-major) ----
// Plane-major [c*25+uv][hw] — REQUIRED: mbconv's reshape(B*U*V,C,H,W) is a flat
// plane regrouping (batch n uses planes [n*64, n*64+64)), which crosses uv
// boundaries (round-2 lesson).
__global__ __launch_bounds__(256,2) void k_ln2(const float* __restrict__ x2,
                                               const float* __restrict__ w,
                                               const float* __restrict__ b,
                                               u16* __restrict__ t2){
  int p = blockIdx.x*256 + threadIdx.x;
  float v[64]; float s=0.f, sq=0.f;
  #pragma unroll
  for(int c=0;c<64;c++){ float f = x2[c*POS+p]; v[c]=f; s+=f; sq+=f*f; }
  float mu = s*(1.f/64.f);
  float r = rsqrtf(sq*(1.f/64.f) - mu*mu + 1e-5f);
  #pragma unroll
  for(int c=0;c<64;c++){
    t2[c*POS+p] = f2us((v[c]-mu)*r*w[c] + b[c]);
  }
}

// ---------------- K2a: pool over (u,v) -> P_hw[c][h][w] (raw sums) ----------------
__global__ void k_pool_hw(const u16* __restrict__ t, float* __restrict__ P){
  int idx = blockIdx.x*256 + threadIdx.x;      // < 64*16384
  int c = idx>>14, hw = idx & 16383;
  const u16* base = t + c*POS + hw;
  float s = 0.f;
  #pragma unroll
  for(int uv=0; uv<25; uv++) s += us2f(base[uv*HW]);
  P[idx] = s;
}

// ---------------- K2b: pool over (v,w) -> P_hu[c][u][h] ----------------
__global__ void k_pool_hu(const u16* __restrict__ t, float* __restrict__ P){
  int g = blockIdx.x*256 + threadIdx.x;
  int wid = g>>6, lane = g&63;                 // wid < 40960
  int c = wid/640, rem = wid - c*640;
  int u = rem>>7, h = rem&127;
  const u16* base = t + c*POS + u*5*HW + h*128;
  float s = 0.f;
  #pragma unroll
  for(int v=0;v<5;v++){ s += us2f(base[v*HW+lane]) + us2f(base[v*HW+lane+64]); }
  for(int off=32; off; off>>=1) s += __shfl_down(s, off);
  if(lane==0) P[wid] = s;
}

// ---------------- K2c: pool over (u,h) -> P_vw[c][v][w] (direct reduction) --------
__global__ void k_pool_vw(const u16* __restrict__ t, float* __restrict__ P){
  int bid = blockIdx.x;                        // 320 = 64*5
  int c = bid/5, v = bid - c*5;
  int w = threadIdx.x;                         // 128 threads
  float s = 0.f;
  for(int u=0;u<5;u++){
    const u16* base = t + c*POS + (u*5+v)*HW + w;
    for(int h=0;h<128;h++) s += us2f(base[h*128]);
  }
  P[(c*5+v)*128 + w] = s;
}

// ---------------- K2d: pool over (h,w) -> P_uv[c][u][v] ----------------
__global__ void k_pool_uv(const u16* __restrict__ t, float* __restrict__ P){
  int g = blockIdx.x*256 + threadIdx.x;
  int wid = g>>6, lane = g&63;                 // wid < 1600
  int c = wid/25, rem = wid - c*25;
  const u16* base = t + c*POS + rem*HW;
  float s = 0.f;
  #pragma unroll 8
  for(int k=0;k<256;k++) s += us2f(base[lane + k*64]);
  for(int off=32; off; off>>=1) s += __shfl_down(s, off);
  if(lane==0) P[wid] = s;
}

// ---------------- K3: MCA fused conv1 -> silu -> conv2 -> head conv -> fields ----------
__global__ __launch_bounds__(256,1) void k_mca(
    const float* __restrict__ Phw, const float* __restrict__ Phu,
    const float* __restrict__ Pvw, const float* __restrict__ Puv,
    const float* __restrict__ w1, const float* __restrict__ b1,
    const float* __restrict__ w2, const float* __restrict__ b2,
    const float* __restrict__ fw, const float* __restrict__ fb,
    float* __restrict__ F0, float* __restrict__ F1,
    float* __restrict__ F2, float* __restrict__ F3){
  __shared__ float W1s[4096], W2s[4096];
  for(int i=threadIdx.x;i<4096;i+=256){ W1s[i]=w1[i]; W2s[i]=w2[i]; }
  __syncthreads();
  int pos = blockIdx.x*256 + threadIdx.x;
  if(pos >= 133*133) return;
  int r = pos/133, cc = pos - r*133;

  float y1[64];
  #pragma unroll
  for(int o=0;o<64;o++) y1[o] = b1[o];
  for(int c=0;c<64;c++){
    float in;
    if(r<128){
      if(cc<128) in = Phw[(c<<14)+(r<<7)+cc]*(1.f/25.f);
      else       in = Phu[(c*5+(cc-128))*128 + r]*(1.f/640.f);
    } else {
      if(cc<128) in = Pvw[(c*5+(r-128))*128 + cc]*(1.f/640.f);
      else       in = Puv[c*25 + (cc-128)*5 + (r-128)]*(1.f/16384.f);
    }
    #pragma unroll
    for(int o=0;o<64;o++) y1[o] += W1s[o*64+c]*in;
  }
  float y2[64];
  #pragma unroll
  for(int o=0;o<64;o++) y2[o] = b2[o];
  for(int c=0;c<64;c++){
    float v = silu_f(y1[c]);
    #pragma unroll
    for(int o=0;o<64;o++) y2[o] += W2s[o*64+c]*v;
  }
  int hidx, idx0, stride_o; float* dst;
  if(r<128){
    if(cc<128){ hidx=0; dst=F0; idx0=(r<<7)+cc;            stride_o=16384; }
    else      { hidx=2; dst=F2; idx0=(cc-128)*128 + r;     stride_o=640;   }
  } else {
    if(cc<128){ hidx=3; dst=F3; idx0=(r-128)*128 + cc;     stride_o=640;   }
    else      { hidx=1; dst=F1; idx0=(cc-128)*5 + (r-128); stride_o=25;    }
  }
  const float* fwh = fw + hidx*4096;
  for(int o=0;o<64;o++){
    float f = fb[hidx*64+o];
    #pragma unroll
    for(int c=0;c<64;c++) f += fwh[o*64+c]*y2[c];
    dst[o*stride_o + idx0] = f;
  }
}

// ---------------- K5: attention bias gather -> Bt[h][query][key] (round-4 layout) ----
__global__ void k_bias(const int* __restrict__ rpi, const float* __restrict__ tab,
                       float* __restrict__ Bt){
  int idx = blockIdx.x*256 + threadIdx.x;      // < 4096, idx = i*64 + tk (i=query)
  int ri = rpi[idx];
  #pragma unroll
  for(int h=0;h<4;h++) Bt[h*4096 + idx] = tab[ri*4+h];
}

// ---------------- K5b: pre-fragment qkv + proj weights (hi/lo split bf16) ----
// Same verified B-frag recipe as mbconv's w1f: frag f=(t*2+h)*2+s, lane l elem e:
// W[n = t*16+(l&15)][k = h*32 + 8*(l>>4) + e].  qkvw: 12 N-tiles (48 frags),
// projw: 4 N-tiles (16 frags). Layout frag*512 + l*8 + e (u16).
__global__ void k_wt(const float* __restrict__ qkvw, const float* __restrict__ projw,
                     u16* __restrict__ qf, u16* __restrict__ pjf){
  int g = blockIdx.x*256 + threadIdx.x;        // < 32768
  int g2 = (g < 24576) ? g : (g - 24576);
  int f = g2 >> 9, i = g2 & 511;
  int l = i >> 3, e = i & 7;
  int l15 = l & 15, lgv = l >> 4;
  int s = f & 1, h = (f>>1) & 1, tt = f >> 2;
  int n = tt*16 + l15, k = h*32 + lgv*8 + e;
  if(g < 24576){
    float w = qkvw[n*64 + k];
    u16 hi = f2us(w);
    qf[f*512 + i] = (s==0) ? hi : f2us(w - us2f(hi));
  } else {
    float w = projw[n*64 + k];
    u16 hi = f2us(w);
    pjf[f*512 + i] = (s==0) ? hi : f2us(w - us2f(hi));
  }
}

// ---------------- K4: x2 = x + LN1(x)*A  (fused-LN MCA combine, all fp32) -------
__global__ __launch_bounds__(256) void k_combine(
    const float* __restrict__ x,
    const float* __restrict__ n1w, const float* __restrict__ n1b,
    const float* __restrict__ F0, const float* __restrict__ F1,
    const float* __restrict__ F2, const float* __restrict__ F3,
    float* __restrict__ x2){
  int p = blockIdx.x*256 + threadIdx.x;        // < 409600
  float v[64]; float s=0.f, sq=0.f;
  #pragma unroll
  for(int c=0;c<64;c++){ float f = x[c*POS+p]; v[c]=f; s+=f; sq+=f*f; }
  float mu = s*(1.f/64.f);
  float r = rsqrtf(sq*(1.f/64.f) - mu*mu + 1e-5f);
  int uvi = p>>14, hw = p & 16383;
  int u = uvi/5, vv = uvi - 5*u;
  int h = hw>>7, w = hw & 127;
  #pragma unroll
  for(int c=0;c<64;c++){
    float t = (v[c]-mu)*r*n1w[c] + n1b[c];
    float A = F0[(c<<14)+hw] + F1[c*25+uvi] + F2[(c*5+u)*128+h] + F3[(c*5+vv)*128+w];
    x2[c*POS+p] = v[c] + t*A;
  }
}

// ---------------- K6 v2: shifted window attention on MATRIX CORES, += x2 --------
// Round-3 profile: 734us, MfmaUtil=0, VALUBusy=34%, Occ=21% -> latency-bound fp32
// VALU matmuls (~20 GFLOP). All 4 matmuls (qkv K=64, scores K=16pad32, PV K=64,
// proj K=64) now on mfma_f32_16x16x32_bf16. Input = t (bf16 LN1(x), already
// computed for pools) -> no in-kernel LN, gather bytes halved.
// Wave w owns head w end-to-end (qkv N-tiles 3w..3w+2, scores, softmax, PV) and
// out-channel tile w of proj -> q/k/vt/P wave-private, 4 barriers total.
// Scores trick: K=32 MFMA with kS zero-padded d16..31; A-side garbage reads
// (q stride 16) are annihilated by B-side zeros.
// LDS overlay (peak 45KB -> 3 blocks/CU):
//   [0,9216)      xbn [64][72]        -> P[0..]   -> ao (post-PV)
//   [9216,17408)  qS  [4][64][16]     -> P        -> projS fp32 [64][69]
//   [17408,33792) kS  [4][64][32]     -> P (ends 36864)
//   [36864,46080) vt  [4][16][72]
__global__ __launch_bounds__(256,3) void k_attn(
    const u16* __restrict__ t,
    const u16* __restrict__ qf, const float* __restrict__ qkvb,
    const u16* __restrict__ pjf, const float* __restrict__ projb,
    const float* __restrict__ Bt, float* __restrict__ x2){
  __shared__ __align__(16) char smem[46080];
  u16*   xbn = (u16*)smem;                 // [64][72]
  u16*   qS  = (u16*)(smem + 9216);        // [4][64][16]
  u16*   kS  = (u16*)(smem + 17408);       // [4][64][32]
  u16*   P   = (u16*)smem;                 // [4][64][72] overlay
  u16*   vt  = (u16*)(smem + 36864);       // [4][16][72]
  u16*   ao  = (u16*)smem;                 // [64][72] overlay (post-PV)
  float* pS  = (float*)(smem + 9216);      // [64][69] overlay (proj out)

  int tid = threadIdx.x;
  int lane = tid & 63, wv = tid >> 6;
  int l15 = lane & 15, lg = lane >> 4;
  int bid = blockIdx.x;
  int wid = (bid & 7)*800 + (bid >> 3);    // XCD swizzle (6400 = 8*800, bijective)
  int uv = wid >> 8; int u = uv/5, v = uv - 5*u;
  int hb = (wid>>4) & 15, wb = wid & 15;
  const u16* tb = t + (u*5+v)*HW;

  // zero kS (provides the d16..31 zeros for the K=32 scores MFMA)
  {
    u32* kz = (u32*)kS;
    #pragma unroll
    for(int i=0;i<16;i++) kz[tid + i*256] = 0;
  }
  // gather t window (roll +4,+4), 4-token quads are contiguous (shift=4 even)
  #pragma unroll
  for(int it=0; it<4; it++){
    int item = it*256 + tid;               // 1024 = 64 c x 16 quads
    int c = item >> 4, qd = item & 15;
    int ti = qd >> 1, tjq = (qd & 1) * 4;
    int hs = (hb*8 + ti - 4) & 127;
    int wsb = (wb*8 + tjq - 4) & 127;
    ushort4 vals = *(const ushort4*)(tb + c*POS + hs*128 + wsb);
    int tok = ti*8 + tjq;
    xbn[(tok  )*72 + c] = vals.x;
    xbn[(tok+1)*72 + c] = vals.y;
    xbn[(tok+2)*72 + c] = vals.z;
    xbn[(tok+3)*72 + c] = vals.w;
  }
  __syncthreads();                         // B1: xbn + kS zeros ready

  // ---- qkv (MFMA): wave w -> head w's q,k,v ----
  {
    s16x8 Af[4][2];
    #pragma unroll
    for(int mt=0;mt<4;mt++)
      #pragma unroll
      for(int ks=0;ks<2;ks++)
        Af[mt][ks] = *(const s16x8*)(xbn + (mt*16+l15)*72 + ks*32 + lg*8);
    const uint4* wf = (const uint4*)qf;
    #pragma unroll
    for(int nt=0; nt<3; nt++){
      int tgl = wv*3 + nt;
      float bv = qkvb[tgl*16 + l15];
      s16x8 B00 = as_s8(wf[((tgl*2+0)*2+0)*64 + lane]);
      s16x8 B01 = as_s8(wf[((tgl*2+0)*2+1)*64 + lane]);
      s16x8 B10 = as_s8(wf[((tgl*2+1)*2+0)*64 + lane]);
      s16x8 B11 = as_s8(wf[((tgl*2+1)*2+1)*64 + lane]);
      #pragma unroll
      for(int mt=0;mt<4;mt++){
        f32x4 acc = (f32x4){bv,bv,bv,bv};
        acc = mfma16(Af[mt][0], B00, acc);
        acc = mfma16(Af[mt][0], B01, acc);
        acc = mfma16(Af[mt][1], B10, acc);
        acc = mfma16(Af[mt][1], B11, acc);
        #pragma unroll
        for(int r=0;r<4;r++){
          int tok = mt*16 + 4*lg + r;
          u16 hv = f2us(acc[r]);
          if(nt==0)      qS[(wv*64 + tok)*16 + l15] = hv;       // q[d=l15]
          else if(nt==1) kS[(wv*64 + tok)*32 + l15] = hv;       // k[d=l15]
          else           vt[(wv*16 + l15)*72 + tok] = hv;       // v^T[d][tok]
        }
      }
    }
  }
  // q/k/vt wave-private: no barrier (in-wave LDS ordering)

  // ---- scores (MFMA, head = wv): S[q][tk], K=32 (d16..31 zero in kS) ----
  f32x4 sc[4][4];
  {
    s16x8 Aq[4], Bk[4];
    #pragma unroll
    for(int mt=0;mt<4;mt++)
      Aq[mt] = *(const s16x8*)(qS + (wv*64 + mt*16 + l15)*16 + lg*8);
    #pragma unroll
    for(int nt=0;nt<4;nt++)
      Bk[nt] = *(const s16x8*)(kS + (wv*64 + nt*16 + l15)*32 + lg*8);
    #pragma unroll
    for(int mt=0;mt<4;mt++)
      #pragma unroll
      for(int nt=0;nt<4;nt++){
        f32x4 z = (f32x4){0.f,0.f,0.f,0.f};
        sc[mt][nt] = mfma16(Aq[mt], Bk[nt], z);
      }
  }
  __syncthreads();                         // B2: all q/k/xbn reads done (P overlays)

  // ---- bias + softmax (16-lane shfl reductions) -> P bf16 [q][tk] ----
  {
    const float* Bth = Bt + wv*4096;
    #pragma unroll
    for(int mt=0;mt<4;mt++){
      #pragma unroll
      for(int r=0;r<4;r++){
        int qrow = mt*16 + 4*lg + r;
        float v0 = sc[mt][0][r]*0.25f + Bth[qrow*64 +  0 + l15];
        float v1 = sc[mt][1][r]*0.25f + Bth[qrow*64 + 16 + l15];
        float v2 = sc[mt][2][r]*0.25f + Bth[qrow*64 + 32 + l15];
        float v3 = sc[mt][3][r]*0.25f + Bth[qrow*64 + 48 + l15];
        float mx = fmaxf(fmaxf(v0,v1), fmaxf(v2,v3));
        #pragma unroll
        for(int m2=1;m2<16;m2<<=1) mx = fmaxf(mx, __shfl_xor(mx, m2));
        float e0 = __expf(v0-mx), e1 = __expf(v1-mx);
        float e2 = __expf(v2-mx), e3 = __expf(v3-mx);
        float sm = e0+e1+e2+e3;
        #pragma unroll
        for(int m2=1;m2<16;m2<<=1) sm += __shfl_xor(sm, m2);
        float inv = 1.f/sm;
        u16* Pr = P + (wv*64 + qrow)*72;
        Pr[     l15] = f2us(e0*inv);
        Pr[16 + l15] = f2us(e1*inv);
        Pr[32 + l15] = f2us(e2*inv);
        Pr[48 + l15] = f2us(e3*inv);
      }
    }
  }

  // ---- PV (MFMA): AO[q][d] = P . V  (wave-private) ----
  f32x4 av[4];
  #pragma unroll
  for(int mt=0;mt<4;mt++) av[mt] = (f32x4){0.f,0.f,0.f,0.f};
  #pragma unroll
  for(int ks=0;ks<2;ks++){
    s16x8 Bv = *(const s16x8*)(vt + (wv*16 + l15)*72 + ks*32 + lg*8);
    #pragma unroll
    for(int mt=0;mt<4;mt++){
      s16x8 Ap = *(const s16x8*)(P + (wv*64 + mt*16 + l15)*72 + ks*32 + lg*8);
      av[mt] = mfma16(Ap, Bv, av[mt]);
    }
  }
  __syncthreads();                         // B3: all PV done (P, vt dead)
  #pragma unroll
  for(int mt=0;mt<4;mt++)
    #pragma unroll
    for(int r=0;r<4;r++)
      ao[(mt*16 + 4*lg + r)*72 + wv*16 + l15] = f2us(av[mt][r]);
  __syncthreads();                         // B4: ao ready (read by all waves)

  // ---- proj (MFMA): out-ch tile wv; + bias; stage fp32 to pS ----
  {
    float bv = projb[wv*16 + l15];
    const uint4* wf = (const uint4*)pjf;
    s16x8 B00 = as_s8(wf[((wv*2+0)*2+0)*64 + lane]);
    s16x8 B01 = as_s8(wf[((wv*2+0)*2+1)*64 + lane]);
    s16x8 B10 = as_s8(wf[((wv*2+1)*2+0)*64 + lane]);
    s16x8 B11 = as_s8(wf[((wv*2+1)*2+1)*64 + lane]);
    #pragma unroll
    for(int mt=0;mt<4;mt++){
      s16x8 A0 = *(const s16x8*)(ao + (mt*16+l15)*72 + lg*8);
      s16x8 A1 = *(const s16x8*)(ao + (mt*16+l15)*72 + 32 + lg*8);
      f32x4 acc = (f32x4){bv,bv,bv,bv};
      acc = mfma16(A0, B00, acc);
      acc = mfma16(A0, B01, acc);
      acc = mfma16(A1, B10, acc);
      acc = mfma16(A1, B11, acc);
      #pragma unroll
      for(int r=0;r<4;r++)
        pS[(mt*16 + 4*lg + r)*69 + wv*16 + l15] = acc[r];  // wave-private cols
    }
  }
  // ---- scatter-add into x2 (inverse roll; unique-writer RMW, old pattern) ----
  {
    int tok = lane;
    int ti = tok>>3, tj = tok&7;
    int hf = (hb*8+ti-4)&127, wf_ = (wb*8+tj-4)&127;
    float* xb = x2 + (u*5+v)*HW + hf*128 + wf_;
    #pragma unroll
    for(int cq=0;cq<16;cq++){
      int c = wv*16 + cq;
      xb[c*POS] += pS[tok*69 + c];
    }
  }
}

// ---------------- K9: pre-fragment mbconv weights for MFMA (hi/lo split bf16) ----
__global__ void k_wfrag(const float* __restrict__ w1, const float* __restrict__ w2,
                        u16* __restrict__ w1f, u16* __restrict__ w2f){
  int g = blockIdx.x*256 + threadIdx.x;        // < 65536
  int table = g >> 15;
  int rem = g & 32767;
  int f = rem >> 9, i = rem & 511;
  int l = i >> 3, e = i & 7;
  int l15 = l & 15, lgv = l >> 4;
  if(table==0){
    int tt = f >> 2, h = (f>>1)&1, s = f&1;
    int o = tt*16 + l15, c = h*32 + lgv*8 + e;
    float w = w1[o*64 + c];
    u16 hi = f2us(w);
    w1f[f*512 + i] = (s==0) ? hi : f2us(w - us2f(hi));
  } else {
    int tt = f & 3, g2 = f >> 2;
    int s = g2 & 1, h = (g2>>1)&1, q = g2>>2;
    int oc = q*64 + h*32 + lgv*8 + e, outc = tt*16 + l15;
    float w = w2[outc*256 + oc];
    u16 hi = f2us(w);
    w2f[f*512 + i] = (s==0) ? hi : f2us(w - us2f(hi));
  }
}

// ---------------- K8 v5: fused MBConv on matrix cores (verified round 3) ----------
#define LN_T2 72   // t2s row stride (u16)
#define LN_Y1 68   // y1s row stride (u16)
#define LN_Y2 72   // y2h/y2l row stride (u16)
__global__ __launch_bounds__(256,2) void k_mbconv(
    const u16* __restrict__ t2, const float* x2,
    const u16* __restrict__ w1f, const float* __restrict__ b1,
    const float* __restrict__ dwg, const float* __restrict__ db,
    const u16* __restrict__ w2f, const float* __restrict__ b2,
    float* out){
  __shared__ __align__(16) u16 t2s[144*LN_T2];   // 12x12 halo x 64ch   20736B
  __shared__ __align__(16) u16 y1s[144*LN_Y1];   // chunk expand+silu   19584B
  __shared__ __align__(16) u16 y2h[64*LN_Y2];    // dw out hi            9216B
  __shared__ __align__(16) u16 y2l[64*LN_Y2];    // dw out lo            9216B
  __shared__ float dws[64*25];                   // dw weights chunk     6400B
  int tid = threadIdx.x;
  int lane = tid & 63, wv = tid >> 6;
  int l15 = lane & 15, lg = lane >> 4;
  int n = blockIdx.x >> 8, tile = blockIdx.x & 255;   // 25 groups x 256 tiles
  int h0 = (tile>>4)<<3, w0 = (tile&15)<<3;

  // ---- stage t2 halo: plane-major global -> pixel-major bf16 LDS tile ----
  {
    const u16* tb = t2 + (size_t)n*64*HW;
    for(int L=tid; L<4608; L+=256){
      int c = L/72, j = L - c*72;
      int rr = j/6, k2 = j - rr*6;
      int pc = k2*2;
      int hh = h0-2+rr, ww = w0-2+pc;
      u32 val = 0;
      if((unsigned)hh<128u){
        const u16* rowp = tb + c*HW + hh*128;
        if((unsigned)ww<127u) val = *(const u32*)(rowp + ww);
        else {
          u32 lo = ((unsigned)ww    <128u) ? rowp[ww]   : 0;
          u32 hi = ((unsigned)(ww+1)<128u) ? rowp[ww+1] : 0;
          val = lo | (hi<<16);
        }
      }
      int p = rr*12 + pc;
      t2s[p*LN_T2 + c]      = (u16)val;
      t2s[(p+1)*LN_T2 + c]  = (u16)(val>>16);
    }
  }
  f32x4 accP[4];
  #pragma unroll
  for(int m=0;m<4;m++) accP[m] = (f32x4){0.f,0.f,0.f,0.f};
  __syncthreads();

  for(int q=0;q<4;q++){                        // 4 chunks of 64 expanded channels
    for(int i=tid;i<1600;i+=256) dws[i] = dwg[q*1600 + i];

    // ---- expand 1x1 (MFMA) ----
    {
      int t_g = q*4 + wv;
      float b1v = b1[t_g*16 + l15];
      const uint4* wf = (const uint4*)w1f;
      s16x8 b00 = as_s8(wf[((t_g*2+0)*2+0)*64 + lane]);
      s16x8 b01 = as_s8(wf[((t_g*2+0)*2+1)*64 + lane]);
      s16x8 b10 = as_s8(wf[((t_g*2+1)*2+0)*64 + lane]);
      s16x8 b11 = as_s8(wf[((t_g*2+1)*2+1)*64 + lane]);
      int colw = wv*16 + l15;
      #pragma unroll
      for(int m=0;m<9;m++){
        s16x8 a0 = *(const s16x8*)(t2s + (m*16+l15)*LN_T2 + lg*8);
        s16x8 a1 = *(const s16x8*)(t2s + (m*16+l15)*LN_T2 + 32 + lg*8);
        f32x4 acc = (f32x4){b1v,b1v,b1v,b1v};
        acc = mfma16(a0, b00, acc);
        acc = mfma16(a0, b01, acc);
        acc = mfma16(a1, b10, acc);
        acc = mfma16(a1, b11, acc);
        #pragma unroll
        for(int r=0;r<4;r++){
          int pos = m*16 + lg*4 + r;
          int rr = pos/12, pc = pos - rr*12;
          int hh = h0-2+rr, ww = w0-2+pc;
          bool in = ((unsigned)hh<128u)&&((unsigned)ww<128u);
          y1s[pos*LN_Y1 + colw] = in ? f2us(silu_f(acc[r])) : (u16)0;
        }
      }
    }
    __syncthreads();

    // ---- depthwise 5x5 + silu (fp32 VALU), split hi/lo bf16 ----
    {
      float wreg[25];
      #pragma unroll
      for(int k=0;k<25;k++) wreg[k] = dws[lane*25+k];
      float dbv = db[q*64+lane];
      #pragma unroll
      for(int pp=0;pp<16;pp++){
        int pix = wv*16 + pp;
        int r = pix>>3, cc = pix&7;
        float s = 0.f;
        #pragma unroll
        for(int kh=0;kh<5;kh++)
          #pragma unroll
          for(int kw=0;kw<5;kw++)
            s += us2f(y1s[((r+kh)*12 + cc+kw)*LN_Y1 + lane]) * wreg[kh*5+kw];
        float y2 = silu_f(s + dbv);
        u16 hi = f2us(y2);
        y2h[pix*LN_Y2 + lane] = hi;
        y2l[pix*LN_Y2 + lane] = f2us(y2 - us2f(hi));
      }
    }
    __syncthreads();

    // ---- project 1x1 (MFMA) accumulate ----
    {
      const uint4* wf = (const uint4*)w2f;
      s16x8 bh0 = as_s8(wf[(((q*2+0)*2+0)*4 + wv)*64 + lane]);
      s16x8 bl0 = as_s8(wf[(((q*2+0)*2+1)*4 + wv)*64 + lane]);
      s16x8 bh1 = as_s8(wf[(((q*2+1)*2+0)*4 + wv)*64 + lane]);
      s16x8 bl1 = as_s8(wf[(((q*2+1)*2+1)*4 + wv)*64 + lane]);
      #pragma unroll
      for(int m=0;m<4;m++){
        s16x8 ah0 = *(const s16x8*)(y2h + (m*16+l15)*LN_Y2 + lg*8);
        s16x8 al0 = *(const s16x8*)(y2l + (m*16+l15)*LN_Y2 + lg*8);
        s16x8 ah1 = *(const s16x8*)(y2h + (m*16+l15)*LN_Y2 + 32 + lg*8);
        s16x8 al1 = *(const s16x8*)(y2l + (m*16+l15)*LN_Y2 + 32 + lg*8);
        f32x4 acc = accP[m];
        acc = mfma16(ah0, bh0, acc);
        acc = mfma16(ah0, bl0, acc);
        acc = mfma16(al0, bh0, acc);
        acc = mfma16(ah1, bh1, acc);
        acc = mfma16(ah1, bl1, acc);
        acc = mfma16(al1, bh1, acc);
        accP[m] = acc;
      }
    }
    __syncthreads();
  }

  int outc = wv*16 + l15;
  float b2v = b2[outc];
  float*       ob = out + (size_t)(n*64+outc)*HW;
  const float* xb = x2  + (size_t)(n*64+outc)*HW;
  #pragma unroll
  for(int m=0;m<4;m++){
    #pragma unroll
    for(int r=0;r<4;r++){
      int pix = m*16 + lg*4 + r;
      int rr = pix>>3, cc = pix&7;
      int g = (h0+rr)*128 + (w0+cc);
      ob[g] = accP[m][r] + b2v + xb[g];
    }
  }
}

// ---------------- workspace layout (bytes), total 61,600,256 ----------------
static const size_t OFF_T   = 0;             // u16  t / t2 (reused)   52,428,800
static const size_t OFF_PHW = 52428800;      // f32  pool hw            4,194,304
static const size_t OFF_PHU = 56623104;      // f32  pool hu              163,840
static const size_t OFF_PVW = 56786944;      // f32  pool vw              163,840
static const size_t OFF_PUV = 56950784;      // f32  pool uv                6,400
static const size_t OFF_F0  = 56957184;      // f32  field hw           4,194,304
static const size_t OFF_F2  = 61151488;      // f32  field uh             163,840
static const size_t OFF_F3  = 61315328;      // f32  field vw             163,840
static const size_t OFF_F1  = 61479168;      // f32  field uv               6,400
static const size_t OFF_BT  = 61485568;      // f32  attn bias             65,536
static const size_t OFF_QT  = 61551104;      // u16  qkv MFMA frags        49,152
// Aliased onto the Phw region (dead after k_mca):
static const size_t OFF_W1F = 52428800;      // u16  w1 MFMA frags         65,536
static const size_t OFF_W2F = 52494336;      // u16  w2 MFMA frags         65,536
static const size_t OFF_PJF = 52559872;      // u16  proj MFMA frags       16,384

extern "C" void kernel_launch(void* const* d_in, const int* in_sizes, int n_in,
                              void* d_out, int out_size, void* d_ws, size_t ws_size,
                              hipStream_t stream){
  (void)in_sizes; (void)n_in; (void)out_size; (void)ws_size;
  const float* x     = (const float*)d_in[0];
  const float* n1w   = (const float*)d_in[1];
  const float* n1b   = (const float*)d_in[2];
  const float* n2w   = (const float*)d_in[3];
  const float* n2b   = (const float*)d_in[4];
  const float* qkvw  = (const float*)d_in[5];
  const float* qkvb  = (const float*)d_in[6];
  const float* projw = (const float*)d_in[7];
  const float* projb = (const float*)d_in[8];
  const float* rpbt  = (const float*)d_in[9];
  const int*   rpi   = (const int*)d_in[10];
  const float* mw1   = (const float*)d_in[11];
  const float* mb1   = (const float*)d_in[12];
  const float* mw2   = (const float*)d_in[13];
  const float* mb2   = (const float*)d_in[14];
  const float* mfw   = (const float*)d_in[15];
  const float* mfb   = (const float*)d_in[16];
  const float* bw1   = (const float*)d_in[17];
  const float* bb1   = (const float*)d_in[18];
  const float* bdw   = (const float*)d_in[19];
  const float* bdb   = (const float*)d_in[20];
  const float* bw2   = (const float*)d_in[21];
  const float* bb2   = (const float*)d_in[22];

  char* ws = (char*)d_ws;
  u16*   t   = (u16*)  (ws + OFF_T);
  float* Phw = (float*)(ws + OFF_PHW);
  float* Phu = (float*)(ws + OFF_PHU);
  float* Pvw = (float*)(ws + OFF_PVW);
  float* Puv = (float*)(ws + OFF_PUV);
  float* F0  = (float*)(ws + OFF_F0);
  float* F1  = (float*)(ws + OFF_F1);
  float* F2  = (float*)(ws + OFF_F2);
  float* F3  = (float*)(ws + OFF_F3);
  float* Bt  = (float*)(ws + OFF_BT);
  u16*   qf  = (u16*)  (ws + OFF_QT);
  u16*   w1f = (u16*)  (ws + OFF_W1F);
  u16*   w2f = (u16*)  (ws + OFF_W2F);
  u16*   pjf = (u16*)  (ws + OFF_PJF);
  float* x2  = (float*)d_out;    // f32 residual accumulator lives in d_out
  float* outp= (float*)d_out;

  // 1) t = LN1(x) (bf16 channel-major; pools + MFMA attention input)
  k_ln1<<<1600,256,0,stream>>>(x, n1w, n1b, t);
  // 2) pools of t
  k_pool_hw<<<4096,256,0,stream>>>(t, Phw);
  k_pool_hu<<<10240,256,0,stream>>>(t, Phu);
  k_pool_vw<<<320,128,0,stream>>>(t, Pvw);
  k_pool_uv<<<400,256,0,stream>>>(t, Puv);
  // 3) MCA convs -> gate fields
  k_mca<<<70,256,0,stream>>>(Phw,Phu,Pvw,Puv, mw1,mb1,mw2,mb2, mfw,mfb, F0,F1,F2,F3);
  // 4) attention bias table [h][q][tk] + qkv/proj weight fragments
  k_bias<<<16,256,0,stream>>>(rpi, rpbt, Bt);
  k_wt<<<128,256,0,stream>>>(qkvw, projw, qf, pjf);
  // 5) x2 = x + LN1(x)*A  (fused LN, pure write of all of d_out)
  k_combine<<<1600,256,0,stream>>>(x, n1w, n1b, F0,F1,F2,F3, x2);
  // 6) x2 += window_attn(t)  (MFMA v2; unique-writer RMW)
  k_attn<<<6400,256,0,stream>>>(t, qf, qkvb, pjf, projb, Bt, x2);
  // 7) pre-fragment mbconv weights
  k_wfrag<<<256,256,0,stream>>>(bw1, bw2, w1f, w2f);
  // 8) t2 = LN2(x2), plane-major bf16 (t buffer reused)
  k_ln2<<<1600,256,0,stream>>>(x2, n2w, n2b, t);
  // 9) out = x2 + mbconv(t2)  (MFMA v5, in-place on d_out)
  k_mbconv<<<6400,256,0,stream>>>(t, x2, w1f, bb1, bdw, bdb, w2f, bb2, outp);
}

// Round 5
// 1146.721 us; speedup vs baseline: 2.4495x; 1.2558x over previous
//
#include <hip/hip_runtime.h>

// ---------------- problem constants ----------------
#define C_   64
#define U_   5
#define V_   5
#define H_   128
#define W_   128
#define NH_  4
#define HD_  16
#define WSZ  8
#define S_   64        // tokens per window
#define HW   16384     // H*W
#define UV   25        // U*V
#define POS  409600    // UV*HW, per-channel spatial size
#define TOT  26214400  // C_*POS
#define C4_  256

typedef unsigned short u16;
typedef unsigned int   u32;
typedef __attribute__((ext_vector_type(8))) short s16x8;   // 8 bf16 (4 VGPR)
typedef __attribute__((ext_vector_type(4))) float f32x4;   // MFMA acc

// bf16 <-> fp32 helpers (raw bit manipulation, round-to-nearest-even)
__device__ __forceinline__ float us2f(u16 h){ return __uint_as_float(((u32)h)<<16); }
__device__ __forceinline__ u16 f2us(float f){
  u32 u = __float_as_uint(f);
  return (u16)((u + 0x7fffu + ((u>>16)&1u))>>16);
}
__device__ __forceinline__ float silu_f(float x){ return x/(1.f+__expf(-x)); }
__device__ __forceinline__ s16x8 as_s8(uint4 u){ return __builtin_bit_cast(s16x8, u); }
__device__ __forceinline__ f32x4 mfma16(s16x8 a, s16x8 b, f32x4 c){
  return __builtin_amdgcn_mfma_f32_16x16x32_bf16(a, b, c, 0, 0, 0);
}

// ---------------- K1: LayerNorm over C (norm1) : x(f32) -> t(bf16) ----
// t is consumed by the pools AND as the bf16 input to MFMA attention.
__global__ __launch_bounds__(256,2) void k_ln1(const float* __restrict__ x,
                                               const float* __restrict__ w,
                                               const float* __restrict__ b,
                                               u16* __restrict__ t){
  int p = blockIdx.x*256 + threadIdx.x;        // 0..409599
  float v[64]; float s=0.f, sq=0.f;
  #pragma unroll
  for(int c=0;c<64;c++){ float f = x[c*POS+p]; v[c]=f; s+=f; sq+=f*f; }
  float mu = s*(1.f/64.f);
  float var = sq*(1.f/64.f) - mu*mu;
  float r = rsqrtf(var + 1e-5f);
  #pragma unroll
  for(int c=0;c<64;c++){
    t[c*POS+p] = f2us((v[c]-mu)*r*w[c] + b[c]);
  }
}

// ---------------- K7: LayerNorm over C (norm2) : x2(f32) -> t2(bf16, plane-major) ----
// Plane-major [c*25+uv][hw] — REQUIRED: mbconv's reshape(B*U*V,C,H,W) is a flat
// plane regrouping (round-2 lesson).
__global__ __launch_bounds__(256,2) void k_ln2(const float* __restrict__ x2,
                                               const float* __restrict__ w,
                                               const float* __restrict__ b,
                                               u16* __restrict__ t2){
  int p = blockIdx.x*256 + threadIdx.x;
  float v[64]; float s=0.f, sq=0.f;
  #pragma unroll
  for(int c=0;c<64;c++){ float f = x2[c*POS+p]; v[c]=f; s+=f; sq+=f*f; }
  float mu = s*(1.f/64.f);
  float r = rsqrtf(sq*(1.f/64.f) - mu*mu + 1e-5f);
  #pragma unroll
  for(int c=0;c<64;c++){
    t2[c*POS+p] = f2us((v[c]-mu)*r*w[c] + b[c]);
  }
}

// ---------------- K2a: pool over (u,v) -> P_hw[c][h][w] (raw sums) ----------------
__global__ void k_pool_hw(const u16* __restrict__ t, float* __restrict__ P){
  int idx = blockIdx.x*256 + threadIdx.x;      // < 64*16384
  int c = idx>>14, hw = idx & 16383;
  const u16* base = t + c*POS + hw;
  float s = 0.f;
  #pragma unroll
  for(int uv=0; uv<25; uv++) s += us2f(base[uv*HW]);
  P[idx] = s;
}

// ---------------- K2b: pool over (v,w) -> P_hu[c][u][h] ----------------
__global__ void k_pool_hu(const u16* __restrict__ t, float* __restrict__ P){
  int g = blockIdx.x*256 + threadIdx.x;
  int wid = g>>6, lane = g&63;                 // wid < 40960
  int c = wid/640, rem = wid - c*640;
  int u = rem>>7, h = rem&127;
  const u16* base = t + c*POS + u*5*HW + h*128;
  float s = 0.f;
  #pragma unroll
  for(int v=0;v<5;v++){ s += us2f(base[v*HW+lane]) + us2f(base[v*HW+lane+64]); }
  for(int off=32; off; off>>=1) s += __shfl_down(s, off);
  if(lane==0) P[wid] = s;
}

// ---------------- K2c: pool over (u,h) -> P_vw[c][v][w] (direct reduction) --------
__global__ void k_pool_vw(const u16* __restrict__ t, float* __restrict__ P){
  int bid = blockIdx.x;                        // 320 = 64*5
  int c = bid/5, v = bid - c*5;
  int w = threadIdx.x;                         // 128 threads
  float s = 0.f;
  for(int u=0;u<5;u++){
    const u16* base = t + c*POS + (u*5+v)*HW + w;
    for(int h=0;h<128;h++) s += us2f(base[h*128]);
  }
  P[(c*5+v)*128 + w] = s;
}

// ---------------- K2d: pool over (h,w) -> P_uv[c][u][v] ----------------
__global__ void k_pool_uv(const u16* __restrict__ t, float* __restrict__ P){
  int g = blockIdx.x*256 + threadIdx.x;
  int wid = g>>6, lane = g&63;                 // wid < 1600
  int c = wid/25, rem = wid - c*25;
  const u16* base = t + c*POS + rem*HW;
  float s = 0.f;
  #pragma unroll 8
  for(int k=0;k<256;k++) s += us2f(base[lane + k*64]);
  for(int off=32; off; off>>=1) s += __shfl_down(s, off);
  if(lane==0) P[wid] = s;
}

// ---------------- K3: MCA fused conv1 -> silu -> conv2 -> head conv -> fields ----------
__global__ __launch_bounds__(256,1) void k_mca(
    const float* __restrict__ Phw, const float* __restrict__ Phu,
    const float* __restrict__ Pvw, const float* __restrict__ Puv,
    const float* __restrict__ w1, const float* __restrict__ b1,
    const float* __restrict__ w2, const float* __restrict__ b2,
    const float* __restrict__ fw, const float* __restrict__ fb,
    float* __restrict__ F0, float* __restrict__ F1,
    float* __restrict__ F2, float* __restrict__ F3){
  __shared__ float W1s[4096], W2s[4096];
  for(int i=threadIdx.x;i<4096;i+=256){ W1s[i]=w1[i]; W2s[i]=w2[i]; }
  __syncthreads();
  int pos = blockIdx.x*256 + threadIdx.x;
  if(pos >= 133*133) return;
  int r = pos/133, cc = pos - r*133;

  float y1[64];
  #pragma unroll
  for(int o=0;o<64;o++) y1[o] = b1[o];
  for(int c=0;c<64;c++){
    float in;
    if(r<128){
      if(cc<128) in = Phw[(c<<14)+(r<<7)+cc]*(1.f/25.f);
      else       in = Phu[(c*5+(cc-128))*128 + r]*(1.f/640.f);
    } else {
      if(cc<128) in = Pvw[(c*5+(r-128))*128 + cc]*(1.f/640.f);
      else       in = Puv[c*25 + (cc-128)*5 + (r-128)]*(1.f/16384.f);
    }
    #pragma unroll
    for(int o=0;o<64;o++) y1[o] += W1s[o*64+c]*in;
  }
  float y2[64];
  #pragma unroll
  for(int o=0;o<64;o++) y2[o] = b2[o];
  for(int c=0;c<64;c++){
    float v = silu_f(y1[c]);
    #pragma unroll
    for(int o=0;o<64;o++) y2[o] += W2s[o*64+c]*v;
  }
  int hidx, idx0, stride_o; float* dst;
  if(r<128){
    if(cc<128){ hidx=0; dst=F0; idx0=(r<<7)+cc;            stride_o=16384; }
    else      { hidx=2; dst=F2; idx0=(cc-128)*128 + r;     stride_o=640;   }
  } else {
    if(cc<128){ hidx=3; dst=F3; idx0=(r-128)*128 + cc;     stride_o=640;   }
    else      { hidx=1; dst=F1; idx0=(cc-128)*5 + (r-128); stride_o=25;    }
  }
  const float* fwh = fw + hidx*4096;
  for(int o=0;o<64;o++){
    float f = fb[hidx*64+o];
    #pragma unroll
    for(int c=0;c<64;c++) f += fwh[o*64+c]*y2[c];
    dst[o*stride_o + idx0] = f;
  }
}

// ---------------- K5: attention bias gather -> Bt[h][query][key] ----------------
__global__ void k_bias(const int* __restrict__ rpi, const float* __restrict__ tab,
                       float* __restrict__ Bt){
  int idx = blockIdx.x*256 + threadIdx.x;      // < 4096, idx = i*64 + tk (i=query)
  int ri = rpi[idx];
  #pragma unroll
  for(int h=0;h<4;h++) Bt[h*4096 + idx] = tab[ri*4+h];
}

// ---------------- K5b: pre-fragment qkv + proj weights (hi/lo split bf16) ----
__global__ void k_wt(const float* __restrict__ qkvw, const float* __restrict__ projw,
                     u16* __restrict__ qf, u16* __restrict__ pjf){
  int g = blockIdx.x*256 + threadIdx.x;        // < 32768
  int g2 = (g < 24576) ? g : (g - 24576);
  int f = g2 >> 9, i = g2 & 511;
  int l = i >> 3, e = i & 7;
  int l15 = l & 15, lgv = l >> 4;
  int s = f & 1, h = (f>>1) & 1, tt = f >> 2;
  int n = tt*16 + l15, k = h*32 + lgv*8 + e;
  if(g < 24576){
    float w = qkvw[n*64 + k];
    u16 hi = f2us(w);
    qf[f*512 + i] = (s==0) ? hi : f2us(w - us2f(hi));
  } else {
    float w = projw[n*64 + k];
    u16 hi = f2us(w);
    pjf[f*512 + i] = (s==0) ? hi : f2us(w - us2f(hi));
  }
}

// ---------------- K4: x2 = x + LN1(x)*A  (fused-LN MCA combine, all fp32) -------
__global__ __launch_bounds__(256) void k_combine(
    const float* __restrict__ x,
    const float* __restrict__ n1w, const float* __restrict__ n1b,
    const float* __restrict__ F0, const float* __restrict__ F1,
    const float* __restrict__ F2, const float* __restrict__ F3,
    float* __restrict__ x2){
  int p = blockIdx.x*256 + threadIdx.x;        // < 409600
  float v[64]; float s=0.f, sq=0.f;
  #pragma unroll
  for(int c=0;c<64;c++){ float f = x[c*POS+p]; v[c]=f; s+=f; sq+=f*f; }
  float mu = s*(1.f/64.f);
  float r = rsqrtf(sq*(1.f/64.f) - mu*mu + 1e-5f);
  int uvi = p>>14, hw = p & 16383;
  int u = uvi/5, vv = uvi - 5*u;
  int h = hw>>7, w = hw & 127;
  #pragma unroll
  for(int c=0;c<64;c++){
    float t = (v[c]-mu)*r*n1w[c] + n1b[c];
    float A = F0[(c<<14)+hw] + F1[c*25+uvi] + F2[(c*5+u)*128+h] + F3[(c*5+vv)*128+w];
    x2[c*POS+p] = v[c] + t*A;
  }
}

// ---------------- K6 v2: shifted window attention on MATRIX CORES, += x2 --------
// (verified round 4: all 4 matmuls on mfma_f32_16x16x32_bf16, wave=head,
//  K=32 scores with zero-padded kS, 16-lane shfl softmax, LDS overlay 45KB)
__global__ __launch_bounds__(256,3) void k_attn(
    const u16* __restrict__ t,
    const u16* __restrict__ qf, const float* __restrict__ qkvb,
    const u16* __restrict__ pjf, const float* __restrict__ projb,
    const float* __restrict__ Bt, float* __restrict__ x2){
  __shared__ __align__(16) char smem[46080];
  u16*   xbn = (u16*)smem;                 // [64][72]
  u16*   qS  = (u16*)(smem + 9216);        // [4][64][16]
  u16*   kS  = (u16*)(smem + 17408);       // [4][64][32]
  u16*   P   = (u16*)smem;                 // [4][64][72] overlay
  u16*   vt  = (u16*)(smem + 36864);       // [4][16][72]
  u16*   ao  = (u16*)smem;                 // [64][72] overlay (post-PV)
  float* pS  = (float*)(smem + 9216);      // [64][69] overlay (proj out)

  int tid = threadIdx.x;
  int lane = tid & 63, wv = tid >> 6;
  int l15 = lane & 15, lg = lane >> 4;
  int bid = blockIdx.x;
  int wid = (bid & 7)*800 + (bid >> 3);    // XCD swizzle (6400 = 8*800, bijective)
  int uv = wid >> 8; int u = uv/5, v = uv - 5*u;
  int hb = (wid>>4) & 15, wb = wid & 15;
  const u16* tb = t + (u*5+v)*HW;

  // zero kS (provides the d16..31 zeros for the K=32 scores MFMA)
  {
    u32* kz = (u32*)kS;
    #pragma unroll
    for(int i=0;i<16;i++) kz[tid + i*256] = 0;
  }
  // gather t window (roll +4,+4), 4-token quads are contiguous (shift=4 even)
  #pragma unroll
  for(int it=0; it<4; it++){
    int item = it*256 + tid;               // 1024 = 64 c x 16 quads
    int c = item >> 4, qd = item & 15;
    int ti = qd >> 1, tjq = (qd & 1) * 4;
    int hs = (hb*8 + ti - 4) & 127;
    int wsb = (wb*8 + tjq - 4) & 127;
    ushort4 vals = *(const ushort4*)(tb + c*POS + hs*128 + wsb);
    int tok = ti*8 + tjq;
    xbn[(tok  )*72 + c] = vals.x;
    xbn[(tok+1)*72 + c] = vals.y;
    xbn[(tok+2)*72 + c] = vals.z;
    xbn[(tok+3)*72 + c] = vals.w;
  }
  __syncthreads();                         // B1: xbn + kS zeros ready

  // ---- qkv (MFMA): wave w -> head w's q,k,v ----
  {
    s16x8 Af[4][2];
    #pragma unroll
    for(int mt=0;mt<4;mt++)
      #pragma unroll
      for(int ks=0;ks<2;ks++)
        Af[mt][ks] = *(const s16x8*)(xbn + (mt*16+l15)*72 + ks*32 + lg*8);
    const uint4* wf = (const uint4*)qf;
    #pragma unroll
    for(int nt=0; nt<3; nt++){
      int tgl = wv*3 + nt;
      float bv = qkvb[tgl*16 + l15];
      s16x8 B00 = as_s8(wf[((tgl*2+0)*2+0)*64 + lane]);
      s16x8 B01 = as_s8(wf[((tgl*2+0)*2+1)*64 + lane]);
      s16x8 B10 = as_s8(wf[((tgl*2+1)*2+0)*64 + lane]);
      s16x8 B11 = as_s8(wf[((tgl*2+1)*2+1)*64 + lane]);
      #pragma unroll
      for(int mt=0;mt<4;mt++){
        f32x4 acc = (f32x4){bv,bv,bv,bv};
        acc = mfma16(Af[mt][0], B00, acc);
        acc = mfma16(Af[mt][0], B01, acc);
        acc = mfma16(Af[mt][1], B10, acc);
        acc = mfma16(Af[mt][1], B11, acc);
        #pragma unroll
        for(int r=0;r<4;r++){
          int tok = mt*16 + 4*lg + r;
          u16 hv = f2us(acc[r]);
          if(nt==0)      qS[(wv*64 + tok)*16 + l15] = hv;       // q[d=l15]
          else if(nt==1) kS[(wv*64 + tok)*32 + l15] = hv;       // k[d=l15]
          else           vt[(wv*16 + l15)*72 + tok] = hv;       // v^T[d][tok]
        }
      }
    }
  }
  // q/k/vt wave-private: no barrier (in-wave LDS ordering)

  // ---- scores (MFMA, head = wv): S[q][tk], K=32 (d16..31 zero in kS) ----
  f32x4 sc[4][4];
  {
    s16x8 Aq[4], Bk[4];
    #pragma unroll
    for(int mt=0;mt<4;mt++)
      Aq[mt] = *(const s16x8*)(qS + (wv*64 + mt*16 + l15)*16 + lg*8);
    #pragma unroll
    for(int nt=0;nt<4;nt++)
      Bk[nt] = *(const s16x8*)(kS + (wv*64 + nt*16 + l15)*32 + lg*8);
    #pragma unroll
    for(int mt=0;mt<4;mt++)
      #pragma unroll
      for(int nt=0;nt<4;nt++){
        f32x4 z = (f32x4){0.f,0.f,0.f,0.f};
        sc[mt][nt] = mfma16(Aq[mt], Bk[nt], z);
      }
  }
  __syncthreads();                         // B2: all q/k/xbn reads done (P overlays)

  // ---- bias + softmax (16-lane shfl reductions) -> P bf16 [q][tk] ----
  {
    const float* Bth = Bt + wv*4096;
    #pragma unroll
    for(int mt=0;mt<4;mt++){
      #pragma unroll
      for(int r=0;r<4;r++){
        int qrow = mt*16 + 4*lg + r;
        float v0 = sc[mt][0][r]*0.25f + Bth[qrow*64 +  0 + l15];
        float v1 = sc[mt][1][r]*0.25f + Bth[qrow*64 + 16 + l15];
        float v2 = sc[mt][2][r]*0.25f + Bth[qrow*64 + 32 + l15];
        float v3 = sc[mt][3][r]*0.25f + Bth[qrow*64 + 48 + l15];
        float mx = fmaxf(fmaxf(v0,v1), fmaxf(v2,v3));
        #pragma unroll
        for(int m2=1;m2<16;m2<<=1) mx = fmaxf(mx, __shfl_xor(mx, m2));
        float e0 = __expf(v0-mx), e1 = __expf(v1-mx);
        float e2 = __expf(v2-mx), e3 = __expf(v3-mx);
        float sm = e0+e1+e2+e3;
        #pragma unroll
        for(int m2=1;m2<16;m2<<=1) sm += __shfl_xor(sm, m2);
        float inv = 1.f/sm;
        u16* Pr = P + (wv*64 + qrow)*72;
        Pr[     l15] = f2us(e0*inv);
        Pr[16 + l15] = f2us(e1*inv);
        Pr[32 + l15] = f2us(e2*inv);
        Pr[48 + l15] = f2us(e3*inv);
      }
    }
  }

  // ---- PV (MFMA): AO[q][d] = P . V  (wave-private) ----
  f32x4 av[4];
  #pragma unroll
  for(int mt=0;mt<4;mt++) av[mt] = (f32x4){0.f,0.f,0.f,0.f};
  #pragma unroll
  for(int ks=0;ks<2;ks++){
    s16x8 Bv = *(const s16x8*)(vt + (wv*16 + l15)*72 + ks*32 + lg*8);
    #pragma unroll
    for(int mt=0;mt<4;mt++){
      s16x8 Ap = *(const s16x8*)(P + (wv*64 + mt*16 + l15)*72 + ks*32 + lg*8);
      av[mt] = mfma16(Ap, Bv, av[mt]);
    }
  }
  __syncthreads();                         // B3: all PV done (P, vt dead)
  #pragma unroll
  for(int mt=0;mt<4;mt++)
    #pragma unroll
    for(int r=0;r<4;r++)
      ao[(mt*16 + 4*lg + r)*72 + wv*16 + l15] = f2us(av[mt][r]);
  __syncthreads();                         // B4: ao ready (read by all waves)

  // ---- proj (MFMA): out-ch tile wv; + bias; stage fp32 to pS ----
  {
    float bv = projb[wv*16 + l15];
    const uint4* wf = (const uint4*)pjf;
    s16x8 B00 = as_s8(wf[((wv*2+0)*2+0)*64 + lane]);
    s16x8 B01 = as_s8(wf[((wv*2+0)*2+1)*64 + lane]);
    s16x8 B10 = as_s8(wf[((wv*2+1)*2+0)*64 + lane]);
    s16x8 B11 = as_s8(wf[((wv*2+1)*2+1)*64 + lane]);
    #pragma unroll
    for(int mt=0;mt<4;mt++){
      s16x8 A0 = *(const s16x8*)(ao + (mt*16+l15)*72 + lg*8);
      s16x8 A1 = *(const s16x8*)(ao + (mt*16+l15)*72 + 32 + lg*8);
      f32x4 acc = (f32x4){bv,bv,bv,bv};
      acc = mfma16(A0, B00, acc);
      acc = mfma16(A0, B01, acc);
      acc = mfma16(A1, B10, acc);
      acc = mfma16(A1, B11, acc);
      #pragma unroll
      for(int r=0;r<4;r++)
        pS[(mt*16 + 4*lg + r)*69 + wv*16 + l15] = acc[r];  // wave-private cols
    }
  }
  // ---- scatter-add into x2 (inverse roll; unique-writer RMW) ----
  {
    int tok = lane;
    int ti = tok>>3, tj = tok&7;
    int hf = (hb*8+ti-4)&127, wf_ = (wb*8+tj-4)&127;
    float* xb = x2 + (u*5+v)*HW + hf*128 + wf_;
    #pragma unroll
    for(int cq=0;cq<16;cq++){
      int c = wv*16 + cq;
      xb[c*POS] += pS[tok*69 + c];
    }
  }
}

// ---------------- K9: pre-fragment mbconv weights for MFMA (hi/lo split bf16) ----
__global__ void k_wfrag(const float* __restrict__ w1, const float* __restrict__ w2,
                        u16* __restrict__ w1f, u16* __restrict__ w2f){
  int g = blockIdx.x*256 + threadIdx.x;        // < 65536
  int table = g >> 15;
  int rem = g & 32767;
  int f = rem >> 9, i = rem & 511;
  int l = i >> 3, e = i & 7;
  int l15 = l & 15, lgv = l >> 4;
  if(table==0){
    int tt = f >> 2, h = (f>>1)&1, s = f&1;
    int o = tt*16 + l15, c = h*32 + lgv*8 + e;
    float w = w1[o*64 + c];
    u16 hi = f2us(w);
    w1f[f*512 + i] = (s==0) ? hi : f2us(w - us2f(hi));
  } else {
    int tt = f & 3, g2 = f >> 2;
    int s = g2 & 1, h = (g2>>1)&1, q = g2>>2;
    int oc = q*64 + h*32 + lgv*8 + e, outc = tt*16 + l15;
    float w = w2[outc*256 + oc];
    u16 hi = f2us(w);
    w2f[f*512 + i] = (s==0) ? hi : f2us(w - us2f(hi));
  }
}

// ---------------- K9b: pack dw weights as bf16 channel-pairs dwp[q][tap][po] ----
// dwp[(q*25+k)*32+po] = (bf16 dw[q*64+2po][k], bf16 dw[q*64+2po+1][k]) packed u32.
__global__ void k_dwp(const float* __restrict__ dwg, u32* __restrict__ dwp){
  int i = blockIdx.x*256 + threadIdx.x;        // < 3200
  if(i >= 3200) return;
  int q = i/800, rem = i - q*800;
  int k = rem >> 5, po = rem & 31;
  int ch = q*64 + 2*po;
  u32 lo = f2us(dwg[ch*25 + k]);
  u32 hi = f2us(dwg[(ch+1)*25 + k]);
  dwp[i] = lo | (hi<<16);
}

// ---------------- K8 v6: fused MBConv, MFMA 1x1 + row-sliding dw ----------------
// Round-4 profile: 733us, MfmaUtil 5.9, VALUBusy 54, Occ 22.5 (65KB LDS),
// LDS conflicts 2.6e7. Diagnosis: dw phase = 400 ds_read_u16/thread/chunk
// (16pix x 25taps) ~ 32K LDS-pipe cycles/block -> LDS-instruction-bound.
// v6: (a) dw thread = (row, channel-pair): per kh load 12 row u32 (2ch each),
//     slide 5-tap window in registers -> 85 LDS reads/chunk (4.7x fewer);
// (b) drop y2 lo-split + bf16-pair dw weights: LDS 65152->52736 -> 3 blocks/CU,
//     project 6->4 MFMA/tile (error budget: absmax 0.031 vs 0.11 threshold);
// (c) XCD-swizzled bid for halo-row L2 locality (FETCH 431MB, ~2x ideal).
#define LN_T2 72   // t2s row stride (u16)
#define LN_Y1 68   // y1s row stride (u16)
#define LN_Y2 72   // y2h row stride (u16)
__global__ __launch_bounds__(256,3) void k_mbconv(
    const u16* __restrict__ t2, const float* x2,
    const u16* __restrict__ w1f, const float* __restrict__ b1,
    const u32* __restrict__ dwpg, const float* __restrict__ db,
    const u16* __restrict__ w2f, const float* __restrict__ b2,
    float* out){
  __shared__ __align__(16) u16 t2s[144*LN_T2];   // 12x12 halo x 64ch   20736B
  __shared__ __align__(16) u16 y1s[144*LN_Y1];   // chunk expand+silu   19584B
  __shared__ __align__(16) u16 y2h[64*LN_Y2];    // dw out (bf16)        9216B
  __shared__ __align__(16) u32 dwp_s[25*32];     // dw weight pairs      3200B
  int tid = threadIdx.x;                         // total 52736B -> 3 blocks/CU
  int lane = tid & 63, wv = tid >> 6;
  int l15 = lane & 15, lg = lane >> 4;
  int bid = blockIdx.x;
  int wid = (bid & 7)*800 + (bid >> 3);          // XCD swizzle, bijective
  int n = wid >> 8, tile = wid & 255;            // 25 groups x 256 tiles
  int h0 = (tile>>4)<<3, w0 = (tile&15)<<3;

  // ---- stage t2 halo: plane-major global -> pixel-major bf16 LDS tile ----
  {
    const u16* tb = t2 + (size_t)n*64*HW;
    for(int L=tid; L<4608; L+=256){
      int c = L/72, j = L - c*72;
      int rr = j/6, k2 = j - rr*6;
      int pc = k2*2;
      int hh = h0-2+rr, ww = w0-2+pc;
      u32 val = 0;
      if((unsigned)hh<128u){
        const u16* rowp = tb + c*HW + hh*128;
        if((unsigned)ww<127u) val = *(const u32*)(rowp + ww);
        else {
          u32 lo = ((unsigned)ww    <128u) ? rowp[ww]   : 0;
          u32 hi = ((unsigned)(ww+1)<128u) ? rowp[ww+1] : 0;
          val = lo | (hi<<16);
        }
      }
      int p = rr*12 + pc;
      t2s[p*LN_T2 + c]      = (u16)val;
      t2s[(p+1)*LN_T2 + c]  = (u16)(val>>16);
    }
  }
  f32x4 accP[4];
  #pragma unroll
  for(int m=0;m<4;m++) accP[m] = (f32x4){0.f,0.f,0.f,0.f};
  // dw mapping: thread = (output row r, channel pair po)
  int po = tid & 31, rdw = tid >> 5;             // rdw 0..7, po 0..31
  int oc0 = 2*po;
  __syncthreads();

  for(int q=0;q<4;q++){                          // 4 chunks of 64 expanded ch
    // stage this chunk's packed dw weights
    for(int i=tid;i<800;i+=256) dwp_s[i] = dwpg[q*800 + i];

    // ---- expand 1x1 (MFMA): y1s[pos][oc] = pad ? 0 : silu(t2.w1 + b1) ----
    {
      int t_g = q*4 + wv;
      float b1v = b1[t_g*16 + l15];
      const uint4* wf = (const uint4*)w1f;
      s16x8 b00 = as_s8(wf[((t_g*2+0)*2+0)*64 + lane]);
      s16x8 b01 = as_s8(wf[((t_g*2+0)*2+1)*64 + lane]);
      s16x8 b10 = as_s8(wf[((t_g*2+1)*2+0)*64 + lane]);
      s16x8 b11 = as_s8(wf[((t_g*2+1)*2+1)*64 + lane]);
      int colw = wv*16 + l15;
      #pragma unroll
      for(int m=0;m<9;m++){
        s16x8 a0 = *(const s16x8*)(t2s + (m*16+l15)*LN_T2 + lg*8);
        s16x8 a1 = *(const s16x8*)(t2s + (m*16+l15)*LN_T2 + 32 + lg*8);
        f32x4 acc = (f32x4){b1v,b1v,b1v,b1v};
        acc = mfma16(a0, b00, acc);
        acc = mfma16(a0, b01, acc);
        acc = mfma16(a1, b10, acc);
        acc = mfma16(a1, b11, acc);
        #pragma unroll
        for(int r=0;r<4;r++){
          int pos = m*16 + lg*4 + r;
          int rr = pos/12, pc = pos - rr*12;
          int hh = h0-2+rr, ww = w0-2+pc;
          bool in = ((unsigned)hh<128u)&&((unsigned)ww<128u);
          y1s[pos*LN_Y1 + colw] = in ? f2us(silu_f(acc[r])) : (u16)0;
        }
      }
    }
    __syncthreads();                             // y1s + dwp_s ready

    // ---- depthwise 5x5 + silu: row-sliding, 2 channels/thread, u32 reads ----
    {
      float a0[8], a1[8];
      #pragma unroll
      for(int cc=0;cc<8;cc++){ a0[cc]=0.f; a1[cc]=0.f; }
      #pragma unroll
      for(int kh=0;kh<5;kh++){
        float w0[5], w1[5];
        #pragma unroll
        for(int kw=0;kw<5;kw++){
          u32 wp = dwp_s[(kh*5+kw)*32 + po];
          w0[kw] = us2f((u16)wp); w1[kw] = us2f((u16)(wp>>16));
        }
        float ra[12], rb[12];
        #pragma unroll
        for(int j=0;j<12;j++){
          u32 vv = *(const u32*)(y1s + ((rdw+kh)*12 + j)*LN_Y1 + oc0);
          ra[j] = us2f((u16)vv); rb[j] = us2f((u16)(vv>>16));
        }
        #pragma unroll
        for(int cc=0;cc<8;cc++)
          #pragma unroll
          for(int kw=0;kw<5;kw++){
            a0[cc] += ra[cc+kw]*w0[kw];
            a1[cc] += rb[cc+kw]*w1[kw];
          }
      }
      float db0 = db[q*64 + oc0], db1 = db[q*64 + oc0 + 1];
      #pragma unroll
      for(int cc=0;cc<8;cc++){
        u32 p0 = f2us(silu_f(a0[cc] + db0));
        u32 p1 = f2us(silu_f(a1[cc] + db1));
        *(u32*)(y2h + (rdw*8+cc)*LN_Y2 + oc0) = p0 | (p1<<16);
      }
    }
    __syncthreads();                             // y2h ready

    // ---- project 1x1 (MFMA) accumulate: D[pix][outc] += y2 . w2(hi+lo) ----
    {
      const uint4* wf = (const uint4*)w2f;
      s16x8 bh0 = as_s8(wf[(((q*2+0)*2+0)*4 + wv)*64 + lane]);
      s16x8 bl0 = as_s8(wf[(((q*2+0)*2+1)*4 + wv)*64 + lane]);
      s16x8 bh1 = as_s8(wf[(((q*2+1)*2+0)*4 + wv)*64 + lane]);
      s16x8 bl1 = as_s8(wf[(((q*2+1)*2+1)*4 + wv)*64 + lane]);
      #pragma unroll
      for(int m=0;m<4;m++){
        s16x8 ah0 = *(const s16x8*)(y2h + (m*16+l15)*LN_Y2 + lg*8);
        s16x8 ah1 = *(const s16x8*)(y2h + (m*16+l15)*LN_Y2 + 32 + lg*8);
        f32x4 acc = accP[m];
        acc = mfma16(ah0, bh0, acc);
        acc = mfma16(ah0, bl0, acc);
        acc = mfma16(ah1, bh1, acc);
        acc = mfma16(ah1, bl1, acc);
        accP[m] = acc;
      }
    }
    __syncthreads();                             // before next chunk reuse
  }

  int outc = wv*16 + l15;
  float b2v = b2[outc];
  float*       ob = out + (size_t)(n*64+outc)*HW;
  const float* xb = x2  + (size_t)(n*64+outc)*HW;
  #pragma unroll
  for(int m=0;m<4;m++){
    #pragma unroll
    for(int r=0;r<4;r++){
      int pix = m*16 + lg*4 + r;
      int rr = pix>>3, cc = pix&7;
      int g = (h0+rr)*128 + (w0+cc);
      ob[g] = accP[m][r] + b2v + xb[g];
    }
  }
}

// ---------------- workspace layout (bytes), total 61,600,256 ----------------
static const size_t OFF_T   = 0;             // u16  t / t2 (reused)   52,428,800
static const size_t OFF_PHW = 52428800;      // f32  pool hw            4,194,304
static const size_t OFF_PHU = 56623104;      // f32  pool hu              163,840
static const size_t OFF_PVW = 56786944;      // f32  pool vw              163,840
static const size_t OFF_PUV = 56950784;      // f32  pool uv                6,400
static const size_t OFF_F0  = 56957184;      // f32  field hw           4,194,304
static const size_t OFF_F2  = 61151488;      // f32  field uh             163,840
static const size_t OFF_F3  = 61315328;      // f32  field vw             163,840
static const size_t OFF_F1  = 61479168;      // f32  field uv               6,400
static const size_t OFF_BT  = 61485568;      // f32  attn bias             65,536
static const size_t OFF_QT  = 61551104;      // u16  qkv MFMA frags        49,152
// Aliased onto the Phw region (dead after k_mca):
static const size_t OFF_W1F = 52428800;      // u16  w1 MFMA frags         65,536
static const size_t OFF_W2F = 52494336;      // u16  w2 MFMA frags         65,536
static const size_t OFF_PJF = 52559872;      // u16  proj MFMA frags       16,384
static const size_t OFF_DWP = 52576256;      // u32  dw bf16 pairs         12,800

extern "C" void kernel_launch(void* const* d_in, const int* in_sizes, int n_in,
                              void* d_out, int out_size, void* d_ws, size_t ws_size,
                              hipStream_t stream){
  (void)in_sizes; (void)n_in; (void)out_size; (void)ws_size;
  const float* x     = (const float*)d_in[0];
  const float* n1w   = (const float*)d_in[1];
  const float* n1b   = (const float*)d_in[2];
  const float* n2w   = (const float*)d_in[3];
  const float* n2b   = (const float*)d_in[4];
  const float* qkvw  = (const float*)d_in[5];
  const float* qkvb  = (const float*)d_in[6];
  const float* projw = (const float*)d_in[7];
  const float* projb = (const float*)d_in[8];
  const float* rpbt  = (const float*)d_in[9];
  const int*   rpi   = (const int*)d_in[10];
  const float* mw1   = (const float*)d_in[11];
  const float* mb1   = (const float*)d_in[12];
  const float* mw2   = (const float*)d_in[13];
  const float* mb2   = (const float*)d_in[14];
  const float* mfw   = (const float*)d_in[15];
  const float* mfb   = (const float*)d_in[16];
  const float* bw1   = (const float*)d_in[17];
  const float* bb1   = (const float*)d_in[18];
  const float* bdw   = (const float*)d_in[19];
  const float* bdb   = (const float*)d_in[20];
  const float* bw2   = (const float*)d_in[21];
  const float* bb2   = (const float*)d_in[22];

  char* ws = (char*)d_ws;
  u16*   t   = (u16*)  (ws + OFF_T);
  float* Phw = (float*)(ws + OFF_PHW);
  float* Phu = (float*)(ws + OFF_PHU);
  float* Pvw = (float*)(ws + OFF_PVW);
  float* Puv = (float*)(ws + OFF_PUV);
  float* F0  = (float*)(ws + OFF_F0);
  float* F1  = (float*)(ws + OFF_F1);
  float* F2  = (float*)(ws + OFF_F2);
  float* F3  = (float*)(ws + OFF_F3);
  float* Bt  = (float*)(ws + OFF_BT);
  u16*   qf  = (u16*)  (ws + OFF_QT);
  u16*   w1f = (u16*)  (ws + OFF_W1F);
  u16*   w2f = (u16*)  (ws + OFF_W2F);
  u16*   pjf = (u16*)  (ws + OFF_PJF);
  u32*   dwp = (u32*)  (ws + OFF_DWP);
  float* x2  = (float*)d_out;    // f32 residual accumulator lives in d_out
  float* outp= (float*)d_out;

  // 1) t = LN1(x) (bf16 channel-major; pools + MFMA attention input)
  k_ln1<<<1600,256,0,stream>>>(x, n1w, n1b, t);
  // 2) pools of t
  k_pool_hw<<<4096,256,0,stream>>>(t, Phw);
  k_pool_hu<<<10240,256,0,stream>>>(t, Phu);
  k_pool_vw<<<320,128,0,stream>>>(t, Pvw);
  k_pool_uv<<<400,256,0,stream>>>(t, Puv);
  // 3) MCA convs -> gate fields
  k_mca<<<70,256,0,stream>>>(Phw,Phu,Pvw,Puv, mw1,mb1,mw2,mb2, mfw,mfb, F0,F1,F2,F3);
  // 4) attention bias table [h][q][tk] + qkv/proj weight fragments
  k_bias<<<16,256,0,stream>>>(rpi, rpbt, Bt);
  k_wt<<<128,256,0,stream>>>(qkvw, projw, qf, pjf);
  // 5) x2 = x + LN1(x)*A  (fused LN, pure write of all of d_out)
  k_combine<<<1600,256,0,stream>>>(x, n1w, n1b, F0,F1,F2,F3, x2);
  // 6) x2 += window_attn(t)  (MFMA; unique-writer RMW)
  k_attn<<<6400,256,0,stream>>>(t, qf, qkvb, pjf, projb, Bt, x2);
  // 7) pre-fragment mbconv weights + packed dw pairs
  k_wfrag<<<256,256,0,stream>>>(bw1, bw2, w1f, w2f);
  k_dwp<<<13,256,0,stream>>>(bdw, dwp);
  // 8) t2 = LN2(x2), plane-major bf16 (t buffer reused)
  k_ln2<<<1600,256,0,stream>>>(x2, n2w, n2b, t);
  // 9) out = x2 + mbconv(t2)  (MFMA v6, in-place on d_out)
  k_mbconv<<<6400,256,0,stream>>>(t, x2, w1f, bb1, dwp, bdb, w2f, bb2, outp);
}

// Round 7
// 1134.028 us; speedup vs baseline: 2.4770x; 1.0112x over previous
//
#include <hip/hip_runtime.h>

// ---------------- problem constants ----------------
#define C_   64
#define U_   5
#define V_   5
#define H_   128
#define W_   128
#define NH_  4
#define HD_  16
#define WSZ  8
#define S_   64        // tokens per window
#define HW   16384     // H*W
#define UV   25        // U*V
#define POS  409600    // UV*HW, per-channel spatial size
#define TOT  26214400  // C_*POS
#define C4_  256

typedef unsigned short u16;
typedef unsigned int   u32;
typedef __attribute__((ext_vector_type(8))) short s16x8;   // 8 bf16 (4 VGPR)
typedef __attribute__((ext_vector_type(4))) float f32x4;   // MFMA acc
typedef __attribute__((ext_vector_type(2))) float f32x2;   // packed dual fp32

// bf16 <-> fp32 helpers (raw bit manipulation, round-to-nearest-even)
// ROUND-6 LESSON: rcp-silu + v_cvt_pk_bf16_f32 inline asm produced NaN output;
// reverted to these verified scalar forms (rounds 0-5). Do not reintroduce.
__device__ __forceinline__ float us2f(u16 h){ return __uint_as_float(((u32)h)<<16); }
__device__ __forceinline__ u16 f2us(float f){
  u32 u = __float_as_uint(f);
  return (u16)((u + 0x7fffu + ((u>>16)&1u))>>16);
}
__device__ __forceinline__ f32x2 up2f(u32 w){
  f32x2 r; r.x = __uint_as_float(w<<16); r.y = __uint_as_float(w & 0xffff0000u);
  return r;
}
__device__ __forceinline__ float silu_f(float x){ return x/(1.f+__expf(-x)); }
__device__ __forceinline__ s16x8 as_s8(uint4 u){ return __builtin_bit_cast(s16x8, u); }
__device__ __forceinline__ f32x4 mfma16(s16x8 a, s16x8 b, f32x4 c){
  return __builtin_amdgcn_mfma_f32_16x16x32_bf16(a, b, c, 0, 0, 0);
}

// ---------------- K1: LayerNorm over C (norm1) : x(f32) -> t(bf16) ----
__global__ __launch_bounds__(256,2) void k_ln1(const float* __restrict__ x,
                                               const float* __restrict__ w,
                                               const float* __restrict__ b,
                                               u16* __restrict__ t){
  int p = blockIdx.x*256 + threadIdx.x;        // 0..409599
  float v[64]; float s=0.f, sq=0.f;
  #pragma unroll
  for(int c=0;c<64;c++){ float f = x[c*POS+p]; v[c]=f; s+=f; sq+=f*f; }
  float mu = s*(1.f/64.f);
  float var = sq*(1.f/64.f) - mu*mu;
  float r = rsqrtf(var + 1e-5f);
  #pragma unroll
  for(int c=0;c<64;c++){
    t[c*POS+p] = f2us((v[c]-mu)*r*w[c] + b[c]);
  }
}

// ---------------- K7: LayerNorm over C (norm2) : x2(f32) -> t2(bf16, plane-major) ----
// Plane-major [c*25+uv][hw] — REQUIRED: mbconv's reshape is a flat plane regrouping.
__global__ __launch_bounds__(256,2) void k_ln2(const float* __restrict__ x2,
                                               const float* __restrict__ w,
                                               const float* __restrict__ b,
                                               u16* __restrict__ t2){
  int p = blockIdx.x*256 + threadIdx.x;
  float v[64]; float s=0.f, sq=0.f;
  #pragma unroll
  for(int c=0;c<64;c++){ float f = x2[c*POS+p]; v[c]=f; s+=f; sq+=f*f; }
  float mu = s*(1.f/64.f);
  float r = rsqrtf(sq*(1.f/64.f) - mu*mu + 1e-5f);
  #pragma unroll
  for(int c=0;c<64;c++){
    t2[c*POS+p] = f2us((v[c]-mu)*r*w[c] + b[c]);
  }
}

// ---------------- K2a: pool over (u,v) -> P_hw[c][h][w] (raw sums) ----------------
__global__ void k_pool_hw(const u16* __restrict__ t, float* __restrict__ P){
  int idx = blockIdx.x*256 + threadIdx.x;      // < 64*16384
  int c = idx>>14, hw = idx & 16383;
  const u16* base = t + c*POS + hw;
  float s = 0.f;
  #pragma unroll
  for(int uv=0; uv<25; uv++) s += us2f(base[uv*HW]);
  P[idx] = s;
}

// ---------------- K2b: pool over (v,w) -> P_hu[c][u][h] ----------------
__global__ void k_pool_hu(const u16* __restrict__ t, float* __restrict__ P){
  int g = blockIdx.x*256 + threadIdx.x;
  int wid = g>>6, lane = g&63;                 // wid < 40960
  int c = wid/640, rem = wid - c*640;
  int u = rem>>7, h = rem&127;
  const u16* base = t + c*POS + u*5*HW + h*128;
  float s = 0.f;
  #pragma unroll
  for(int v=0;v<5;v++){ s += us2f(base[v*HW+lane]) + us2f(base[v*HW+lane+64]); }
  for(int off=32; off; off>>=1) s += __shfl_down(s, off);
  if(lane==0) P[wid] = s;
}

// ---------------- K2c: pool over (u,h) -> P_vw[c][v][w] (direct reduction) --------
__global__ void k_pool_vw(const u16* __restrict__ t, float* __restrict__ P){
  int bid = blockIdx.x;                        // 320 = 64*5
  int c = bid/5, v = bid - c*5;
  int w = threadIdx.x;                         // 128 threads
  float s = 0.f;
  for(int u=0;u<5;u++){
    const u16* base = t + c*POS + (u*5+v)*HW + w;
    for(int h=0;h<128;h++) s += us2f(base[h*128]);
  }
  P[(c*5+v)*128 + w] = s;
}

// ---------------- K2d: pool over (h,w) -> P_uv[c][u][v] ----------------
__global__ void k_pool_uv(const u16* __restrict__ t, float* __restrict__ P){
  int g = blockIdx.x*256 + threadIdx.x;
  int wid = g>>6, lane = g&63;                 // wid < 1600
  int c = wid/25, rem = wid - c*25;
  const u16* base = t + c*POS + rem*HW;
  float s = 0.f;
  #pragma unroll 8
  for(int k=0;k<256;k++) s += us2f(base[lane + k*64]);
  for(int off=32; off; off>>=1) s += __shfl_down(s, off);
  if(lane==0) P[wid] = s;
}

// ---------------- K3: MCA fused conv1 -> silu -> conv2 -> head conv -> fields ----------
__global__ __launch_bounds__(256,1) void k_mca(
    const float* __restrict__ Phw, const float* __restrict__ Phu,
    const float* __restrict__ Pvw, const float* __restrict__ Puv,
    const float* __restrict__ w1, const float* __restrict__ b1,
    const float* __restrict__ w2, const float* __restrict__ b2,
    const float* __restrict__ fw, const float* __restrict__ fb,
    float* __restrict__ F0, float* __restrict__ F1,
    float* __restrict__ F2, float* __restrict__ F3){
  __shared__ float W1s[4096], W2s[4096];
  for(int i=threadIdx.x;i<4096;i+=256){ W1s[i]=w1[i]; W2s[i]=w2[i]; }
  __syncthreads();
  int pos = blockIdx.x*256 + threadIdx.x;
  if(pos >= 133*133) return;
  int r = pos/133, cc = pos - r*133;

  float y1[64];
  #pragma unroll
  for(int o=0;o<64;o++) y1[o] = b1[o];
  for(int c=0;c<64;c++){
    float in;
    if(r<128){
      if(cc<128) in = Phw[(c<<14)+(r<<7)+cc]*(1.f/25.f);
      else       in = Phu[(c*5+(cc-128))*128 + r]*(1.f/640.f);
    } else {
      if(cc<128) in = Pvw[(c*5+(r-128))*128 + cc]*(1.f/640.f);
      else       in = Puv[c*25 + (cc-128)*5 + (r-128)]*(1.f/16384.f);
    }
    #pragma unroll
    for(int o=0;o<64;o++) y1[o] += W1s[o*64+c]*in;
  }
  float y2[64];
  #pragma unroll
  for(int o=0;o<64;o++) y2[o] = b2[o];
  for(int c=0;c<64;c++){
    float v = silu_f(y1[c]);
    #pragma unroll
    for(int o=0;o<64;o++) y2[o] += W2s[o*64+c]*v;
  }
  int hidx, idx0, stride_o; float* dst;
  if(r<128){
    if(cc<128){ hidx=0; dst=F0; idx0=(r<<7)+cc;            stride_o=16384; }
    else      { hidx=2; dst=F2; idx0=(cc-128)*128 + r;     stride_o=640;   }
  } else {
    if(cc<128){ hidx=3; dst=F3; idx0=(r-128)*128 + cc;     stride_o=640;   }
    else      { hidx=1; dst=F1; idx0=(cc-128)*5 + (r-128); stride_o=25;    }
  }
  const float* fwh = fw + hidx*4096;
  for(int o=0;o<64;o++){
    float f = fb[hidx*64+o];
    #pragma unroll
    for(int c=0;c<64;c++) f += fwh[o*64+c]*y2[c];
    dst[o*stride_o + idx0] = f;
  }
}

// ---------------- K5: attention bias gather -> Bt[h][query][key] ----------------
__global__ void k_bias(const int* __restrict__ rpi, const float* __restrict__ tab,
                       float* __restrict__ Bt){
  int idx = blockIdx.x*256 + threadIdx.x;      // < 4096, idx = i*64 + tk (i=query)
  int ri = rpi[idx];
  #pragma unroll
  for(int h=0;h<4;h++) Bt[h*4096 + idx] = tab[ri*4+h];
}

// ---------------- K5b: pre-fragment qkv + proj weights (hi/lo split bf16) ----
__global__ void k_wt(const float* __restrict__ qkvw, const float* __restrict__ projw,
                     u16* __restrict__ qf, u16* __restrict__ pjf){
  int g = blockIdx.x*256 + threadIdx.x;        // < 32768
  int g2 = (g < 24576) ? g : (g - 24576);
  int f = g2 >> 9, i = g2 & 511;
  int l = i >> 3, e = i & 7;
  int l15 = l & 15, lgv = l >> 4;
  int s = f & 1, h = (f>>1) & 1, tt = f >> 2;
  int n = tt*16 + l15, k = h*32 + lgv*8 + e;
  if(g < 24576){
    float w = qkvw[n*64 + k];
    u16 hi = f2us(w);
    qf[f*512 + i] = (s==0) ? hi : f2us(w - us2f(hi));
  } else {
    float w = projw[n*64 + k];
    u16 hi = f2us(w);
    pjf[f*512 + i] = (s==0) ? hi : f2us(w - us2f(hi));
  }
}

// ---------------- K4: x2 = x + LN1(x)*A  (fused-LN MCA combine, all fp32) -------
__global__ __launch_bounds__(256) void k_combine(
    const float* __restrict__ x,
    const float* __restrict__ n1w, const float* __restrict__ n1b,
    const float* __restrict__ F0, const float* __restrict__ F1,
    const float* __restrict__ F2, const float* __restrict__ F3,
    float* __restrict__ x2){
  int p = blockIdx.x*256 + threadIdx.x;        // < 409600
  float v[64]; float s=0.f, sq=0.f;
  #pragma unroll
  for(int c=0;c<64;c++){ float f = x[c*POS+p]; v[c]=f; s+=f; sq+=f*f; }
  float mu = s*(1.f/64.f);
  float r = rsqrtf(sq*(1.f/64.f) - mu*mu + 1e-5f);
  int uvi = p>>14, hw = p & 16383;
  int u = uvi/5, vv = uvi - 5*u;
  int h = hw>>7, w = hw & 127;
  #pragma unroll
  for(int c=0;c<64;c++){
    float t = (v[c]-mu)*r*n1w[c] + n1b[c];
    float A = F0[(c<<14)+hw] + F1[c*25+uvi] + F2[(c*5+u)*128+h] + F3[(c*5+vv)*128+w];
    x2[c*POS+p] = v[c] + t*A;
  }
}

// ---------------- K6 v2: shifted window attention on MATRIX CORES, += x2 --------
// (verified rounds 4-5: all 4 matmuls on mfma_f32_16x16x32_bf16, wave=head,
//  K=32 scores with zero-padded kS, 16-lane shfl softmax, LDS overlay 45KB)
__global__ __launch_bounds__(256,3) void k_attn(
    const u16* __restrict__ t,
    const u16* __restrict__ qf, const float* __restrict__ qkvb,
    const u16* __restrict__ pjf, const float* __restrict__ projb,
    const float* __restrict__ Bt, float* __restrict__ x2){
  __shared__ __align__(16) char smem[46080];
  u16*   xbn = (u16*)smem;                 // [64][72]
  u16*   qS  = (u16*)(smem + 9216);        // [4][64][16]
  u16*   kS  = (u16*)(smem + 17408);       // [4][64][32]
  u16*   P   = (u16*)smem;                 // [4][64][72] overlay
  u16*   vt  = (u16*)(smem + 36864);       // [4][16][72]
  u16*   ao  = (u16*)smem;                 // [64][72] overlay (post-PV)
  float* pS  = (float*)(smem + 9216);      // [64][69] overlay (proj out)

  int tid = threadIdx.x;
  int lane = tid & 63, wv = tid >> 6;
  int l15 = lane & 15, lg = lane >> 4;
  int bid = blockIdx.x;
  int wid = (bid & 7)*800 + (bid >> 3);    // XCD swizzle (6400 = 8*800, bijective)
  int uv = wid >> 8; int u = uv/5, v = uv - 5*u;
  int hb = (wid>>4) & 15, wb = wid & 15;
  const u16* tb = t + (u*5+v)*HW;

  // zero kS (provides the d16..31 zeros for the K=32 scores MFMA)
  {
    u32* kz = (u32*)kS;
    #pragma unroll
    for(int i=0;i<16;i++) kz[tid + i*256] = 0;
  }
  // gather t window (roll +4,+4), 4-token quads are contiguous (shift=4 even)
  #pragma unroll
  for(int it=0; it<4; it++){
    int item = it*256 + tid;               // 1024 = 64 c x 16 quads
    int c = item >> 4, qd = item & 15;
    int ti = qd >> 1, tjq = (qd & 1) * 4;
    int hs = (hb*8 + ti - 4) & 127;
    int wsb = (wb*8 + tjq - 4) & 127;
    ushort4 vals = *(const ushort4*)(tb + c*POS + hs*128 + wsb);
    int tok = ti*8 + tjq;
    xbn[(tok  )*72 + c] = vals.x;
    xbn[(tok+1)*72 + c] = vals.y;
    xbn[(tok+2)*72 + c] = vals.z;
    xbn[(tok+3)*72 + c] = vals.w;
  }
  __syncthreads();                         // B1: xbn + kS zeros ready

  // ---- qkv (MFMA): wave w -> head w's q,k,v ----
  {
    s16x8 Af[4][2];
    #pragma unroll
    for(int mt=0;mt<4;mt++)
      #pragma unroll
      for(int ks=0;ks<2;ks++)
        Af[mt][ks] = *(const s16x8*)(xbn + (mt*16+l15)*72 + ks*32 + lg*8);
    const uint4* wf = (const uint4*)qf;
    #pragma unroll
    for(int nt=0; nt<3; nt++){
      int tgl = wv*3 + nt;
      float bv = qkvb[tgl*16 + l15];
      s16x8 B00 = as_s8(wf[((tgl*2+0)*2+0)*64 + lane]);
      s16x8 B01 = as_s8(wf[((tgl*2+0)*2+1)*64 + lane]);
      s16x8 B10 = as_s8(wf[((tgl*2+1)*2+0)*64 + lane]);
      s16x8 B11 = as_s8(wf[((tgl*2+1)*2+1)*64 + lane]);
      #pragma unroll
      for(int mt=0;mt<4;mt++){
        f32x4 acc = (f32x4){bv,bv,bv,bv};
        acc = mfma16(Af[mt][0], B00, acc);
        acc = mfma16(Af[mt][0], B01, acc);
        acc = mfma16(Af[mt][1], B10, acc);
        acc = mfma16(Af[mt][1], B11, acc);
        #pragma unroll
        for(int r=0;r<4;r++){
          int tok = mt*16 + 4*lg + r;
          u16 hv = f2us(acc[r]);
          if(nt==0)      qS[(wv*64 + tok)*16 + l15] = hv;       // q[d=l15]
          else if(nt==1) kS[(wv*64 + tok)*32 + l15] = hv;       // k[d=l15]
          else           vt[(wv*16 + l15)*72 + tok] = hv;       // v^T[d][tok]
        }
      }
    }
  }
  // q/k/vt wave-private: no barrier (in-wave LDS ordering)

  // ---- scores (MFMA, head = wv): S[q][tk], K=32 (d16..31 zero in kS) ----
  f32x4 sc[4][4];
  {
    s16x8 Aq[4], Bk[4];
    #pragma unroll
    for(int mt=0;mt<4;mt++)
      Aq[mt] = *(const s16x8*)(qS + (wv*64 + mt*16 + l15)*16 + lg*8);
    #pragma unroll
    for(int nt=0;nt<4;nt++)
      Bk[nt] = *(const s16x8*)(kS + (wv*64 + nt*16 + l15)*32 + lg*8);
    #pragma unroll
    for(int mt=0;mt<4;mt++)
      #pragma unroll
      for(int nt=0;nt<4;nt++){
        f32x4 z = (f32x4){0.f,0.f,0.f,0.f};
        sc[mt][nt] = mfma16(Aq[mt], Bk[nt], z);
      }
  }
  __syncthreads();                         // B2: all q/k/xbn reads done (P overlays)

  // ---- bias + softmax (16-lane shfl reductions) -> P bf16 [q][tk] ----
  {
    const float* Bth = Bt + wv*4096;
    #pragma unroll
    for(int mt=0;mt<4;mt++){
      #pragma unroll
      for(int r=0;r<4;r++){
        int qrow = mt*16 + 4*lg + r;
        float v0 = sc[mt][0][r]*0.25f + Bth[qrow*64 +  0 + l15];
        float v1 = sc[mt][1][r]*0.25f + Bth[qrow*64 + 16 + l15];
        float v2 = sc[mt][2][r]*0.25f + Bth[qrow*64 + 32 + l15];
        float v3 = sc[mt][3][r]*0.25f + Bth[qrow*64 + 48 + l15];
        float mx = fmaxf(fmaxf(v0,v1), fmaxf(v2,v3));
        #pragma unroll
        for(int m2=1;m2<16;m2<<=1) mx = fmaxf(mx, __shfl_xor(mx, m2));
        float e0 = __expf(v0-mx), e1 = __expf(v1-mx);
        float e2 = __expf(v2-mx), e3 = __expf(v3-mx);
        float sm = e0+e1+e2+e3;
        #pragma unroll
        for(int m2=1;m2<16;m2<<=1) sm += __shfl_xor(sm, m2);
        float inv = 1.f/sm;
        u16* Pr = P + (wv*64 + qrow)*72;
        Pr[     l15] = f2us(e0*inv);
        Pr[16 + l15] = f2us(e1*inv);
        Pr[32 + l15] = f2us(e2*inv);
        Pr[48 + l15] = f2us(e3*inv);
      }
    }
  }

  // ---- PV (MFMA): AO[q][d] = P . V  (wave-private) ----
  f32x4 av[4];
  #pragma unroll
  for(int mt=0;mt<4;mt++) av[mt] = (f32x4){0.f,0.f,0.f,0.f};
  #pragma unroll
  for(int ks=0;ks<2;ks++){
    s16x8 Bv = *(const s16x8*)(vt + (wv*16 + l15)*72 + ks*32 + lg*8);
    #pragma unroll
    for(int mt=0;mt<4;mt++){
      s16x8 Ap = *(const s16x8*)(P + (wv*64 + mt*16 + l15)*72 + ks*32 + lg*8);
      av[mt] = mfma16(Ap, Bv, av[mt]);
    }
  }
  __syncthreads();                         // B3: all PV done (P, vt dead)
  #pragma unroll
  for(int mt=0;mt<4;mt++)
    #pragma unroll
    for(int r=0;r<4;r++)
      ao[(mt*16 + 4*lg + r)*72 + wv*16 + l15] = f2us(av[mt][r]);
  __syncthreads();                         // B4: ao ready (read by all waves)

  // ---- proj (MFMA): out-ch tile wv; + bias; stage fp32 to pS ----
  {
    float bv = projb[wv*16 + l15];
    const uint4* wf = (const uint4*)pjf;
    s16x8 B00 = as_s8(wf[((wv*2+0)*2+0)*64 + lane]);
    s16x8 B01 = as_s8(wf[((wv*2+0)*2+1)*64 + lane]);
    s16x8 B10 = as_s8(wf[((wv*2+1)*2+0)*64 + lane]);
    s16x8 B11 = as_s8(wf[((wv*2+1)*2+1)*64 + lane]);
    #pragma unroll
    for(int mt=0;mt<4;mt++){
      s16x8 A0 = *(const s16x8*)(ao + (mt*16+l15)*72 + lg*8);
      s16x8 A1 = *(const s16x8*)(ao + (mt*16+l15)*72 + 32 + lg*8);
      f32x4 acc = (f32x4){bv,bv,bv,bv};
      acc = mfma16(A0, B00, acc);
      acc = mfma16(A0, B01, acc);
      acc = mfma16(A1, B10, acc);
      acc = mfma16(A1, B11, acc);
      #pragma unroll
      for(int r=0;r<4;r++)
        pS[(mt*16 + 4*lg + r)*69 + wv*16 + l15] = acc[r];  // wave-private cols
    }
  }
  // ---- scatter-add into x2 (inverse roll; unique-writer RMW) ----
  {
    int tok = lane;
    int ti = tok>>3, tj = tok&7;
    int hf = (hb*8+ti-4)&127, wf_ = (wb*8+tj-4)&127;
    float* xb = x2 + (u*5+v)*HW + hf*128 + wf_;
    #pragma unroll
    for(int cq=0;cq<16;cq++){
      int c = wv*16 + cq;
      xb[c*POS] += pS[tok*69 + c];
    }
  }
}

// ---------------- K9: pre-fragment mbconv weights for MFMA (hi/lo split bf16) ----
__global__ void k_wfrag(const float* __restrict__ w1, const float* __restrict__ w2,
                        u16* __restrict__ w1f, u16* __restrict__ w2f){
  int g = blockIdx.x*256 + threadIdx.x;        // < 65536
  int table = g >> 15;
  int rem = g & 32767;
  int f = rem >> 9, i = rem & 511;
  int l = i >> 3, e = i & 7;
  int l15 = l & 15, lgv = l >> 4;
  if(table==0){
    int tt = f >> 2, h = (f>>1)&1, s = f&1;
    int o = tt*16 + l15, c = h*32 + lgv*8 + e;
    float w = w1[o*64 + c];
    u16 hi = f2us(w);
    w1f[f*512 + i] = (s==0) ? hi : f2us(w - us2f(hi));
  } else {
    int tt = f & 3, g2 = f >> 2;
    int s = g2 & 1, h = (g2>>1)&1, q = g2>>2;
    int oc = q*64 + h*32 + lgv*8 + e, outc = tt*16 + l15;
    float w = w2[outc*256 + oc];
    u16 hi = f2us(w);
    w2f[f*512 + i] = (s==0) ? hi : f2us(w - us2f(hi));
  }
}

// ---------------- K9b: pack dw weights as bf16 channel-pairs dwp[q][tap][po] ----
__global__ void k_dwp(const float* __restrict__ dwg, u32* __restrict__ dwp){
  int i = blockIdx.x*256 + threadIdx.x;        // < 3200
  if(i >= 3200) return;
  int q = i/800, rem = i - q*800;
  int k = rem >> 5, po = rem & 31;
  int ch = q*64 + 2*po;
  u32 lo = f2us(dwg[ch*25 + k]);
  u32 hi = f2us(dwg[(ch+1)*25 + k]);
  dwp[i] = lo | (hi<<16);
}

// ---------------- K8 v7b: fused MBConv — safe VALU diet ----------------
// Round-6 NaN post-mortem: rcp-silu + cvt_pk asm reverted (numeric-risk class);
// kept only the two pure restructurings:
//  (c) expand-epilogue geometry (pos/12 + bounds) hoisted to a 36-bit mask
//      (q-invariant, was recomputed 4x);
//  (d) dw accumulation as packed f32x2 fma -> v_pk_fma_f32 (halves 400 FMA
//      issues/chunk; fp32 math bit-identical to round-5 scalar version).
#define LN_T2 72   // t2s row stride (u16)
#define LN_Y1 68   // y1s row stride (u16)
#define LN_Y2 72   // y2h row stride (u16)
__global__ __launch_bounds__(256,3) void k_mbconv(
    const u16* __restrict__ t2, const float* x2,
    const u16* __restrict__ w1f, const float* __restrict__ b1,
    const u32* __restrict__ dwpg, const float* __restrict__ db,
    const u16* __restrict__ w2f, const float* __restrict__ b2,
    float* out){
  __shared__ __align__(16) u16 t2s[144*LN_T2];   // 12x12 halo x 64ch   20736B
  __shared__ __align__(16) u16 y1s[144*LN_Y1];   // chunk expand+silu   19584B
  __shared__ __align__(16) u16 y2h[64*LN_Y2];    // dw out (bf16)        9216B
  __shared__ __align__(16) u32 dwp_s[25*32];     // dw weight pairs      3200B
  int tid = threadIdx.x;                         // total 52736B -> 3 blocks/CU
  int lane = tid & 63, wv = tid >> 6;
  int l15 = lane & 15, lg = lane >> 4;
  int bid = blockIdx.x;
  int wid = (bid & 7)*800 + (bid >> 3);          // XCD swizzle, bijective
  int n = wid >> 8, tile = wid & 255;            // 25 groups x 256 tiles
  int h0 = (tile>>4)<<3, w0 = (tile&15)<<3;

  // ---- stage t2 halo: plane-major global -> pixel-major bf16 LDS tile ----
  {
    const u16* tb = t2 + (size_t)n*64*HW;
    for(int L=tid; L<4608; L+=256){
      int c = L/72, j = L - c*72;
      int rr = j/6, k2 = j - rr*6;
      int pc = k2*2;
      int hh = h0-2+rr, ww = w0-2+pc;
      u32 val = 0;
      if((unsigned)hh<128u){
        const u16* rowp = tb + c*HW + hh*128;
        if((unsigned)ww<127u) val = *(const u32*)(rowp + ww);
        else {
          u32 lo = ((unsigned)ww    <128u) ? rowp[ww]   : 0;
          u32 hi = ((unsigned)(ww+1)<128u) ? rowp[ww+1] : 0;
          val = lo | (hi<<16);
        }
      }
      int p = rr*12 + pc;
      t2s[p*LN_T2 + c]      = (u16)val;
      t2s[(p+1)*LN_T2 + c]  = (u16)(val>>16);
    }
  }
  f32x4 accP[4];
  #pragma unroll
  for(int m=0;m<4;m++) accP[m] = (f32x4){0.f,0.f,0.f,0.f};
  // dw mapping: thread = (output row r, channel pair po)
  int po = tid & 31, rdw = tid >> 5;             // rdw 0..7, po 0..31
  int oc0 = 2*po;
  // hoisted expand-epilogue in-bounds mask (q-invariant, 36 bits)
  u32 inm0 = 0, inm1 = 0;
  #pragma unroll
  for(int m=0;m<9;m++){
    #pragma unroll
    for(int r=0;r<4;r++){
      int pos = m*16 + lg*4 + r;
      int rr = pos/12, pc = pos - rr*12;
      int hh = h0-2+rr, ww = w0-2+pc;
      u32 in = (((unsigned)hh<128u)&&((unsigned)ww<128u)) ? 1u : 0u;
      int bit = m*4+r;
      if(bit<32) inm0 |= in<<bit; else inm1 |= in<<(bit-32);
    }
  }
  __syncthreads();

  for(int q=0;q<4;q++){                          // 4 chunks of 64 expanded ch
    // stage this chunk's packed dw weights
    for(int i=tid;i<800;i+=256) dwp_s[i] = dwpg[q*800 + i];

    // ---- expand 1x1 (MFMA): y1s[pos][oc] = pad ? 0 : silu(t2.w1 + b1) ----
    {
      int t_g = q*4 + wv;
      float b1v = b1[t_g*16 + l15];
      const uint4* wf = (const uint4*)w1f;
      s16x8 b00 = as_s8(wf[((t_g*2+0)*2+0)*64 + lane]);
      s16x8 b01 = as_s8(wf[((t_g*2+0)*2+1)*64 + lane]);
      s16x8 b10 = as_s8(wf[((t_g*2+1)*2+0)*64 + lane]);
      s16x8 b11 = as_s8(wf[((t_g*2+1)*2+1)*64 + lane]);
      int colw = wv*16 + l15;
      #pragma unroll
      for(int m=0;m<9;m++){
        s16x8 a0 = *(const s16x8*)(t2s + (m*16+l15)*LN_T2 + lg*8);
        s16x8 a1 = *(const s16x8*)(t2s + (m*16+l15)*LN_T2 + 32 + lg*8);
        f32x4 acc = (f32x4){b1v,b1v,b1v,b1v};
        acc = mfma16(a0, b00, acc);
        acc = mfma16(a0, b01, acc);
        acc = mfma16(a1, b10, acc);
        acc = mfma16(a1, b11, acc);
        #pragma unroll
        for(int r=0;r<4;r++){
          int bit = m*4+r;                       // compile-time per unrolled iter
          u32 in = (bit<32) ? ((inm0>>bit)&1u) : ((inm1>>(bit-32))&1u);
          int pos = m*16 + lg*4 + r;
          y1s[pos*LN_Y1 + colw] = in ? f2us(silu_f(acc[r])) : (u16)0;
        }
      }
    }
    __syncthreads();                             // y1s + dwp_s ready

    // ---- depthwise 5x5 + silu: packed f32x2 (v_pk_fma_f32), 2 ch/thread ----
    {
      f32x2 acc2[8];
      #pragma unroll
      for(int cc=0;cc<8;cc++) acc2[cc] = (f32x2){0.f,0.f};
      #pragma unroll
      for(int kh=0;kh<5;kh++){
        f32x2 wv2[5];
        #pragma unroll
        for(int kw=0;kw<5;kw++) wv2[kw] = up2f(dwp_s[(kh*5+kw)*32 + po]);
        f32x2 row[12];
        #pragma unroll
        for(int j=0;j<12;j++)
          row[j] = up2f(*(const u32*)(y1s + ((rdw+kh)*12 + j)*LN_Y1 + oc0));
        #pragma unroll
        for(int cc=0;cc<8;cc++)
          #pragma unroll
          for(int kw=0;kw<5;kw++)
            acc2[cc] = __builtin_elementwise_fma(row[cc+kw], wv2[kw], acc2[cc]);
      }
      float db0 = db[q*64 + oc0], db1 = db[q*64 + oc0 + 1];
      #pragma unroll
      for(int cc=0;cc<8;cc++){
        u32 p0 = f2us(silu_f(acc2[cc].x + db0));
        u32 p1 = f2us(silu_f(acc2[cc].y + db1));
        *(u32*)(y2h + (rdw*8+cc)*LN_Y2 + oc0) = p0 | (p1<<16);
      }
    }
    __syncthreads();                             // y2h ready

    // ---- project 1x1 (MFMA) accumulate: D[pix][outc] += y2 . w2(hi+lo) ----
    {
      const uint4* wf = (const uint4*)w2f;
      s16x8 bh0 = as_s8(wf[(((q*2+0)*2+0)*4 + wv)*64 + lane]);
      s16x8 bl0 = as_s8(wf[(((q*2+0)*2+1)*4 + wv)*64 + lane]);
      s16x8 bh1 = as_s8(wf[(((q*2+1)*2+0)*4 + wv)*64 + lane]);
      s16x8 bl1 = as_s8(wf[(((q*2+1)*2+1)*4 + wv)*64 + lane]);
      #pragma unroll
      for(int m=0;m<4;m++){
        s16x8 ah0 = *(const s16x8*)(y2h + (m*16+l15)*LN_Y2 + lg*8);
        s16x8 ah1 = *(const s16x8*)(y2h + (m*16+l15)*LN_Y2 + 32 + lg*8);
        f32x4 acc = accP[m];
        acc = mfma16(ah0, bh0, acc);
        acc = mfma16(ah0, bl0, acc);
        acc = mfma16(ah1, bh1, acc);
        acc = mfma16(ah1, bl1, acc);
        accP[m] = acc;
      }
    }
    __syncthreads();                             // before next chunk reuse
  }

  int outc = wv*16 + l15;
  float b2v = b2[outc];
  float*       ob = out + (size_t)(n*64+outc)*HW;
  const float* xb = x2  + (size_t)(n*64+outc)*HW;
  #pragma unroll
  for(int m=0;m<4;m++){
    #pragma unroll
    for(int r=0;r<4;r++){
      int pix = m*16 + lg*4 + r;
      int rr = pix>>3, cc = pix&7;
      int g = (h0+rr)*128 + (w0+cc);
      ob[g] = accP[m][r] + b2v + xb[g];
    }
  }
}

// ---------------- workspace layout (bytes), total 61,600,256 ----------------
static const size_t OFF_T   = 0;             // u16  t / t2 (reused)   52,428,800
static const size_t OFF_PHW = 52428800;      // f32  pool hw            4,194,304
static const size_t OFF_PHU = 56623104;      // f32  pool hu              163,840
static const size_t OFF_PVW = 56786944;      // f32  pool vw              163,840
static const size_t OFF_PUV = 56950784;      // f32  pool uv                6,400
static const size_t OFF_F0  = 56957184;      // f32  field hw           4,194,304
static const size_t OFF_F2  = 61151488;      // f32  field uh             163,840
static const size_t OFF_F3  = 61315328;      // f32  field vw             163,840
static const size_t OFF_F1  = 61479168;      // f32  field uv               6,400
static const size_t OFF_BT  = 61485568;      // f32  attn bias             65,536
static const size_t OFF_QT  = 61551104;      // u16  qkv MFMA frags        49,152
// Aliased onto the Phw region (dead after k_mca):
static const size_t OFF_W1F = 52428800;      // u16  w1 MFMA frags         65,536
static const size_t OFF_W2F = 52494336;      // u16  w2 MFMA frags         65,536
static const size_t OFF_PJF = 52559872;      // u16  proj MFMA frags       16,384
static const size_t OFF_DWP = 52576256;      // u32  dw bf16 pairs         12,800

extern "C" void kernel_launch(void* const* d_in, const int* in_sizes, int n_in,
                              void* d_out, int out_size, void* d_ws, size_t ws_size,
                              hipStream_t stream){
  (void)in_sizes; (void)n_in; (void)out_size; (void)ws_size;
  const float* x     = (const float*)d_in[0];
  const float* n1w   = (const float*)d_in[1];
  const float* n1b   = (const float*)d_in[2];
  const float* n2w   = (const float*)d_in[3];
  const float* n2b   = (const float*)d_in[4];
  const float* qkvw  = (const float*)d_in[5];
  const float* qkvb  = (const float*)d_in[6];
  const float* projw = (const float*)d_in[7];
  const float* projb = (const float*)d_in[8];
  const float* rpbt  = (const float*)d_in[9];
  const int*   rpi   = (const int*)d_in[10];
  const float* mw1   = (const float*)d_in[11];
  const float* mb1   = (const float*)d_in[12];
  const float* mw2   = (const float*)d_in[13];
  const float* mb2   = (const float*)d_in[14];
  const float* mfw   = (const float*)d_in[15];
  const float* mfb   = (const float*)d_in[16];
  const float* bw1   = (const float*)d_in[17];
  const float* bb1   = (const float*)d_in[18];
  const float* bdw   = (const float*)d_in[19];
  const float* bdb   = (const float*)d_in[20];
  const float* bw2   = (const float*)d_in[21];
  const float* bb2   = (const float*)d_in[22];

  char* ws = (char*)d_ws;
  u16*   t   = (u16*)  (ws + OFF_T);
  float* Phw = (float*)(ws + OFF_PHW);
  float* Phu = (float*)(ws + OFF_PHU);
  float* Pvw = (float*)(ws + OFF_PVW);
  float* Puv = (float*)(ws + OFF_PUV);
  float* F0  = (float*)(ws + OFF_F0);
  float* F1  = (float*)(ws + OFF_F1);
  float* F2  = (float*)(ws + OFF_F2);
  float* F3  = (float*)(ws + OFF_F3);
  float* Bt  = (float*)(ws + OFF_BT);
  u16*   qf  = (u16*)  (ws + OFF_QT);
  u16*   w1f = (u16*)  (ws + OFF_W1F);
  u16*   w2f = (u16*)  (ws + OFF_W2F);
  u16*   pjf = (u16*)  (ws + OFF_PJF);
  u32*   dwp = (u32*)  (ws + OFF_DWP);
  float* x2  = (float*)d_out;    // f32 residual accumulator lives in d_out
  float* outp= (float*)d_out;

  // 1) t = LN1(x) (bf16 channel-major; pools + MFMA attention input)
  k_ln1<<<1600,256,0,stream>>>(x, n1w, n1b, t);
  // 2) pools of t
  k_pool_hw<<<4096,256,0,stream>>>(t, Phw);
  k_pool_hu<<<10240,256,0,stream>>>(t, Phu);
  k_pool_vw<<<320,128,0,stream>>>(t, Pvw);
  k_pool_uv<<<400,256,0,stream>>>(t, Puv);
  // 3) MCA convs -> gate fields
  k_mca<<<70,256,0,stream>>>(Phw,Phu,Pvw,Puv, mw1,mb1,mw2,mb2, mfw,mfb, F0,F1,F2,F3);
  // 4) attention bias table [h][q][tk] + qkv/proj weight fragments
  k_bias<<<16,256,0,stream>>>(rpi, rpbt, Bt);
  k_wt<<<128,256,0,stream>>>(qkvw, projw, qf, pjf);
  // 5) x2 = x + LN1(x)*A  (fused LN, pure write of all of d_out)
  k_combine<<<1600,256,0,stream>>>(x, n1w, n1b, F0,F1,F2,F3, x2);
  // 6) x2 += window_attn(t)  (MFMA; unique-writer RMW)
  k_attn<<<6400,256,0,stream>>>(t, qf, qkvb, pjf, projb, Bt, x2);
  // 7) pre-fragment mbconv weights + packed dw pairs
  k_wfrag<<<256,256,0,stream>>>(bw1, bw2, w1f, w2f);
  k_dwp<<<13,256,0,stream>>>(bdw, dwp);
  // 8) t2 = LN2(x2), plane-major bf16 (t buffer reused)
  k_ln2<<<1600,256,0,stream>>>(x2, n2w, n2b, t);
  // 9) out = x2 + mbconv(t2)  (MFMA v7b, in-place on d_out)
  k_mbconv<<<6400,256,0,stream>>>(t, x2, w1f, bb1, dwp, bdb, w2f, bb2, outp);
}

// Round 11
// 1126.233 us; speedup vs baseline: 2.4941x; 1.0069x over previous
//
#include <hip/hip_runtime.h>

// ---------------- problem constants ----------------
#define C_   64
#define U_   5
#define V_   5
#define H_   128
#define W_   128
#define NH_  4
#define HD_  16
#define WSZ  8
#define S_   64        // tokens per window
#define HW   16384     // H*W
#define UV   25        // U*V
#define POS  409600    // UV*HW, per-channel spatial size
#define TOT  26214400  // C_*POS
#define C4_  256

typedef unsigned short u16;
typedef unsigned int   u32;
typedef __attribute__((ext_vector_type(8))) short s16x8;   // 8 bf16 (4 VGPR)
typedef __attribute__((ext_vector_type(4))) float f32x4;   // MFMA acc
typedef __attribute__((ext_vector_type(2))) float f32x2;   // packed dual fp32

// bf16 <-> fp32 helpers (raw bit manipulation, round-to-nearest-even)
// ROUND-6 LESSON: rcp-silu(1/(1+exp(-x))) + v_cvt_pk_bf16_f32 inline asm produced
// NaN; reverted. Round 8 reintroduces ONLY an inf-free silu (abs form, rcp of
// [1,2]) and ONLY in k_mbconv — if NaN reappears, silu-rcp is convicted.
__device__ __forceinline__ float us2f(u16 h){ return __uint_as_float(((u32)h)<<16); }
__device__ __forceinline__ u16 f2us(float f){
  u32 u = __float_as_uint(f);
  return (u16)((u + 0x7fffu + ((u>>16)&1u))>>16);
}
__device__ __forceinline__ f32x2 up2f(u32 w){
  f32x2 r; r.x = __uint_as_float(w<<16); r.y = __uint_as_float(w & 0xffff0000u);
  return r;
}
__device__ __forceinline__ float silu_f(float x){ return x/(1.f+__expf(-x)); }
// inf-free fast silu: e=exp(-|x|) in (0,1], rcp arg in [1,2] -> no inf/0 anywhere
__device__ __forceinline__ float silu_fast(float x){
  float e = __expf(-fabsf(x));
  float r = __builtin_amdgcn_rcpf(1.f + e);
  return x * ((x >= 0.f) ? r : e*r);
}
__device__ __forceinline__ s16x8 as_s8(uint4 u){ return __builtin_bit_cast(s16x8, u); }
__device__ __forceinline__ f32x4 mfma16(s16x8 a, s16x8 b, f32x4 c){
  return __builtin_amdgcn_mfma_f32_16x16x32_bf16(a, b, c, 0, 0, 0);
}

// ---------------- K1: LayerNorm over C (norm1) : x(f32) -> t(bf16) ----
__global__ __launch_bounds__(256,2) void k_ln1(const float* __restrict__ x,
                                               const float* __restrict__ w,
                                               const float* __restrict__ b,
                                               u16* __restrict__ t){
  int p = blockIdx.x*256 + threadIdx.x;        // 0..409599
  float v[64]; float s=0.f, sq=0.f;
  #pragma unroll
  for(int c=0;c<64;c++){ float f = x[c*POS+p]; v[c]=f; s+=f; sq+=f*f; }
  float mu = s*(1.f/64.f);
  float var = sq*(1.f/64.f) - mu*mu;
  float r = rsqrtf(var + 1e-5f);
  #pragma unroll
  for(int c=0;c<64;c++){
    t[c*POS+p] = f2us((v[c]-mu)*r*w[c] + b[c]);
  }
}

// ---------------- K7: LayerNorm over C (norm2) : x2(f32) -> t2(bf16, plane-major) ----
// Plane-major [c*25+uv][hw] — REQUIRED: mbconv's reshape is a flat plane regrouping.
__global__ __launch_bounds__(256,2) void k_ln2(const float* __restrict__ x2,
                                               const float* __restrict__ w,
                                               const float* __restrict__ b,
                                               u16* __restrict__ t2){
  int p = blockIdx.x*256 + threadIdx.x;
  float v[64]; float s=0.f, sq=0.f;
  #pragma unroll
  for(int c=0;c<64;c++){ float f = x2[c*POS+p]; v[c]=f; s+=f; sq+=f*f; }
  float mu = s*(1.f/64.f);
  float r = rsqrtf(sq*(1.f/64.f) - mu*mu + 1e-5f);
  #pragma unroll
  for(int c=0;c<64;c++){
    t2[c*POS+p] = f2us((v[c]-mu)*r*w[c] + b[c]);
  }
}

// ---------------- K2a: pool over (u,v) -> P_hw[c][h][w] (raw sums) ----------------
__global__ void k_pool_hw(const u16* __restrict__ t, float* __restrict__ P){
  int idx = blockIdx.x*256 + threadIdx.x;      // < 64*16384
  int c = idx>>14, hw = idx & 16383;
  const u16* base = t + c*POS + hw;
  float s = 0.f;
  #pragma unroll
  for(int uv=0; uv<25; uv++) s += us2f(base[uv*HW]);
  P[idx] = s;
}

// ---------------- K2b: pool over (v,w) -> P_hu[c][u][h] ----------------
__global__ void k_pool_hu(const u16* __restrict__ t, float* __restrict__ P){
  int g = blockIdx.x*256 + threadIdx.x;
  int wid = g>>6, lane = g&63;                 // wid < 40960
  int c = wid/640, rem = wid - c*640;
  int u = rem>>7, h = rem&127;
  const u16* base = t + c*POS + u*5*HW + h*128;
  float s = 0.f;
  #pragma unroll
  for(int v=0;v<5;v++){ s += us2f(base[v*HW+lane]) + us2f(base[v*HW+lane+64]); }
  for(int off=32; off; off>>=1) s += __shfl_down(s, off);
  if(lane==0) P[wid] = s;
}

// ---------------- K2c: pool over (u,h) -> P_vw[c][v][w] (direct reduction) --------
__global__ void k_pool_vw(const u16* __restrict__ t, float* __restrict__ P){
  int bid = blockIdx.x;                        // 320 = 64*5
  int c = bid/5, v = bid - c*5;
  int w = threadIdx.x;                         // 128 threads
  float s = 0.f;
  for(int u=0;u<5;u++){
    const u16* base = t + c*POS + (u*5+v)*HW + w;
    for(int h=0;h<128;h++) s += us2f(base[h*128]);
  }
  P[(c*5+v)*128 + w] = s;
}

// ---------------- K2d: pool over (h,w) -> P_uv[c][u][v] ----------------
__global__ void k_pool_uv(const u16* __restrict__ t, float* __restrict__ P){
  int g = blockIdx.x*256 + threadIdx.x;
  int wid = g>>6, lane = g&63;                 // wid < 1600
  int c = wid/25, rem = wid - c*25;
  const u16* base = t + c*POS + rem*HW;
  float s = 0.f;
  #pragma unroll 8
  for(int k=0;k<256;k++) s += us2f(base[lane + k*64]);
  for(int off=32; off; off>>=1) s += __shfl_down(s, off);
  if(lane==0) P[wid] = s;
}

// ---------------- K3: MCA fused conv1 -> silu -> conv2 -> head conv -> fields ----------
__global__ __launch_bounds__(256,1) void k_mca(
    const float* __restrict__ Phw, const float* __restrict__ Phu,
    const float* __restrict__ Pvw, const float* __restrict__ Puv,
    const float* __restrict__ w1, const float* __restrict__ b1,
    const float* __restrict__ w2, const float* __restrict__ b2,
    const float* __restrict__ fw, const float* __restrict__ fb,
    float* __restrict__ F0, float* __restrict__ F1,
    float* __restrict__ F2, float* __restrict__ F3){
  __shared__ float W1s[4096], W2s[4096];
  for(int i=threadIdx.x;i<4096;i+=256){ W1s[i]=w1[i]; W2s[i]=w2[i]; }
  __syncthreads();
  int pos = blockIdx.x*256 + threadIdx.x;
  if(pos >= 133*133) return;
  int r = pos/133, cc = pos - r*133;

  float y1[64];
  #pragma unroll
  for(int o=0;o<64;o++) y1[o] = b1[o];
  for(int c=0;c<64;c++){
    float in;
    if(r<128){
      if(cc<128) in = Phw[(c<<14)+(r<<7)+cc]*(1.f/25.f);
      else       in = Phu[(c*5+(cc-128))*128 + r]*(1.f/640.f);
    } else {
      if(cc<128) in = Pvw[(c*5+(r-128))*128 + cc]*(1.f/640.f);
      else       in = Puv[c*25 + (cc-128)*5 + (r-128)]*(1.f/16384.f);
    }
    #pragma unroll
    for(int o=0;o<64;o++) y1[o] += W1s[o*64+c]*in;
  }
  float y2[64];
  #pragma unroll
  for(int o=0;o<64;o++) y2[o] = b2[o];
  for(int c=0;c<64;c++){
    float v = silu_f(y1[c]);
    #pragma unroll
    for(int o=0;o<64;o++) y2[o] += W2s[o*64+c]*v;
  }
  int hidx, idx0, stride_o; float* dst;
  if(r<128){
    if(cc<128){ hidx=0; dst=F0; idx0=(r<<7)+cc;            stride_o=16384; }
    else      { hidx=2; dst=F2; idx0=(cc-128)*128 + r;     stride_o=640;   }
  } else {
    if(cc<128){ hidx=3; dst=F3; idx0=(r-128)*128 + cc;     stride_o=640;   }
    else      { hidx=1; dst=F1; idx0=(cc-128)*5 + (r-128); stride_o=25;    }
  }
  const float* fwh = fw + hidx*4096;
  for(int o=0;o<64;o++){
    float f = fb[hidx*64+o];
    #pragma unroll
    for(int c=0;c<64;c++) f += fwh[o*64+c]*y2[c];
    dst[o*stride_o + idx0] = f;
  }
}

// ---------------- K5: attention bias gather -> Bt[h][query][key] ----------------
__global__ void k_bias(const int* __restrict__ rpi, const float* __restrict__ tab,
                       float* __restrict__ Bt){
  int idx = blockIdx.x*256 + threadIdx.x;      // < 4096, idx = i*64 + tk (i=query)
  int ri = rpi[idx];
  #pragma unroll
  for(int h=0;h<4;h++) Bt[h*4096 + idx] = tab[ri*4+h];
}

// ---------------- K5b: pre-fragment qkv + proj weights (hi/lo split bf16) ----
__global__ void k_wt(const float* __restrict__ qkvw, const float* __restrict__ projw,
                     u16* __restrict__ qf, u16* __restrict__ pjf){
  int g = blockIdx.x*256 + threadIdx.x;        // < 32768
  int g2 = (g < 24576) ? g : (g - 24576);
  int f = g2 >> 9, i = g2 & 511;
  int l = i >> 3, e = i & 7;
  int l15 = l & 15, lgv = l >> 4;
  int s = f & 1, h = (f>>1) & 1, tt = f >> 2;
  int n = tt*16 + l15, k = h*32 + lgv*8 + e;
  if(g < 24576){
    float w = qkvw[n*64 + k];
    u16 hi = f2us(w);
    qf[f*512 + i] = (s==0) ? hi : f2us(w - us2f(hi));
  } else {
    float w = projw[n*64 + k];
    u16 hi = f2us(w);
    pjf[f*512 + i] = (s==0) ? hi : f2us(w - us2f(hi));
  }
}

// ---------------- K4: x2 = x + LN1(x)*A  (fused-LN MCA combine, all fp32) -------
__global__ __launch_bounds__(256) void k_combine(
    const float* __restrict__ x,
    const float* __restrict__ n1w, const float* __restrict__ n1b,
    const float* __restrict__ F0, const float* __restrict__ F1,
    const float* __restrict__ F2, const float* __restrict__ F3,
    float* __restrict__ x2){
  int p = blockIdx.x*256 + threadIdx.x;        // < 409600
  float v[64]; float s=0.f, sq=0.f;
  #pragma unroll
  for(int c=0;c<64;c++){ float f = x[c*POS+p]; v[c]=f; s+=f; sq+=f*f; }
  float mu = s*(1.f/64.f);
  float r = rsqrtf(sq*(1.f/64.f) - mu*mu + 1e-5f);
  int uvi = p>>14, hw = p & 16383;
  int u = uvi/5, vv = uvi - 5*u;
  int h = hw>>7, w = hw & 127;
  #pragma unroll
  for(int c=0;c<64;c++){
    float t = (v[c]-mu)*r*n1w[c] + n1b[c];
    float A = F0[(c<<14)+hw] + F1[c*25+uvi] + F2[(c*5+u)*128+h] + F3[(c*5+vv)*128+w];
    x2[c*POS+p] = v[c] + t*A;
  }
}

// ---------------- K6 v2: shifted window attention on MATRIX CORES, += x2 --------
// (verified rounds 4-7: all 4 matmuls on mfma_f32_16x16x32_bf16, wave=head,
//  K=32 scores with zero-padded kS, 16-lane shfl softmax, LDS overlay 45KB)
__global__ __launch_bounds__(256,3) void k_attn(
    const u16* __restrict__ t,
    const u16* __restrict__ qf, const float* __restrict__ qkvb,
    const u16* __restrict__ pjf, const float* __restrict__ projb,
    const float* __restrict__ Bt, float* __restrict__ x2){
  __shared__ __align__(16) char smem[46080];
  u16*   xbn = (u16*)smem;                 // [64][72]
  u16*   qS  = (u16*)(smem + 9216);        // [4][64][16]
  u16*   kS  = (u16*)(smem + 17408);       // [4][64][32]
  u16*   P   = (u16*)smem;                 // [4][64][72] overlay
  u16*   vt  = (u16*)(smem + 36864);       // [4][16][72]
  u16*   ao  = (u16*)smem;                 // [64][72] overlay (post-PV)
  float* pS  = (float*)(smem + 9216);      // [64][69] overlay (proj out)

  int tid = threadIdx.x;
  int lane = tid & 63, wv = tid >> 6;
  int l15 = lane & 15, lg = lane >> 4;
  int bid = blockIdx.x;
  int wid = (bid & 7)*800 + (bid >> 3);    // XCD swizzle (6400 = 8*800, bijective)
  int uv = wid >> 8; int u = uv/5, v = uv - 5*u;
  int hb = (wid>>4) & 15, wb = wid & 15;
  const u16* tb = t + (u*5+v)*HW;

  // zero kS (provides the d16..31 zeros for the K=32 scores MFMA)
  {
    u32* kz = (u32*)kS;
    #pragma unroll
    for(int i=0;i<16;i++) kz[tid + i*256] = 0;
  }
  // gather t window (roll +4,+4), 4-token quads are contiguous (shift=4 even)
  #pragma unroll
  for(int it=0; it<4; it++){
    int item = it*256 + tid;               // 1024 = 64 c x 16 quads
    int c = item >> 4, qd = item & 15;
    int ti = qd >> 1, tjq = (qd & 1) * 4;
    int hs = (hb*8 + ti - 4) & 127;
    int wsb = (wb*8 + tjq - 4) & 127;
    ushort4 vals = *(const ushort4*)(tb + c*POS + hs*128 + wsb);
    int tok = ti*8 + tjq;
    xbn[(tok  )*72 + c] = vals.x;
    xbn[(tok+1)*72 + c] = vals.y;
    xbn[(tok+2)*72 + c] = vals.z;
    xbn[(tok+3)*72 + c] = vals.w;
  }
  __syncthreads();                         // B1: xbn + kS zeros ready

  // ---- qkv (MFMA): wave w -> head w's q,k,v ----
  {
    s16x8 Af[4][2];
    #pragma unroll
    for(int mt=0;mt<4;mt++)
      #pragma unroll
      for(int ks=0;ks<2;ks++)
        Af[mt][ks] = *(const s16x8*)(xbn + (mt*16+l15)*72 + ks*32 + lg*8);
    const uint4* wf = (const uint4*)qf;
    #pragma unroll
    for(int nt=0; nt<3; nt++){
      int tgl = wv*3 + nt;
      float bv = qkvb[tgl*16 + l15];
      s16x8 B00 = as_s8(wf[((tgl*2+0)*2+0)*64 + lane]);
      s16x8 B01 = as_s8(wf[((tgl*2+0)*2+1)*64 + lane]);
      s16x8 B10 = as_s8(wf[((tgl*2+1)*2+0)*64 + lane]);
      s16x8 B11 = as_s8(wf[((tgl*2+1)*2+1)*64 + lane]);
      #pragma unroll
      for(int mt=0;mt<4;mt++){
        f32x4 acc = (f32x4){bv,bv,bv,bv};
        acc = mfma16(Af[mt][0], B00, acc);
        acc = mfma16(Af[mt][0], B01, acc);
        acc = mfma16(Af[mt][1], B10, acc);
        acc = mfma16(Af[mt][1], B11, acc);
        #pragma unroll
        for(int r=0;r<4;r++){
          int tok = mt*16 + 4*lg + r;
          u16 hv = f2us(acc[r]);
          if(nt==0)      qS[(wv*64 + tok)*16 + l15] = hv;       // q[d=l15]
          else if(nt==1) kS[(wv*64 + tok)*32 + l15] = hv;       // k[d=l15]
          else           vt[(wv*16 + l15)*72 + tok] = hv;       // v^T[d][tok]
        }
      }
    }
  }
  // q/k/vt wave-private: no barrier (in-wave LDS ordering)

  // ---- scores (MFMA, head = wv): S[q][tk], K=32 (d16..31 zero in kS) ----
  f32x4 sc[4][4];
  {
    s16x8 Aq[4], Bk[4];
    #pragma unroll
    for(int mt=0;mt<4;mt++)
      Aq[mt] = *(const s16x8*)(qS + (wv*64 + mt*16 + l15)*16 + lg*8);
    #pragma unroll
    for(int nt=0;nt<4;nt++)
      Bk[nt] = *(const s16x8*)(kS + (wv*64 + nt*16 + l15)*32 + lg*8);
    #pragma unroll
    for(int mt=0;mt<4;mt++)
      #pragma unroll
      for(int nt=0;nt<4;nt++){
        f32x4 z = (f32x4){0.f,0.f,0.f,0.f};
        sc[mt][nt] = mfma16(Aq[mt], Bk[nt], z);
      }
  }
  __syncthreads();                         // B2: all q/k/xbn reads done (P overlays)

  // ---- bias + softmax (16-lane shfl reductions) -> P bf16 [q][tk] ----
  {
    const float* Bth = Bt + wv*4096;
    #pragma unroll
    for(int mt=0;mt<4;mt++){
      #pragma unroll
      for(int r=0;r<4;r++){
        int qrow = mt*16 + 4*lg + r;
        float v0 = sc[mt][0][r]*0.25f + Bth[qrow*64 +  0 + l15];
        float v1 = sc[mt][1][r]*0.25f + Bth[qrow*64 + 16 + l15];
        float v2 = sc[mt][2][r]*0.25f + Bth[qrow*64 + 32 + l15];
        float v3 = sc[mt][3][r]*0.25f + Bth[qrow*64 + 48 + l15];
        float mx = fmaxf(fmaxf(v0,v1), fmaxf(v2,v3));
        #pragma unroll
        for(int m2=1;m2<16;m2<<=1) mx = fmaxf(mx, __shfl_xor(mx, m2));
        float e0 = __expf(v0-mx), e1 = __expf(v1-mx);
        float e2 = __expf(v2-mx), e3 = __expf(v3-mx);
        float sm = e0+e1+e2+e3;
        #pragma unroll
        for(int m2=1;m2<16;m2<<=1) sm += __shfl_xor(sm, m2);
        float inv = 1.f/sm;
        u16* Pr = P + (wv*64 + qrow)*72;
        Pr[     l15] = f2us(e0*inv);
        Pr[16 + l15] = f2us(e1*inv);
        Pr[32 + l15] = f2us(e2*inv);
        Pr[48 + l15] = f2us(e3*inv);
      }
    }
  }

  // ---- PV (MFMA): AO[q][d] = P . V  (wave-private) ----
  f32x4 av[4];
  #pragma unroll
  for(int mt=0;mt<4;mt++) av[mt] = (f32x4){0.f,0.f,0.f,0.f};
  #pragma unroll
  for(int ks=0;ks<2;ks++){
    s16x8 Bv = *(const s16x8*)(vt + (wv*16 + l15)*72 + ks*32 + lg*8);
    #pragma unroll
    for(int mt=0;mt<4;mt++){
      s16x8 Ap = *(const s16x8*)(P + (wv*64 + mt*16 + l15)*72 + ks*32 + lg*8);
      av[mt] = mfma16(Ap, Bv, av[mt]);
    }
  }
  __syncthreads();                         // B3: all PV done (P, vt dead)
  #pragma unroll
  for(int mt=0;mt<4;mt++)
    #pragma unroll
    for(int r=0;r<4;r++)
      ao[(mt*16 + 4*lg + r)*72 + wv*16 + l15] = f2us(av[mt][r]);
  __syncthreads();                         // B4: ao ready (read by all waves)

  // ---- proj (MFMA): out-ch tile wv; + bias; stage fp32 to pS ----
  {
    float bv = projb[wv*16 + l15];
    const uint4* wf = (const uint4*)pjf;
    s16x8 B00 = as_s8(wf[((wv*2+0)*2+0)*64 + lane]);
    s16x8 B01 = as_s8(wf[((wv*2+0)*2+1)*64 + lane]);
    s16x8 B10 = as_s8(wf[((wv*2+1)*2+0)*64 + lane]);
    s16x8 B11 = as_s8(wf[((wv*2+1)*2+1)*64 + lane]);
    #pragma unroll
    for(int mt=0;mt<4;mt++){
      s16x8 A0 = *(const s16x8*)(ao + (mt*16+l15)*72 + lg*8);
      s16x8 A1 = *(const s16x8*)(ao + (mt*16+l15)*72 + 32 + lg*8);
      f32x4 acc = (f32x4){bv,bv,bv,bv};
      acc = mfma16(A0, B00, acc);
      acc = mfma16(A0, B01, acc);
      acc = mfma16(A1, B10, acc);
      acc = mfma16(A1, B11, acc);
      #pragma unroll
      for(int r=0;r<4;r++)
        pS[(mt*16 + 4*lg + r)*69 + wv*16 + l15] = acc[r];  // wave-private cols
    }
  }
  // ---- scatter-add into x2 (inverse roll; unique-writer RMW) ----
  {
    int tok = lane;
    int ti = tok>>3, tj = tok&7;
    int hf = (hb*8+ti-4)&127, wf_ = (wb*8+tj-4)&127;
    float* xb = x2 + (u*5+v)*HW + hf*128 + wf_;
    #pragma unroll
    for(int cq=0;cq<16;cq++){
      int c = wv*16 + cq;
      xb[c*POS] += pS[tok*69 + c];
    }
  }
}

// ---------------- K9: pre-fragment mbconv weights for MFMA (hi/lo split bf16) ----
__global__ void k_wfrag(const float* __restrict__ w1, const float* __restrict__ w2,
                        u16* __restrict__ w1f, u16* __restrict__ w2f){
  int g = blockIdx.x*256 + threadIdx.x;        // < 65536
  int table = g >> 15;
  int rem = g & 32767;
  int f = rem >> 9, i = rem & 511;
  int l = i >> 3, e = i & 7;
  int l15 = l & 15, lgv = l >> 4;
  if(table==0){
    int tt = f >> 2, h = (f>>1)&1, s = f&1;
    int o = tt*16 + l15, c = h*32 + lgv*8 + e;
    float w = w1[o*64 + c];
    u16 hi = f2us(w);
    w1f[f*512 + i] = (s==0) ? hi : f2us(w - us2f(hi));
  } else {
    int tt = f & 3, g2 = f >> 2;
    int s = g2 & 1, h = (g2>>1)&1, q = g2>>2;
    int oc = q*64 + h*32 + lgv*8 + e, outc = tt*16 + l15;
    float w = w2[outc*256 + oc];
    u16 hi = f2us(w);
    w2f[f*512 + i] = (s==0) ? hi : f2us(w - us2f(hi));
  }
}

// ---------------- K9b: pack dw weights as bf16 channel-pairs dwp[q][tap][po] ----
__global__ void k_dwp(const float* __restrict__ dwg, u32* __restrict__ dwp){
  int i = blockIdx.x*256 + threadIdx.x;        // < 3200
  if(i >= 3200) return;
  int q = i/800, rem = i - q*800;
  int k = rem >> 5, po = rem & 31;
  int ch = q*64 + 2*po;
  u32 lo = f2us(dwg[ch*25 + k]);
  u32 hi = f2us(dwg[(ch+1)*25 + k]);
  dwp[i] = lo | (hi<<16);
}

// ---------------- K8 v8: fused MBConv — wide-LDS dw path ----------------
// Round-7 falsification: cutting ~18% of VALU instrs gained only 2% -> NOT
// VALU-throughput-bound. VGPR_Count=68 + 60 scalar ds_read_b32/thread/chunk in
// the dw phase => serialized load->wait->fma chains (LDS latency-bound at 3
// waves/SIMD). v8: y1 stored PAIR-PACKED [po][pos] (u32 = 2 channels/pos,
// row stride 148 dw) -> dw reads become 3x ds_read_b128 per kh (15 wide,
// independent loads/chunk vs 60 scalar). Expand epilogue interleaves channel
// pairs via one __shfl_xor(1) + guarded ds_write_b128 (9 writes vs 36).
// Plus inf-free rcp silu (mbconv only; see helper comment).
#define LN_T2 72    // t2s row stride (u16)
#define RS1P  148   // y1p row stride (u32 per channel-pair row)
#define LN_Y2 72    // y2h row stride (u16)
__global__ __launch_bounds__(256,3) void k_mbconv(
    const u16* __restrict__ t2, const float* x2,
    const u16* __restrict__ w1f, const float* __restrict__ b1,
    const u32* __restrict__ dwpg, const float* __restrict__ db,
    const u16* __restrict__ w2f, const float* __restrict__ b2,
    float* out){
  __shared__ __align__(16) u16 t2s[144*LN_T2];   // 12x12 halo x 64ch   20736B
  __shared__ __align__(16) u32 y1p[32*RS1P];     // pair-packed y1      18944B
  __shared__ __align__(16) u16 y2h[64*LN_Y2];    // dw out (bf16)        9216B
  __shared__ __align__(16) u32 dwp_s[25*32];     // dw weight pairs      3200B
  int tid = threadIdx.x;                         // total 52096B -> 3 blocks/CU
  int lane = tid & 63, wv = tid >> 6;
  int l15 = lane & 15, lg = lane >> 4;
  int bid = blockIdx.x;
  int wid = (bid & 7)*800 + (bid >> 3);          // XCD swizzle, bijective
  int n = wid >> 8, tile = wid & 255;            // 25 groups x 256 tiles
  int h0 = (tile>>4)<<3, w0 = (tile&15)<<3;

  // ---- stage t2 halo: plane-major global -> pixel-major bf16 LDS tile ----
  {
    const u16* tb = t2 + (size_t)n*64*HW;
    for(int L=tid; L<4608; L+=256){
      int c = L/72, j = L - c*72;
      int rr = j/6, k2 = j - rr*6;
      int pc = k2*2;
      int hh = h0-2+rr, ww = w0-2+pc;
      u32 val = 0;
      if((unsigned)hh<128u){
        const u16* rowp = tb + c*HW + hh*128;
        if((unsigned)ww<127u) val = *(const u32*)(rowp + ww);
        else {
          u32 lo = ((unsigned)ww    <128u) ? rowp[ww]   : 0;
          u32 hi = ((unsigned)(ww+1)<128u) ? rowp[ww+1] : 0;
          val = lo | (hi<<16);
        }
      }
      int p = rr*12 + pc;
      t2s[p*LN_T2 + c]      = (u16)val;
      t2s[(p+1)*LN_T2 + c]  = (u16)(val>>16);
    }
  }
  f32x4 accP[4];
  #pragma unroll
  for(int m=0;m<4;m++) accP[m] = (f32x4){0.f,0.f,0.f,0.f};
  // dw mapping: thread = (output row r, channel pair po)
  int po = tid & 31, rdw = tid >> 5;             // rdw 0..7, po 0..31
  int oc0 = 2*po;
  // hoisted expand-epilogue in-bounds mask (q-invariant, 36 bits)
  u32 inm0 = 0, inm1 = 0;
  #pragma unroll
  for(int m=0;m<9;m++){
    #pragma unroll
    for(int r=0;r<4;r++){
      int pos = m*16 + lg*4 + r;
      int rr = pos/12, pc = pos - rr*12;
      int hh = h0-2+rr, ww = w0-2+pc;
      u32 in = (((unsigned)hh<128u)&&((unsigned)ww<128u)) ? 1u : 0u;
      int bit = m*4+r;
      if(bit<32) inm0 |= in<<bit; else inm1 |= in<<(bit-32);
    }
  }
  int pairrow = wv*8 + (l15>>1);                 // expand-write y1p row
  bool evenl = (l15 & 1) == 0;
  __syncthreads();

  for(int q=0;q<4;q++){                          // 4 chunks of 64 expanded ch
    // stage this chunk's packed dw weights
    for(int i=tid;i<800;i+=256) dwp_s[i] = dwpg[q*800 + i];

    // ---- expand 1x1 (MFMA) -> pair-packed y1p[po][pos] ----
    {
      int t_g = q*4 + wv;
      float b1v = b1[t_g*16 + l15];
      const uint4* wf = (const uint4*)w1f;
      s16x8 b00 = as_s8(wf[((t_g*2+0)*2+0)*64 + lane]);
      s16x8 b01 = as_s8(wf[((t_g*2+0)*2+1)*64 + lane]);
      s16x8 b10 = as_s8(wf[((t_g*2+1)*2+0)*64 + lane]);
      s16x8 b11 = as_s8(wf[((t_g*2+1)*2+1)*64 + lane]);
      #pragma unroll
      for(int m=0;m<9;m++){
        s16x8 a0 = *(const s16x8*)(t2s + (m*16+l15)*LN_T2 + lg*8);
        s16x8 a1 = *(const s16x8*)(t2s + (m*16+l15)*LN_T2 + 32 + lg*8);
        f32x4 acc = (f32x4){b1v,b1v,b1v,b1v};
        acc = mfma16(a0, b00, acc);
        acc = mfma16(a0, b01, acc);
        acc = mfma16(a1, b10, acc);
        acc = mfma16(a1, b11, acc);
        float sv[4];
        #pragma unroll
        for(int r=0;r<4;r++){
          int bit = m*4+r;                       // compile-time per unrolled iter
          u32 in = (bit<32) ? ((inm0>>bit)&1u) : ((inm1>>(bit-32))&1u);
          sv[r] = in ? silu_fast(acc[r]) : 0.f;
        }
        // my channel's bf16 pairs over positions
        u32 A = (u32)f2us(sv[0]) | ((u32)f2us(sv[1])<<16);
        u32 B = (u32)f2us(sv[2]) | ((u32)f2us(sv[3])<<16);
        // partner channel (l15^1) same positions
        u32 Ap = __shfl_xor(A, 1);
        u32 Bp = __shfl_xor(B, 1);
        if(evenl){
          // interleave: W[i] = (my sv[i] lo, partner sv[i] hi)
          uint4 W;
          W.x = (A  & 0xffffu)      | (Ap << 16);
          W.y = (A  >> 16)          | (Ap & 0xffff0000u);
          W.z = (B  & 0xffffu)      | (Bp << 16);
          W.w = (B  >> 16)          | (Bp & 0xffff0000u);
          int pos0 = m*16 + lg*4;
          *(uint4*)(y1p + pairrow*RS1P + pos0) = W;
        }
      }
    }
    __syncthreads();                             // y1p + dwp_s ready

    // ---- depthwise 5x5 + silu: 3x ds_read_b128 per kh, packed f32x2 fma ----
    {
      f32x2 acc2[8];
      #pragma unroll
      for(int cc=0;cc<8;cc++) acc2[cc] = (f32x2){0.f,0.f};
      #pragma unroll
      for(int kh=0;kh<5;kh++){
        f32x2 wv2[5];
        #pragma unroll
        for(int kw=0;kw<5;kw++) wv2[kw] = up2f(dwp_s[(kh*5+kw)*32 + po]);
        const uint4* rp = (const uint4*)(y1p + po*RS1P + (rdw+kh)*12);
        uint4 Ra = rp[0], Rb = rp[1], Rc = rp[2];   // 12 consecutive pair-u32
        u32 rw[12] = {Ra.x,Ra.y,Ra.z,Ra.w, Rb.x,Rb.y,Rb.z,Rb.w, Rc.x,Rc.y,Rc.z,Rc.w};
        f32x2 row[12];
        #pragma unroll
        for(int j=0;j<12;j++) row[j] = up2f(rw[j]);
        #pragma unroll
        for(int cc=0;cc<8;cc++)
          #pragma unroll
          for(int kw=0;kw<5;kw++)
            acc2[cc] = __builtin_elementwise_fma(row[cc+kw], wv2[kw], acc2[cc]);
      }
      float db0 = db[q*64 + oc0], db1 = db[q*64 + oc0 + 1];
      #pragma unroll
      for(int cc=0;cc<8;cc++){
        u32 p0 = f2us(silu_fast(acc2[cc].x + db0));
        u32 p1 = f2us(silu_fast(acc2[cc].y + db1));
        *(u32*)(y2h + (rdw*8+cc)*LN_Y2 + oc0) = p0 | (p1<<16);
      }
    }
    __syncthreads();                             // y2h ready

    // ---- project 1x1 (MFMA) accumulate: D[pix][outc] += y2 . w2(hi+lo) ----
    {
      const uint4* wf = (const uint4*)w2f;
      s16x8 bh0 = as_s8(wf[(((q*2+0)*2+0)*4 + wv)*64 + lane]);
      s16x8 bl0 = as_s8(wf[(((q*2+0)*2+1)*4 + wv)*64 + lane]);
      s16x8 bh1 = as_s8(wf[(((q*2+1)*2+0)*4 + wv)*64 + lane]);
      s16x8 bl1 = as_s8(wf[(((q*2+1)*2+1)*4 + wv)*64 + lane]);
      #pragma unroll
      for(int m=0;m<4;m++){
        s16x8 ah0 = *(const s16x8*)(y2h + (m*16+l15)*LN_Y2 + lg*8);
        s16x8 ah1 = *(const s16x8*)(y2h + (m*16+l15)*LN_Y2 + 32 + lg*8);
        f32x4 acc = accP[m];
        acc = mfma16(ah0, bh0, acc);
        acc = mfma16(ah0, bl0, acc);
        acc = mfma16(ah1, bh1, acc);
        acc = mfma16(ah1, bl1, acc);
        accP[m] = acc;
      }
    }
    __syncthreads();                             // before next chunk reuse
  }

  int outc = wv*16 + l15;
  float b2v = b2[outc];
  float*       ob = out + (size_t)(n*64+outc)*HW;
  const float* xb = x2  + (size_t)(n*64+outc)*HW;
  #pragma unroll
  for(int m=0;m<4;m++){
    #pragma unroll
    for(int r=0;r<4;r++){
      int pix = m*16 + lg*4 + r;
      int rr = pix>>3, cc = pix&7;
      int g = (h0+rr)*128 + (w0+cc);
      ob[g] = accP[m][r] + b2v + xb[g];
    }
  }
}

// ---------------- workspace layout (bytes), total 61,600,256 ----------------
static const size_t OFF_T   = 0;             // u16  t / t2 (reused)   52,428,800
static const size_t OFF_PHW = 52428800;      // f32  pool hw            4,194,304
static const size_t OFF_PHU = 56623104;      // f32  pool hu              163,840
static const size_t OFF_PVW = 56786944;      // f32  pool vw              163,840
static const size_t OFF_PUV = 56950784;      // f32  pool uv                6,400
static const size_t OFF_F0  = 56957184;      // f32  field hw           4,194,304
static const size_t OFF_F2  = 61151488;      // f32  field uh             163,840
static const size_t OFF_F3  = 61315328;      // f32  field vw             163,840
static const size_t OFF_F1  = 61479168;      // f32  field uv               6,400
static const size_t OFF_BT  = 61485568;      // f32  attn bias             65,536
static const size_t OFF_QT  = 61551104;      // u16  qkv MFMA frags        49,152
// Aliased onto the Phw region (dead after k_mca):
static const size_t OFF_W1F = 52428800;      // u16  w1 MFMA frags         65,536
static const size_t OFF_W2F = 52494336;      // u16  w2 MFMA frags         65,536
static const size_t OFF_PJF = 52559872;      // u16  proj MFMA frags       16,384
static const size_t OFF_DWP = 52576256;      // u32  dw bf16 pairs         12,800

extern "C" void kernel_launch(void* const* d_in, const int* in_sizes, int n_in,
                              void* d_out, int out_size, void* d_ws, size_t ws_size,
                              hipStream_t stream){
  (void)in_sizes; (void)n_in; (void)out_size; (void)ws_size;
  const float* x     = (const float*)d_in[0];
  const float* n1w   = (const float*)d_in[1];
  const float* n1b   = (const float*)d_in[2];
  const float* n2w   = (const float*)d_in[3];
  const float* n2b   = (const float*)d_in[4];
  const float* qkvw  = (const float*)d_in[5];
  const float* qkvb  = (const float*)d_in[6];
  const float* projw = (const float*)d_in[7];
  const float* projb = (const float*)d_in[8];
  const float* rpbt  = (const float*)d_in[9];
  const int*   rpi   = (const int*)d_in[10];
  const float* mw1   = (const float*)d_in[11];
  const float* mb1   = (const float*)d_in[12];
  const float* mw2   = (const float*)d_in[13];
  const float* mb2   = (const float*)d_in[14];
  const float* mfw   = (const float*)d_in[15];
  const float* mfb   = (const float*)d_in[16];
  const float* bw1   = (const float*)d_in[17];
  const float* bb1   = (const float*)d_in[18];
  const float* bdw   = (const float*)d_in[19];
  const float* bdb   = (const float*)d_in[20];
  const float* bw2   = (const float*)d_in[21];
  const float* bb2   = (const float*)d_in[22];

  char* ws = (char*)d_ws;
  u16*   t   = (u16*)  (ws + OFF_T);
  float* Phw = (float*)(ws + OFF_PHW);
  float* Phu = (float*)(ws + OFF_PHU);
  float* Pvw = (float*)(ws + OFF_PVW);
  float* Puv = (float*)(ws + OFF_PUV);
  float* F0  = (float*)(ws + OFF_F0);
  float* F1  = (float*)(ws + OFF_F1);
  float* F2  = (float*)(ws + OFF_F2);
  float* F3  = (float*)(ws + OFF_F3);
  float* Bt  = (float*)(ws + OFF_BT);
  u16*   qf  = (u16*)  (ws + OFF_QT);
  u16*   w1f = (u16*)  (ws + OFF_W1F);
  u16*   w2f = (u16*)  (ws + OFF_W2F);
  u16*   pjf = (u16*)  (ws + OFF_PJF);
  u32*   dwp = (u32*)  (ws + OFF_DWP);
  float* x2  = (float*)d_out;    // f32 residual accumulator lives in d_out
  float* outp= (float*)d_out;

  // 1) t = LN1(x) (bf16 channel-major; pools + MFMA attention input)
  k_ln1<<<1600,256,0,stream>>>(x, n1w, n1b, t);
  // 2) pools of t
  k_pool_hw<<<4096,256,0,stream>>>(t, Phw);
  k_pool_hu<<<10240,256,0,stream>>>(t, Phu);
  k_pool_vw<<<320,128,0,stream>>>(t, Pvw);
  k_pool_uv<<<400,256,0,stream>>>(t, Puv);
  // 3) MCA convs -> gate fields
  k_mca<<<70,256,0,stream>>>(Phw,Phu,Pvw,Puv, mw1,mb1,mw2,mb2, mfw,mfb, F0,F1,F2,F3);
  // 4) attention bias table [h][q][tk] + qkv/proj weight fragments
  k_bias<<<16,256,0,stream>>>(rpi, rpbt, Bt);
  k_wt<<<128,256,0,stream>>>(qkvw, projw, qf, pjf);
  // 5) x2 = x + LN1(x)*A  (fused LN, pure write of all of d_out)
  k_combine<<<1600,256,0,stream>>>(x, n1w, n1b, F0,F1,F2,F3, x2);
  // 6) x2 += window_attn(t)  (MFMA; unique-writer RMW)
  k_attn<<<6400,256,0,stream>>>(t, qf, qkvb, pjf, projb, Bt, x2);
  // 7) pre-fragment mbconv weights + packed dw pairs
  k_wfrag<<<256,256,0,stream>>>(bw1, bw2, w1f, w2f);
  k_dwp<<<13,256,0,stream>>>(bdw, dwp);
  // 8) t2 = LN2(x2), plane-major bf16 (t buffer reused)
  k_ln2<<<1600,256,0,stream>>>(x2, n2w, n2b, t);
  // 9) out = x2 + mbconv(t2)  (MFMA v8, in-place on d_out)
  k_mbconv<<<6400,256,0,stream>>>(t, x2, w1f, bb1, dwp, bdb, w2f, bb2, outp);
}

// Round 12
// 889.889 us; speedup vs baseline: 3.1565x; 1.2656x over previous
//
#include <hip/hip_runtime.h>

// ---------------- problem constants ----------------
#define C_   64
#define U_   5
#define V_   5
#define H_   128
#define W_   128
#define NH_  4
#define HD_  16
#define WSZ  8
#define S_   64        // tokens per window
#define HW   16384     // H*W
#define UV   25        // U*V
#define POS  409600    // UV*HW, per-channel spatial size
#define TOT  26214400  // C_*POS
#define C4_  256

typedef unsigned short u16;
typedef unsigned int   u32;
typedef __attribute__((ext_vector_type(8))) short s16x8;   // 8 bf16 (4 VGPR)
typedef __attribute__((ext_vector_type(4))) float f32x4;   // MFMA acc
typedef __attribute__((ext_vector_type(2))) float f32x2;   // packed dual fp32

// bf16 <-> fp32 helpers (raw bit manipulation, round-to-nearest-even)
// ROUND-6 LESSON: rcp-silu(1/(1+exp(-x))) + v_cvt_pk_bf16_f32 inline asm produced
// NaN; the inf-free abs-form rcp silu below was verified clean in rounds 8-11.
__device__ __forceinline__ float us2f(u16 h){ return __uint_as_float(((u32)h)<<16); }
__device__ __forceinline__ u16 f2us(float f){
  u32 u = __float_as_uint(f);
  return (u16)((u + 0x7fffu + ((u>>16)&1u))>>16);
}
__device__ __forceinline__ f32x2 up2f(u32 w){
  f32x2 r; r.x = __uint_as_float(w<<16); r.y = __uint_as_float(w & 0xffff0000u);
  return r;
}
__device__ __forceinline__ float silu_f(float x){ return x/(1.f+__expf(-x)); }
// inf-free fast silu: e=exp(-|x|) in (0,1], rcp arg in [1,2] -> no inf/0 anywhere
__device__ __forceinline__ float silu_fast(float x){
  float e = __expf(-fabsf(x));
  float r = __builtin_amdgcn_rcpf(1.f + e);
  return x * ((x >= 0.f) ? r : e*r);
}
__device__ __forceinline__ s16x8 as_s8(uint4 u){ return __builtin_bit_cast(s16x8, u); }
__device__ __forceinline__ f32x4 mfma16(s16x8 a, s16x8 b, f32x4 c){
  return __builtin_amdgcn_mfma_f32_16x16x32_bf16(a, b, c, 0, 0, 0);
}

// ---------------- K1: LayerNorm over C (norm1) : x(f32) -> t(bf16) ----
__global__ __launch_bounds__(256,2) void k_ln1(const float* __restrict__ x,
                                               const float* __restrict__ w,
                                               const float* __restrict__ b,
                                               u16* __restrict__ t){
  int p = blockIdx.x*256 + threadIdx.x;        // 0..409599
  float v[64]; float s=0.f, sq=0.f;
  #pragma unroll
  for(int c=0;c<64;c++){ float f = x[c*POS+p]; v[c]=f; s+=f; sq+=f*f; }
  float mu = s*(1.f/64.f);
  float var = sq*(1.f/64.f) - mu*mu;
  float r = rsqrtf(var + 1e-5f);
  #pragma unroll
  for(int c=0;c<64;c++){
    t[c*POS+p] = f2us((v[c]-mu)*r*w[c] + b[c]);
  }
}

// ---------------- K7: LayerNorm over C (norm2) : x2(f32) -> t2(bf16, plane-major) ----
// Plane-major [c*25+uv][hw] — REQUIRED: mbconv's reshape is a flat plane regrouping.
__global__ __launch_bounds__(256,2) void k_ln2(const float* __restrict__ x2,
                                               const float* __restrict__ w,
                                               const float* __restrict__ b,
                                               u16* __restrict__ t2){
  int p = blockIdx.x*256 + threadIdx.x;
  float v[64]; float s=0.f, sq=0.f;
  #pragma unroll
  for(int c=0;c<64;c++){ float f = x2[c*POS+p]; v[c]=f; s+=f; sq+=f*f; }
  float mu = s*(1.f/64.f);
  float r = rsqrtf(sq*(1.f/64.f) - mu*mu + 1e-5f);
  #pragma unroll
  for(int c=0;c<64;c++){
    t2[c*POS+p] = f2us((v[c]-mu)*r*w[c] + b[c]);
  }
}

// ---------------- K2a: pool over (u,v) -> P_hw[c][h][w] (raw sums) ----------------
__global__ void k_pool_hw(const u16* __restrict__ t, float* __restrict__ P){
  int idx = blockIdx.x*256 + threadIdx.x;      // < 64*16384
  int c = idx>>14, hw = idx & 16383;
  const u16* base = t + c*POS + hw;
  float s = 0.f;
  #pragma unroll
  for(int uv=0; uv<25; uv++) s += us2f(base[uv*HW]);
  P[idx] = s;
}

// ---------------- K2b: pool over (v,w) -> P_hu[c][u][h] ----------------
__global__ void k_pool_hu(const u16* __restrict__ t, float* __restrict__ P){
  int g = blockIdx.x*256 + threadIdx.x;
  int wid = g>>6, lane = g&63;                 // wid < 40960
  int c = wid/640, rem = wid - c*640;
  int u = rem>>7, h = rem&127;
  const u16* base = t + c*POS + u*5*HW + h*128;
  float s = 0.f;
  #pragma unroll
  for(int v=0;v<5;v++){ s += us2f(base[v*HW+lane]) + us2f(base[v*HW+lane+64]); }
  for(int off=32; off; off>>=1) s += __shfl_down(s, off);
  if(lane==0) P[wid] = s;
}

// ---------------- K2c: pool over (u,h) -> P_vw[c][v][w] (direct reduction) --------
__global__ void k_pool_vw(const u16* __restrict__ t, float* __restrict__ P){
  int bid = blockIdx.x;                        // 320 = 64*5
  int c = bid/5, v = bid - c*5;
  int w = threadIdx.x;                         // 128 threads
  float s = 0.f;
  for(int u=0;u<5;u++){
    const u16* base = t + c*POS + (u*5+v)*HW + w;
    for(int h=0;h<128;h++) s += us2f(base[h*128]);
  }
  P[(c*5+v)*128 + w] = s;
}

// ---------------- K2d: pool over (h,w) -> P_uv[c][u][v] ----------------
__global__ void k_pool_uv(const u16* __restrict__ t, float* __restrict__ P){
  int g = blockIdx.x*256 + threadIdx.x;
  int wid = g>>6, lane = g&63;                 // wid < 1600
  int c = wid/25, rem = wid - c*25;
  const u16* base = t + c*POS + rem*HW;
  float s = 0.f;
  #pragma unroll 8
  for(int k=0;k<256;k++) s += us2f(base[lane + k*64]);
  for(int off=32; off; off>>=1) s += __shfl_down(s, off);
  if(lane==0) P[wid] = s;
}

// ---------------- K3 v2: MCA convs -> fields; 64-thread blocks (round 12) --------
// Round-11 analysis: 70 blocks left 73% of CUs idle. 64-thread blocks x 277 cover
// all 256 CUs with identical per-thread work (12K serial FMA each).
__global__ __launch_bounds__(64,1) void k_mca(
    const float* __restrict__ Phw, const float* __restrict__ Phu,
    const float* __restrict__ Pvw, const float* __restrict__ Puv,
    const float* __restrict__ w1, const float* __restrict__ b1,
    const float* __restrict__ w2, const float* __restrict__ b2,
    const float* __restrict__ fw, const float* __restrict__ fb,
    float* __restrict__ F0, float* __restrict__ F1,
    float* __restrict__ F2, float* __restrict__ F3){
  __shared__ float W1s[4096], W2s[4096];
  for(int i=threadIdx.x;i<4096;i+=64){ W1s[i]=w1[i]; W2s[i]=w2[i]; }
  __syncthreads();
  int pos = blockIdx.x*64 + threadIdx.x;
  if(pos >= 133*133) return;
  int r = pos/133, cc = pos - r*133;

  float y1[64];
  #pragma unroll
  for(int o=0;o<64;o++) y1[o] = b1[o];
  for(int c=0;c<64;c++){
    float in;
    if(r<128){
      if(cc<128) in = Phw[(c<<14)+(r<<7)+cc]*(1.f/25.f);
      else       in = Phu[(c*5+(cc-128))*128 + r]*(1.f/640.f);
    } else {
      if(cc<128) in = Pvw[(c*5+(r-128))*128 + cc]*(1.f/640.f);
      else       in = Puv[c*25 + (cc-128)*5 + (r-128)]*(1.f/16384.f);
    }
    #pragma unroll
    for(int o=0;o<64;o++) y1[o] += W1s[o*64+c]*in;
  }
  float y2[64];
  #pragma unroll
  for(int o=0;o<64;o++) y2[o] = b2[o];
  for(int c=0;c<64;c++){
    float v = silu_f(y1[c]);
    #pragma unroll
    for(int o=0;o<64;o++) y2[o] += W2s[o*64+c]*v;
  }
  int hidx, idx0, stride_o; float* dst;
  if(r<128){
    if(cc<128){ hidx=0; dst=F0; idx0=(r<<7)+cc;            stride_o=16384; }
    else      { hidx=2; dst=F2; idx0=(cc-128)*128 + r;     stride_o=640;   }
  } else {
    if(cc<128){ hidx=3; dst=F3; idx0=(r-128)*128 + cc;     stride_o=640;   }
    else      { hidx=1; dst=F1; idx0=(cc-128)*5 + (r-128); stride_o=25;    }
  }
  const float* fwh = fw + hidx*4096;
  for(int o=0;o<64;o++){
    float f = fb[hidx*64+o];
    #pragma unroll
    for(int c=0;c<64;c++) f += fwh[o*64+c]*y2[c];
    dst[o*stride_o + idx0] = f;
  }
}

// ---------------- K5: attention bias gather -> Bt[h][query][key] ----------------
__global__ void k_bias(const int* __restrict__ rpi, const float* __restrict__ tab,
                       float* __restrict__ Bt){
  int idx = blockIdx.x*256 + threadIdx.x;      // < 4096, idx = i*64 + tk (i=query)
  int ri = rpi[idx];
  #pragma unroll
  for(int h=0;h<4;h++) Bt[h*4096 + idx] = tab[ri*4+h];
}

// ---------------- K5b: pre-fragment qkv + proj weights (hi/lo split bf16) ----
__global__ void k_wt(const float* __restrict__ qkvw, const float* __restrict__ projw,
                     u16* __restrict__ qf, u16* __restrict__ pjf){
  int g = blockIdx.x*256 + threadIdx.x;        // < 32768
  int g2 = (g < 24576) ? g : (g - 24576);
  int f = g2 >> 9, i = g2 & 511;
  int l = i >> 3, e = i & 7;
  int l15 = l & 15, lgv = l >> 4;
  int s = f & 1, h = (f>>1) & 1, tt = f >> 2;
  int n = tt*16 + l15, k = h*32 + lgv*8 + e;
  if(g < 24576){
    float w = qkvw[n*64 + k];
    u16 hi = f2us(w);
    qf[f*512 + i] = (s==0) ? hi : f2us(w - us2f(hi));
  } else {
    float w = projw[n*64 + k];
    u16 hi = f2us(w);
    pjf[f*512 + i] = (s==0) ? hi : f2us(w - us2f(hi));
  }
}

// ---------------- K6 v3: window attention + MCA-combine fused, pure write -------
// Round-12: k_combine deleted; the scatter (unique writer per output pixel)
// computes x2 = x + t*A + attn_proj directly, re-reading x/t/F at the pixel.
// Saves one full 105MB read + 105MB RMW pass vs the combine+RMW pair (489->331MB).
// t*A uses bf16 t (vs combine's fp32 LN value): delta ~2^-9*|t*A|, in budget.
// Attention body is byte-identical to the round-4..11 verified kernel.
__global__ __launch_bounds__(256,3) void k_catt(
    const u16* __restrict__ t, const float* __restrict__ x,
    const u16* __restrict__ qf, const float* __restrict__ qkvb,
    const u16* __restrict__ pjf, const float* __restrict__ projb,
    const float* __restrict__ Bt,
    const float* __restrict__ F0, const float* __restrict__ F1,
    const float* __restrict__ F2, const float* __restrict__ F3,
    float* __restrict__ x2){
  __shared__ __align__(16) char smem[46080];
  u16*   xbn = (u16*)smem;                 // [64][72]
  u16*   qS  = (u16*)(smem + 9216);        // [4][64][16]
  u16*   kS  = (u16*)(smem + 17408);       // [4][64][32]
  u16*   P   = (u16*)smem;                 // [4][64][72] overlay
  u16*   vt  = (u16*)(smem + 36864);       // [4][16][72]
  u16*   ao  = (u16*)smem;                 // [64][72] overlay (post-PV)
  float* pS  = (float*)(smem + 9216);      // [64][69] overlay (proj out)

  int tid = threadIdx.x;
  int lane = tid & 63, wv = tid >> 6;
  int l15 = lane & 15, lg = lane >> 4;
  int bid = blockIdx.x;
  int wid = (bid & 7)*800 + (bid >> 3);    // XCD swizzle (6400 = 8*800, bijective)
  int uv = wid >> 8; int u = uv/5, v = uv - 5*u;
  int hb = (wid>>4) & 15, wb = wid & 15;
  const u16* tb = t + (u*5+v)*HW;

  // zero kS (provides the d16..31 zeros for the K=32 scores MFMA)
  {
    u32* kz = (u32*)kS;
    #pragma unroll
    for(int i=0;i<16;i++) kz[tid + i*256] = 0;
  }
  // gather t window (roll +4,+4), 4-token quads are contiguous (shift=4 even)
  #pragma unroll
  for(int it=0; it<4; it++){
    int item = it*256 + tid;               // 1024 = 64 c x 16 quads
    int c = item >> 4, qd = item & 15;
    int ti = qd >> 1, tjq = (qd & 1) * 4;
    int hs = (hb*8 + ti - 4) & 127;
    int wsb = (wb*8 + tjq - 4) & 127;
    ushort4 vals = *(const ushort4*)(tb + c*POS + hs*128 + wsb);
    int tok = ti*8 + tjq;
    xbn[(tok  )*72 + c] = vals.x;
    xbn[(tok+1)*72 + c] = vals.y;
    xbn[(tok+2)*72 + c] = vals.z;
    xbn[(tok+3)*72 + c] = vals.w;
  }
  __syncthreads();                         // B1: xbn + kS zeros ready

  // ---- qkv (MFMA): wave w -> head w's q,k,v ----
  {
    s16x8 Af[4][2];
    #pragma unroll
    for(int mt=0;mt<4;mt++)
      #pragma unroll
      for(int ks=0;ks<2;ks++)
        Af[mt][ks] = *(const s16x8*)(xbn + (mt*16+l15)*72 + ks*32 + lg*8);
    const uint4* wf = (const uint4*)qf;
    #pragma unroll
    for(int nt=0; nt<3; nt++){
      int tgl = wv*3 + nt;
      float bv = qkvb[tgl*16 + l15];
      s16x8 B00 = as_s8(wf[((tgl*2+0)*2+0)*64 + lane]);
      s16x8 B01 = as_s8(wf[((tgl*2+0)*2+1)*64 + lane]);
      s16x8 B10 = as_s8(wf[((tgl*2+1)*2+0)*64 + lane]);
      s16x8 B11 = as_s8(wf[((tgl*2+1)*2+1)*64 + lane]);
      #pragma unroll
      for(int mt=0;mt<4;mt++){
        f32x4 acc = (f32x4){bv,bv,bv,bv};
        acc = mfma16(Af[mt][0], B00, acc);
        acc = mfma16(Af[mt][0], B01, acc);
        acc = mfma16(Af[mt][1], B10, acc);
        acc = mfma16(Af[mt][1], B11, acc);
        #pragma unroll
        for(int r=0;r<4;r++){
          int tok = mt*16 + 4*lg + r;
          u16 hv = f2us(acc[r]);
          if(nt==0)      qS[(wv*64 + tok)*16 + l15] = hv;       // q[d=l15]
          else if(nt==1) kS[(wv*64 + tok)*32 + l15] = hv;       // k[d=l15]
          else           vt[(wv*16 + l15)*72 + tok] = hv;       // v^T[d][tok]
        }
      }
    }
  }
  // q/k/vt wave-private: no barrier (in-wave LDS ordering)

  // ---- scores (MFMA, head = wv): S[q][tk], K=32 (d16..31 zero in kS) ----
  f32x4 sc[4][4];
  {
    s16x8 Aq[4], Bk[4];
    #pragma unroll
    for(int mt=0;mt<4;mt++)
      Aq[mt] = *(const s16x8*)(qS + (wv*64 + mt*16 + l15)*16 + lg*8);
    #pragma unroll
    for(int nt=0;nt<4;nt++)
      Bk[nt] = *(const s16x8*)(kS + (wv*64 + nt*16 + l15)*32 + lg*8);
    #pragma unroll
    for(int mt=0;mt<4;mt++)
      #pragma unroll
      for(int nt=0;nt<4;nt++){
        f32x4 z = (f32x4){0.f,0.f,0.f,0.f};
        sc[mt][nt] = mfma16(Aq[mt], Bk[nt], z);
      }
  }
  __syncthreads();                         // B2: all q/k/xbn reads done (P overlays)

  // ---- bias + softmax (16-lane shfl reductions) -> P bf16 [q][tk] ----
  {
    const float* Bth = Bt + wv*4096;
    #pragma unroll
    for(int mt=0;mt<4;mt++){
      #pragma unroll
      for(int r=0;r<4;r++){
        int qrow = mt*16 + 4*lg + r;
        float v0 = sc[mt][0][r]*0.25f + Bth[qrow*64 +  0 + l15];
        float v1 = sc[mt][1][r]*0.25f + Bth[qrow*64 + 16 + l15];
        float v2 = sc[mt][2][r]*0.25f + Bth[qrow*64 + 32 + l15];
        float v3 = sc[mt][3][r]*0.25f + Bth[qrow*64 + 48 + l15];
        float mx = fmaxf(fmaxf(v0,v1), fmaxf(v2,v3));
        #pragma unroll
        for(int m2=1;m2<16;m2<<=1) mx = fmaxf(mx, __shfl_xor(mx, m2));
        float e0 = __expf(v0-mx), e1 = __expf(v1-mx);
        float e2 = __expf(v2-mx), e3 = __expf(v3-mx);
        float sm = e0+e1+e2+e3;
        #pragma unroll
        for(int m2=1;m2<16;m2<<=1) sm += __shfl_xor(sm, m2);
        float inv = 1.f/sm;
        u16* Pr = P + (wv*64 + qrow)*72;
        Pr[     l15] = f2us(e0*inv);
        Pr[16 + l15] = f2us(e1*inv);
        Pr[32 + l15] = f2us(e2*inv);
        Pr[48 + l15] = f2us(e3*inv);
      }
    }
  }

  // ---- PV (MFMA): AO[q][d] = P . V  (wave-private) ----
  f32x4 av[4];
  #pragma unroll
  for(int mt=0;mt<4;mt++) av[mt] = (f32x4){0.f,0.f,0.f,0.f};
  #pragma unroll
  for(int ks=0;ks<2;ks++){
    s16x8 Bv = *(const s16x8*)(vt + (wv*16 + l15)*72 + ks*32 + lg*8);
    #pragma unroll
    for(int mt=0;mt<4;mt++){
      s16x8 Ap = *(const s16x8*)(P + (wv*64 + mt*16 + l15)*72 + ks*32 + lg*8);
      av[mt] = mfma16(Ap, Bv, av[mt]);
    }
  }
  __syncthreads();                         // B3: all PV done (P, vt dead)
  #pragma unroll
  for(int mt=0;mt<4;mt++)
    #pragma unroll
    for(int r=0;r<4;r++)
      ao[(mt*16 + 4*lg + r)*72 + wv*16 + l15] = f2us(av[mt][r]);
  __syncthreads();                         // B4: ao ready (read by all waves)

  // ---- proj (MFMA): out-ch tile wv; + bias; stage fp32 to pS ----
  {
    float bv = projb[wv*16 + l15];
    const uint4* wf = (const uint4*)pjf;
    s16x8 B00 = as_s8(wf[((wv*2+0)*2+0)*64 + lane]);
    s16x8 B01 = as_s8(wf[((wv*2+0)*2+1)*64 + lane]);
    s16x8 B10 = as_s8(wf[((wv*2+1)*2+0)*64 + lane]);
    s16x8 B11 = as_s8(wf[((wv*2+1)*2+1)*64 + lane]);
    #pragma unroll
    for(int mt=0;mt<4;mt++){
      s16x8 A0 = *(const s16x8*)(ao + (mt*16+l15)*72 + lg*8);
      s16x8 A1 = *(const s16x8*)(ao + (mt*16+l15)*72 + 32 + lg*8);
      f32x4 acc = (f32x4){bv,bv,bv,bv};
      acc = mfma16(A0, B00, acc);
      acc = mfma16(A0, B01, acc);
      acc = mfma16(A1, B10, acc);
      acc = mfma16(A1, B11, acc);
      #pragma unroll
      for(int r=0;r<4;r++)
        pS[(mt*16 + 4*lg + r)*69 + wv*16 + l15] = acc[r];  // wave-private cols
    }
  }
  __syncthreads();                         // pS ready
  // ---- fused scatter: x2 = x + t*A + proj (pure write; inverse roll) ----
  {
    int tok = lane;
    int ti = tok>>3, tj = tok&7;
    int hf = (hb*8+ti-4)&127, wf_ = (wb*8+tj-4)&127;
    int hw = hf*128 + wf_;
    const float* xb  = x  + (u*5+v)*HW + hw;
    const u16*   tbp = t  + (u*5+v)*HW + hw;
    float*       ob  = x2 + (u*5+v)*HW + hw;
    #pragma unroll
    for(int cq=0;cq<16;cq++){
      int c = wv*16 + cq;
      float tv = us2f(tbp[c*POS]);
      float A = F0[(c<<14)+hw] + F1[c*25+uv]
              + F2[(c*5+u)*128+hf] + F3[(c*5+v)*128+wf_];
      ob[c*POS] = xb[c*POS] + tv*A + pS[tok*69 + c];
    }
  }
}

// ---------------- K9: pre-fragment mbconv weights for MFMA (hi/lo split bf16) ----
__global__ void k_wfrag(const float* __restrict__ w1, const float* __restrict__ w2,
                        u16* __restrict__ w1f, u16* __restrict__ w2f){
  int g = blockIdx.x*256 + threadIdx.x;        // < 65536
  int table = g >> 15;
  int rem = g & 32767;
  int f = rem >> 9, i = rem & 511;
  int l = i >> 3, e = i & 7;
  int l15 = l & 15, lgv = l >> 4;
  if(table==0){
    int tt = f >> 2, h = (f>>1)&1, s = f&1;
    int o = tt*16 + l15, c = h*32 + lgv*8 + e;
    float w = w1[o*64 + c];
    u16 hi = f2us(w);
    w1f[f*512 + i] = (s==0) ? hi : f2us(w - us2f(hi));
  } else {
    int tt = f & 3, g2 = f >> 2;
    int s = g2 & 1, h = (g2>>1)&1, q = g2>>2;
    int oc = q*64 + h*32 + lgv*8 + e, outc = tt*16 + l15;
    float w = w2[outc*256 + oc];
    u16 hi = f2us(w);
    w2f[f*512 + i] = (s==0) ? hi : f2us(w - us2f(hi));
  }
}

// ---------------- K9b: pack dw weights as bf16 channel-pairs dwp[q][tap][po] ----
__global__ void k_dwp(const float* __restrict__ dwg, u32* __restrict__ dwp){
  int i = blockIdx.x*256 + threadIdx.x;        // < 3200
  if(i >= 3200) return;
  int q = i/800, rem = i - q*800;
  int k = rem >> 5, po = rem & 31;
  int ch = q*64 + 2*po;
  u32 lo = f2us(dwg[ch*25 + k]);
  u32 hi = f2us(dwg[(ch+1)*25 + k]);
  dwp[i] = lo | (hi<<16);
}

// ---------------- K8 v8: fused MBConv — wide-LDS dw path (verified round 11) -----
#define LN_T2 72    // t2s row stride (u16)
#define RS1P  148   // y1p row stride (u32 per channel-pair row)
#define LN_Y2 72    // y2h row stride (u16)
__global__ __launch_bounds__(256,3) void k_mbconv(
    const u16* __restrict__ t2, const float* x2,
    const u16* __restrict__ w1f, const float* __restrict__ b1,
    const u32* __restrict__ dwpg, const float* __restrict__ db,
    const u16* __restrict__ w2f, const float* __restrict__ b2,
    float* out){
  __shared__ __align__(16) u16 t2s[144*LN_T2];   // 12x12 halo x 64ch   20736B
  __shared__ __align__(16) u32 y1p[32*RS1P];     // pair-packed y1      18944B
  __shared__ __align__(16) u16 y2h[64*LN_Y2];    // dw out (bf16)        9216B
  __shared__ __align__(16) u32 dwp_s[25*32];     // dw weight pairs      3200B
  int tid = threadIdx.x;                         // total 52096B -> 3 blocks/CU
  int lane = tid & 63, wv = tid >> 6;
  int l15 = lane & 15, lg = lane >> 4;
  int bid = blockIdx.x;
  int wid = (bid & 7)*800 + (bid >> 3);          // XCD swizzle, bijective
  int n = wid >> 8, tile = wid & 255;            // 25 groups x 256 tiles
  int h0 = (tile>>4)<<3, w0 = (tile&15)<<3;

  // ---- stage t2 halo: plane-major global -> pixel-major bf16 LDS tile ----
  {
    const u16* tb = t2 + (size_t)n*64*HW;
    for(int L=tid; L<4608; L+=256){
      int c = L/72, j = L - c*72;
      int rr = j/6, k2 = j - rr*6;
      int pc = k2*2;
      int hh = h0-2+rr, ww = w0-2+pc;
      u32 val = 0;
      if((unsigned)hh<128u){
        const u16* rowp = tb + c*HW + hh*128;
        if((unsigned)ww<127u) val = *(const u32*)(rowp + ww);
        else {
          u32 lo = ((unsigned)ww    <128u) ? rowp[ww]   : 0;
          u32 hi = ((unsigned)(ww+1)<128u) ? rowp[ww+1] : 0;
          val = lo | (hi<<16);
        }
      }
      int p = rr*12 + pc;
      t2s[p*LN_T2 + c]      = (u16)val;
      t2s[(p+1)*LN_T2 + c]  = (u16)(val>>16);
    }
  }
  f32x4 accP[4];
  #pragma unroll
  for(int m=0;m<4;m++) accP[m] = (f32x4){0.f,0.f,0.f,0.f};
  // dw mapping: thread = (output row r, channel pair po)
  int po = tid & 31, rdw = tid >> 5;             // rdw 0..7, po 0..31
  int oc0 = 2*po;
  // hoisted expand-epilogue in-bounds mask (q-invariant, 36 bits)
  u32 inm0 = 0, inm1 = 0;
  #pragma unroll
  for(int m=0;m<9;m++){
    #pragma unroll
    for(int r=0;r<4;r++){
      int pos = m*16 + lg*4 + r;
      int rr = pos/12, pc = pos - rr*12;
      int hh = h0-2+rr, ww = w0-2+pc;
      u32 in = (((unsigned)hh<128u)&&((unsigned)ww<128u)) ? 1u : 0u;
      int bit = m*4+r;
      if(bit<32) inm0 |= in<<bit; else inm1 |= in<<(bit-32);
    }
  }
  int pairrow = wv*8 + (l15>>1);                 // expand-write y1p row
  bool evenl = (l15 & 1) == 0;
  __syncthreads();

  for(int q=0;q<4;q++){                          // 4 chunks of 64 expanded ch
    // stage this chunk's packed dw weights
    for(int i=tid;i<800;i+=256) dwp_s[i] = dwpg[q*800 + i];

    // ---- expand 1x1 (MFMA) -> pair-packed y1p[po][pos] ----
    {
      int t_g = q*4 + wv;
      float b1v = b1[t_g*16 + l15];
      const uint4* wf = (const uint4*)w1f;
      s16x8 b00 = as_s8(wf[((t_g*2+0)*2+0)*64 + lane]);
      s16x8 b01 = as_s8(wf[((t_g*2+0)*2+1)*64 + lane]);
      s16x8 b10 = as_s8(wf[((t_g*2+1)*2+0)*64 + lane]);
      s16x8 b11 = as_s8(wf[((t_g*2+1)*2+1)*64 + lane]);
      #pragma unroll
      for(int m=0;m<9;m++){
        s16x8 a0 = *(const s16x8*)(t2s + (m*16+l15)*LN_T2 + lg*8);
        s16x8 a1 = *(const s16x8*)(t2s + (m*16+l15)*LN_T2 + 32 + lg*8);
        f32x4 acc = (f32x4){b1v,b1v,b1v,b1v};
        acc = mfma16(a0, b00, acc);
        acc = mfma16(a0, b01, acc);
        acc = mfma16(a1, b10, acc);
        acc = mfma16(a1, b11, acc);
        float sv[4];
        #pragma unroll
        for(int r=0;r<4;r++){
          int bit = m*4+r;                       // compile-time per unrolled iter
          u32 in = (bit<32) ? ((inm0>>bit)&1u) : ((inm1>>(bit-32))&1u);
          sv[r] = in ? silu_fast(acc[r]) : 0.f;
        }
        // my channel's bf16 pairs over positions
        u32 A = (u32)f2us(sv[0]) | ((u32)f2us(sv[1])<<16);
        u32 B = (u32)f2us(sv[2]) | ((u32)f2us(sv[3])<<16);
        // partner channel (l15^1) same positions
        u32 Ap = __shfl_xor(A, 1);
        u32 Bp = __shfl_xor(B, 1);
        if(evenl){
          // interleave: W[i] = (my sv[i] lo, partner sv[i] hi)
          uint4 W;
          W.x = (A  & 0xffffu)      | (Ap << 16);
          W.y = (A  >> 16)          | (Ap & 0xffff0000u);
          W.z = (B  & 0xffffu)      | (Bp << 16);
          W.w = (B  >> 16)          | (Bp & 0xffff0000u);
          int pos0 = m*16 + lg*4;
          *(uint4*)(y1p + pairrow*RS1P + pos0) = W;
        }
      }
    }
    __syncthreads();                             // y1p + dwp_s ready

    // ---- depthwise 5x5 + silu: 3x ds_read_b128 per kh, packed f32x2 fma ----
    {
      f32x2 acc2[8];
      #pragma unroll
      for(int cc=0;cc<8;cc++) acc2[cc] = (f32x2){0.f,0.f};
      #pragma unroll
      for(int kh=0;kh<5;kh++){
        f32x2 wv2[5];
        #pragma unroll
        for(int kw=0;kw<5;kw++) wv2[kw] = up2f(dwp_s[(kh*5+kw)*32 + po]);
        const uint4* rp = (const uint4*)(y1p + po*RS1P + (rdw+kh)*12);
        uint4 Ra = rp[0], Rb = rp[1], Rc = rp[2];   // 12 consecutive pair-u32
        u32 rw[12] = {Ra.x,Ra.y,Ra.z,Ra.w, Rb.x,Rb.y,Rb.z,Rb.w, Rc.x,Rc.y,Rc.z,Rc.w};
        f32x2 row[12];
        #pragma unroll
        for(int j=0;j<12;j++) row[j] = up2f(rw[j]);
        #pragma unroll
        for(int cc=0;cc<8;cc++)
          #pragma unroll
          for(int kw=0;kw<5;kw++)
            acc2[cc] = __builtin_elementwise_fma(row[cc+kw], wv2[kw], acc2[cc]);
      }
      float db0 = db[q*64 + oc0], db1 = db[q*64 + oc0 + 1];
      #pragma unroll
      for(int cc=0;cc<8;cc++){
        u32 p0 = f2us(silu_fast(acc2[cc].x + db0));
        u32 p1 = f2us(silu_fast(acc2[cc].y + db1));
        *(u32*)(y2h + (rdw*8+cc)*LN_Y2 + oc0) = p0 | (p1<<16);
      }
    }
    __syncthreads();                             // y2h ready

    // ---- project 1x1 (MFMA) accumulate: D[pix][outc] += y2 . w2(hi+lo) ----
    {
      const uint4* wf = (const uint4*)w2f;
      s16x8 bh0 = as_s8(wf[(((q*2+0)*2+0)*4 + wv)*64 + lane]);
      s16x8 bl0 = as_s8(wf[(((q*2+0)*2+1)*4 + wv)*64 + lane]);
      s16x8 bh1 = as_s8(wf[(((q*2+1)*2+0)*4 + wv)*64 + lane]);
      s16x8 bl1 = as_s8(wf[(((q*2+1)*2+1)*4 + wv)*64 + lane]);
      #pragma unroll
      for(int m=0;m<4;m++){
        s16x8 ah0 = *(const s16x8*)(y2h + (m*16+l15)*LN_Y2 + lg*8);
        s16x8 ah1 = *(const s16x8*)(y2h + (m*16+l15)*LN_Y2 + 32 + lg*8);
        f32x4 acc = accP[m];
        acc = mfma16(ah0, bh0, acc);
        acc = mfma16(ah0, bl0, acc);
        acc = mfma16(ah1, bh1, acc);
        acc = mfma16(ah1, bl1, acc);
        accP[m] = acc;
      }
    }
    __syncthreads();                             // before next chunk reuse
  }

  int outc = wv*16 + l15;
  float b2v = b2[outc];
  float*       ob = out + (size_t)(n*64+outc)*HW;
  const float* xb = x2  + (size_t)(n*64+outc)*HW;
  #pragma unroll
  for(int m=0;m<4;m++){
    #pragma unroll
    for(int r=0;r<4;r++){
      int pix = m*16 + lg*4 + r;
      int rr = pix>>3, cc = pix&7;
      int g = (h0+rr)*128 + (w0+cc);
      ob[g] = accP[m][r] + b2v + xb[g];
    }
  }
}

// ---------------- workspace layout (bytes), total 61,600,256 ----------------
static const size_t OFF_T   = 0;             // u16  t / t2 (reused)   52,428,800
static const size_t OFF_PHW = 52428800;      // f32  pool hw            4,194,304
static const size_t OFF_PHU = 56623104;      // f32  pool hu              163,840
static const size_t OFF_PVW = 56786944;      // f32  pool vw              163,840
static const size_t OFF_PUV = 56950784;      // f32  pool uv                6,400
static const size_t OFF_F0  = 56957184;      // f32  field hw           4,194,304
static const size_t OFF_F2  = 61151488;      // f32  field uh             163,840
static const size_t OFF_F3  = 61315328;      // f32  field vw             163,840
static const size_t OFF_F1  = 61479168;      // f32  field uv               6,400
static const size_t OFF_BT  = 61485568;      // f32  attn bias             65,536
static const size_t OFF_QT  = 61551104;      // u16  qkv MFMA frags        49,152
// Aliased onto the Phw region (dead after k_mca):
static const size_t OFF_W1F = 52428800;      // u16  w1 MFMA frags         65,536
static const size_t OFF_W2F = 52494336;      // u16  w2 MFMA frags         65,536
static const size_t OFF_PJF = 52559872;      // u16  proj MFMA frags       16,384
static const size_t OFF_DWP = 52576256;      // u32  dw bf16 pairs         12,800

extern "C" void kernel_launch(void* const* d_in, const int* in_sizes, int n_in,
                              void* d_out, int out_size, void* d_ws, size_t ws_size,
                              hipStream_t stream){
  (void)in_sizes; (void)n_in; (void)out_size; (void)ws_size;
  const float* x     = (const float*)d_in[0];
  const float* n1w   = (const float*)d_in[1];
  const float* n1b   = (const float*)d_in[2];
  const float* n2w   = (const float*)d_in[3];
  const float* n2b   = (const float*)d_in[4];
  const float* qkvw  = (const float*)d_in[5];
  const float* qkvb  = (const float*)d_in[6];
  const float* projw = (const float*)d_in[7];
  const float* projb = (const float*)d_in[8];
  const float* rpbt  = (const float*)d_in[9];
  const int*   rpi   = (const int*)d_in[10];
  const float* mw1   = (const float*)d_in[11];
  const float* mb1   = (const float*)d_in[12];
  const float* mw2   = (const float*)d_in[13];
  const float* mb2   = (const float*)d_in[14];
  const float* mfw   = (const float*)d_in[15];
  const float* mfb   = (const float*)d_in[16];
  const float* bw1   = (const float*)d_in[17];
  const float* bb1   = (const float*)d_in[18];
  const float* bdw   = (const float*)d_in[19];
  const float* bdb   = (const float*)d_in[20];
  const float* bw2   = (const float*)d_in[21];
  const float* bb2   = (const float*)d_in[22];

  char* ws = (char*)d_ws;
  u16*   t   = (u16*)  (ws + OFF_T);
  float* Phw = (float*)(ws + OFF_PHW);
  float* Phu = (float*)(ws + OFF_PHU);
  float* Pvw = (float*)(ws + OFF_PVW);
  float* Puv = (float*)(ws + OFF_PUV);
  float* F0  = (float*)(ws + OFF_F0);
  float* F1  = (float*)(ws + OFF_F1);
  float* F2  = (float*)(ws + OFF_F2);
  float* F3  = (float*)(ws + OFF_F3);
  float* Bt  = (float*)(ws + OFF_BT);
  u16*   qf  = (u16*)  (ws + OFF_QT);
  u16*   w1f = (u16*)  (ws + OFF_W1F);
  u16*   w2f = (u16*)  (ws + OFF_W2F);
  u16*   pjf = (u16*)  (ws + OFF_PJF);
  u32*   dwp = (u32*)  (ws + OFF_DWP);
  float* x2  = (float*)d_out;    // f32 residual accumulator lives in d_out
  float* outp= (float*)d_out;

  // 1) t = LN1(x) (bf16 channel-major; pools + MFMA attention input)
  k_ln1<<<1600,256,0,stream>>>(x, n1w, n1b, t);
  // 2) pools of t
  k_pool_hw<<<4096,256,0,stream>>>(t, Phw);
  k_pool_hu<<<10240,256,0,stream>>>(t, Phu);
  k_pool_vw<<<320,128,0,stream>>>(t, Pvw);
  k_pool_uv<<<400,256,0,stream>>>(t, Puv);
  // 3) MCA convs -> gate fields (64-thread blocks, full CU coverage)
  k_mca<<<277,64,0,stream>>>(Phw,Phu,Pvw,Puv, mw1,mb1,mw2,mb2, mfw,mfb, F0,F1,F2,F3);
  // 4) attention bias table [h][q][tk] + qkv/proj weight fragments
  k_bias<<<16,256,0,stream>>>(rpi, rpbt, Bt);
  k_wt<<<128,256,0,stream>>>(qkvw, projw, qf, pjf);
  // 5) x2 = x + t*A + window_attn(t)  (fused combine+attn, pure write)
  k_catt<<<6400,256,0,stream>>>(t, x, qf, qkvb, pjf, projb, Bt, F0,F1,F2,F3, x2);
  // 6) pre-fragment mbconv weights + packed dw pairs
  k_wfrag<<<256,256,0,stream>>>(bw1, bw2, w1f, w2f);
  k_dwp<<<13,256,0,stream>>>(bdw, dwp);
  // 7) t2 = LN2(x2), plane-major bf16 (t buffer reused)
  k_ln2<<<1600,256,0,stream>>>(x2, n2w, n2b, t);
  // 8) out = x2 + mbconv(t2)  (MFMA v8, in-place on d_out)
  k_mbconv<<<6400,256,0,stream>>>(t, x2, w1f, bb1, dwp, bdb, w2f, bb2, outp);
}